// Round 2
// baseline (6395.436 us; speedup 1.0000x reference)
//
#include <hip/hip_runtime.h>
#include <hip/hip_fp16.h>
#include <math.h>

typedef _Float16 f16;
typedef _Float16 half8 __attribute__((ext_vector_type(8)));
typedef _Float16 half2v __attribute__((ext_vector_type(2)));
typedef float float4v __attribute__((ext_vector_type(4)));

#define AS1 __attribute__((address_space(1)))
#define AS3 __attribute__((address_space(3)))

// ---------------- workspace layout ----------------
constexpr size_t alup(size_t x){ return (x + 255) & ~(size_t)255; }
constexpr size_t OFF_MT   = 0;                                    // 150*150 fp32 (zeroed)
constexpr size_t OFF_CNT  = alup(OFF_MT + 150*150*4);             // 8 barrier counters, 256B apart (zeroed)
constexpr size_t OFF_DEG  = alup(OFF_CNT + 8*256);                // 150 fp32 (zeroed)
constexpr size_t OFF_HB0  = alup(OFF_DEG + 150*4);                // 32*512 fp32 (zeroed)
constexpr size_t OFF_HB1  = alup(OFF_HB0 + 32*512*4);             // 32*512 fp32 (zeroed)
constexpr size_t OFF_WI2P = alup(OFF_HB1 + 32*512*4);             // 512*512 f16 padded (zeroed)
constexpr size_t OFF_WFCP = alup(OFF_WI2P + (size_t)512*512*2);   // 256*160 f16 padded (zeroed)
constexpr size_t OFF_DECB = alup(OFF_WFCP + (size_t)256*160*2);   // 3200*160 f16 (zeroed)
constexpr size_t ZONE_END = alup(OFF_DECB + (size_t)3200*160*2);
constexpr size_t OFF_WN   = ZONE_END;                             // 150*32 fp32
constexpr size_t OFF_EDST = alup(OFF_WN + 4800*4);                // 1500 int
constexpr size_t OFF_EVAL = alup(OFF_EDST + 1500*4);              // 1500 fp32
constexpr size_t OFF_XF   = alup(OFF_EVAL + 1500*4);              // 480000 fp32 (x in row layout)
constexpr size_t OFF_SS   = alup(OFF_XF + (size_t)480000*4);      // 480000 fp32 (agg scalar)
constexpr size_t OFF_XT   = alup(OFF_SS + (size_t)480000*4);      // 3200*4800 f16
constexpr size_t OFF_WI1H = alup(OFF_XT + (size_t)3200*4800*2);   // 1536*4800 f16
constexpr size_t OFF_XI1  = alup(OFF_WI1H + (size_t)1536*4800*2); // 3200*1536 fp32
constexpr size_t OFF_U    = alup(OFF_XI1 + (size_t)3200*1536*4);  // 3200*512 f16
constexpr size_t OFF_XI2P = alup(OFF_U + (size_t)3200*512*2);     // 3200*512 fp32

static __device__ __forceinline__ float sigmoidf_(float x){ return 1.0f/(1.0f+expf(-x)); }

// ---------------- graph construction ----------------
__global__ void k_norm(const float* __restrict__ emb, float* __restrict__ WN) {
    int n = threadIdx.x;
    if (n < 150) {
        float s = 0.f;
        #pragma unroll
        for (int c = 0; c < 32; ++c) { float v = emb[n*32+c]; s += v*v; }
        float nrm = fmaxf(sqrtf(s), 1e-8f);
        float inv = 1.0f / nrm;
        #pragma unroll
        for (int c = 0; c < 32; ++c) WN[n*32+c] = emb[n*32+c] * inv;
    }
}

__global__ void k_topk(const float* __restrict__ WN, int* __restrict__ EDST,
                       float* __restrict__ EVAL, float* __restrict__ DEG) {
    __shared__ float WnT[32*152];
    __shared__ float As[160];
    int tid = threadIdx.x;
    int i = blockIdx.x;  // row
    for (int idx = tid; idx < 4800; idx += 256) {
        int jj = idx >> 5, c = idx & 31;
        WnT[c*152 + jj] = WN[idx];
    }
    __syncthreads();
    int j = tid;
    if (j < 150) {
        float a = 0.f;
        #pragma unroll
        for (int c = 0; c < 32; ++c) a += WnT[c*152 + i] * WnT[c*152 + j];
        a = (j == i) ? 0.f : fmaxf(a, 0.f);
        As[j] = a;
    }
    __syncthreads();
    if (j < 150) {
        float aj = As[j];
        int cnt = 0;
        for (int m = 0; m < 150; ++m) {
            float am = As[m];
            cnt += (am > aj) || (am == aj && m < j);
        }
        if (cnt < 10) {
            EDST[i*10 + cnt] = j;
            EVAL[i*10 + cnt] = aj;
            atomicAdd(&DEG[j], aj);
        }
    }
}

__global__ void k_finalize(const int* __restrict__ EDST, const float* __restrict__ EVAL,
                           const float* __restrict__ DEG, float* __restrict__ MT) {
    __shared__ float dinv[160];
    int tid = threadIdx.x;
    if (tid < 150) {
        float d = DEG[tid];
        dinv[tid] = (d > 0.f) ? rsqrtf(d) : 0.f;
    }
    __syncthreads();
    for (int e = tid; e < 1500; e += 256) {
        int src = e / 10;
        int dst = EDST[e];
        MT[src*150 + dst] = dinv[src] * EVAL[e] * dinv[dst];
    }
}

// ---------------- fp32 -> f16 (with optional row padding) ----------------
__global__ void k_cvt_pad(const float* __restrict__ src, f16* __restrict__ dst,
                          int rows, int cols, int ldd) {
    long long idx = (long long)blockIdx.x * blockDim.x + threadIdx.x;
    long long n = (long long)rows * cols;
    if (idx >= n) return;
    if (ldd == cols) {
        dst[idx] = (f16)src[idx];
    } else {
        int r = (int)(idx / cols), c = (int)(idx % cols);
        dst[(size_t)r*ldd + c] = (f16)src[idx];
    }
}

// ---------------- x row-layout permute: XF[b*15000 + n*100 + t] = window[b,t,n] ----------------
__global__ void k_perm(const float* __restrict__ window, float* __restrict__ XF) {
    int idx = blockIdx.x * blockDim.x + threadIdx.x;   // source index (b*100+t)*150+n
    if (idx >= 480000) return;
    float v = window[idx];
    int b = idx / 15000;
    int r = idx % 15000;
    int t = r / 150, n = r % 150;
    XF[b*15000 + n*100 + t] = v;
}

// ---------------- scrambled ARMA aggregation: per contiguous 150-chunk of XF ----------------
// SS[base + j] = sum_i MT[i,j] * XF[base + i],  base = chunk*150
__global__ void k_conv(const float* __restrict__ XF, const float* __restrict__ MT,
                       float* __restrict__ SS) {
    __shared__ float xs[152];
    int tid = threadIdx.x;
    int base = blockIdx.x * 150;
    if (tid < 150) xs[tid] = XF[base + tid];
    __syncthreads();
    if (tid < 150) {
        float s = 0.f;
        for (int m = 0; m < 150; ++m) s += MT[m*150 + tid] * xs[m];
        SS[base + tid] = s;
    }
}

// ---------------- epilogue: gelu(SS*wi + XF*wr + b) + emb -> xt (f16) ----------------
// xt[(b*100+t)*150 + n][c], reading SS/XF at f = b*15000 + n*100 + t
__global__ void k_xt(const float* __restrict__ SS, const float* __restrict__ XF,
                     const float* __restrict__ w_init, const float* __restrict__ w_root,
                     const float* __restrict__ arma_b, const float* __restrict__ emb,
                     f16* __restrict__ xt) {
    __shared__ float ssl[152];
    __shared__ float xfl[152];
    int tid = threadIdx.x;
    int bid = blockIdx.x;           // = b*100 + t
    int b = bid / 100, t = bid % 100;
    if (tid < 150) {
        int f = b*15000 + tid*100 + t;
        ssl[tid] = SS[f];
        xfl[tid] = XF[f];
    }
    __syncthreads();
    for (int e = tid; e < 4800; e += 256) {
        int n = e >> 5, c = e & 31;
        float pre = ssl[n]*w_init[c] + xfl[n]*w_root[c] + arma_b[c];
        float g = 0.5f * pre * (1.0f + erff(pre * 0.70710678118654752f));
        xt[(size_t)bid*4800 + e] = (f16)(g + emb[e]);
    }
}

// ---------------- f16 MFMA GEMM: C[M,N] = A[M,K] @ B[N,K]^T + bias ----------------
// M,Npad multiples of 128; K multiple of 32. Stores only cols < nvalid.
__global__ void k_gemm_f16(const f16* __restrict__ A, const f16* __restrict__ Bm,
                           const float* __restrict__ bias, float* __restrict__ C,
                           int K, int ldc, int nvalid, int ntn) {
    __shared__ f16 As[128*32];
    __shared__ f16 Bs[128*32];
    int tid = threadIdx.x;
    int lane = tid & 63, wave = tid >> 6;
    int wm = wave >> 1, wn = wave & 1;
    int tm = blockIdx.x / ntn, tn = blockIdx.x % ntn;
    int m0 = tm * 128, n0 = tn * 128;
    int lrow = lane & 15, quad = lane >> 4;

    float4v acc[4][4];
    #pragma unroll
    for (int mi = 0; mi < 4; ++mi)
        #pragma unroll
        for (int ni = 0; ni < 4; ++ni)
            acc[mi][ni] = (float4v){0.f, 0.f, 0.f, 0.f};

    for (int k0 = 0; k0 < K; k0 += 32) {
        #pragma unroll
        for (int i = 0; i < 2; ++i) {
            int chunk = i*256 + tid;
            int row = chunk >> 2, cq = chunk & 3;
            int cbase = chunk & ~63;  // wave-uniform
            const f16* ga = A + (size_t)(m0+row)*K + k0 + cq*8;
            __builtin_amdgcn_global_load_lds((const AS1 void*)ga, (AS3 void*)(As + cbase*8), 16, 0, 0);
            const f16* gb = Bm + (size_t)(n0+row)*K + k0 + cq*8;
            __builtin_amdgcn_global_load_lds((const AS1 void*)gb, (AS3 void*)(Bs + cbase*8), 16, 0, 0);
        }
        __syncthreads();
        half8 aF[4], bF[4];
        #pragma unroll
        for (int mi = 0; mi < 4; ++mi)
            aF[mi] = *(const half8*)&As[(wm*64 + mi*16 + lrow)*32 + quad*8];
        #pragma unroll
        for (int ni = 0; ni < 4; ++ni)
            bF[ni] = *(const half8*)&Bs[(wn*64 + ni*16 + lrow)*32 + quad*8];
        #pragma unroll
        for (int mi = 0; mi < 4; ++mi)
            #pragma unroll
            for (int ni = 0; ni < 4; ++ni)
                acc[mi][ni] = __builtin_amdgcn_mfma_f32_16x16x32_f16(aF[mi], bF[ni], acc[mi][ni], 0, 0, 0);
        __syncthreads();
    }

    #pragma unroll
    for (int ni = 0; ni < 4; ++ni) {
        int gcol = n0 + wn*64 + ni*16 + lrow;
        if (gcol >= nvalid) continue;
        float bv = bias[gcol];
        #pragma unroll
        for (int mi = 0; mi < 4; ++mi) {
            int growb = m0 + wm*64 + mi*16 + quad*4;
            #pragma unroll
            for (int r = 0; r < 4; ++r)
                C[(size_t)(growb + r)*ldc + gcol] = acc[mi][ni][r] + bv;
        }
    }
}

// ---------------- GRU1: 8 groups x 32 blocks; group g owns batches 4g..4g+3 ----------------
__global__ void k_gru1(const float* __restrict__ xi1, const float* __restrict__ Wh1,
                       const float* __restrict__ bh1, float* __restrict__ hb0,
                       float* __restrict__ hb1, int* __restrict__ cnt) {
    __shared__ __align__(16) f16 Wsh[48*520];
    __shared__ __align__(16) float hs[4*520];
    __shared__ float ghs[4*48];
    __shared__ float xis[4*48];
    int tid = threadIdx.x;
    int g = blockIdx.x >> 5;       // group 0..7
    int j = blockIdx.x & 31;       // hidden-block 0..31 -> hidden [16j,16j+16)
    int b0 = g * 4;

    // preload weights (rows: gate*512 + 16j + i), fp16 into LDS
    for (int idx = tid; idx < 48*512; idx += 256) {
        int rr = idx >> 9, k = idx & 511;
        int gate = rr >> 4, hi = (j << 4) + (rr & 15);
        Wsh[rr*520 + k] = (f16)Wh1[(size_t)(gate*512 + hi)*512 + k];
    }

    bool act = tid < 192;
    int rr = tid >> 2, bl = tid & 3;
    int gate = rr >> 4;
    int grow = gate*512 + (j << 4) + (rr & 15);
    float bhv = 0.f;
    size_t xibase = 0;
    float xi_reg = 0.f;
    if (act) {
        bhv = bh1[grow];
        xibase = ((size_t)(b0 + bl) * 100) * 1536 + grow;
        xi_reg = xi1[xibase];  // t=0 prefetch
    }
    __syncthreads();

    int* mycnt = cnt + g * 64;  // 256B apart

    for (int t = 0; t < 100; ++t) {
        const float* cur = (t & 1) ? hb1 : hb0;
        float* nxt = (t & 1) ? hb0 : hb1;
        // stage h (4 batches x 512) via float4
        for (int idx = tid; idx < 512; idx += 256) {
            int bl2 = idx >> 7, k4 = (idx & 127) << 2;
            float4v v = *(const float4v*)&cur[((size_t)(b0 + bl2) << 9) + k4];
            *(float4v*)&hs[bl2*520 + k4] = v;
        }
        if (act) xis[bl*48 + rr] = xi_reg;
        __syncthreads();

        if (act) {
            const f16* wrow = &Wsh[rr*520];
            const float* hrow = &hs[bl*520];
            float a0 = 0.f, a1 = 0.f, a2 = 0.f, a3 = 0.f;
            #pragma unroll 8
            for (int k = 0; k < 512; k += 8) {
                half8 w = *(const half8*)&wrow[k];
                float4v h0 = *(const float4v*)&hrow[k];
                float4v h1 = *(const float4v*)&hrow[k+4];
                a0 += (float)w[0]*h0[0]; a1 += (float)w[1]*h0[1];
                a2 += (float)w[2]*h0[2]; a3 += (float)w[3]*h0[3];
                a0 += (float)w[4]*h1[0]; a1 += (float)w[5]*h1[1];
                a2 += (float)w[6]*h1[2]; a3 += (float)w[7]*h1[3];
            }
            ghs[bl*48 + rr] = (a0 + a1) + (a2 + a3) + bhv;
            // prefetch next xi (immutable data; safe across fences)
            int tn = (t < 99) ? t + 1 : 99;
            xi_reg = xi1[xibase + (size_t)tn * 1536];
        }
        __syncthreads();

        if (tid < 64) {
            int bl2 = tid >> 4, i = tid & 15;
            float xr = xis[bl2*48 + i],      gr = ghs[bl2*48 + i];
            float xz = xis[bl2*48 + 16 + i], gz = ghs[bl2*48 + 16 + i];
            float xn = xis[bl2*48 + 32 + i], gn = ghs[bl2*48 + 32 + i];
            float r = sigmoidf_(xr + gr);
            float z = sigmoidf_(xz + gz);
            float n = tanhf(xn + r * gn);
            int kidx = (j << 4) + i;
            float hold = hs[bl2*520 + kidx];
            float hnew = (1.f - z) * n + z * hold;
            nxt[((size_t)(b0 + bl2) << 9) + kidx] = hnew;
        }

        if (t < 99) {
            __threadfence();   // release: make h stores visible device-wide
            __syncthreads();
            if (tid == 0) {
                __hip_atomic_fetch_add(mycnt, 1, __ATOMIC_RELEASE, __HIP_MEMORY_SCOPE_AGENT);
                int target = 32 * (t + 1);
                while (__hip_atomic_load(mycnt, __ATOMIC_ACQUIRE, __HIP_MEMORY_SCOPE_AGENT) < target)
                    __builtin_amdgcn_s_sleep(2);
            }
            __syncthreads();
            __threadfence();   // acquire: invalidate caches before reading peers' h
        }
    }
}

// ---------------- u[b,t,k] = h_end[b, (t*512+k)/100]  (repeat_interleave quirk) ----------------
__global__ void k_build_u(const float* __restrict__ hend, f16* __restrict__ u) {
    int idx = blockIdx.x * blockDim.x + threadIdx.x;
    if (idx >= 32*100*512) return;
    int b = idx / 51200;
    int r = idx % 51200;
    int t = r >> 9, k = r & 511;
    u[idx] = (f16)hend[(b << 9) + ((t*512 + k) / 100)];
}

// ---------------- GRU2: one block per batch, Wh2 register-resident ----------------
__global__ void k_gru2(const float* __restrict__ xi2p, const float* __restrict__ Wh2,
                       const float* __restrict__ bh2, f16* __restrict__ decb) {
    __shared__ float hs2[160];
    __shared__ float ghs2[456];
    __shared__ float xis2[456];
    int tid = threadIdx.x;
    int b = blockIdx.x;
    half2v w2[150];
    float bh_lo = 0.f, bh_hi = 0.f;
    if (tid < 225) {
        #pragma unroll
        for (int k = 0; k < 150; ++k) {
            half2v wv;
            wv[0] = (f16)Wh2[tid*150 + k];
            wv[1] = (f16)Wh2[(tid + 225)*150 + k];
            w2[k] = wv;
        }
        bh_lo = bh2[tid];
        bh_hi = bh2[tid + 225];
    }
    if (tid < 150) hs2[tid] = 0.f;
    size_t row0 = (size_t)b * 100 * 512;
    float xr1 = xi2p[row0 + tid];
    float xr2 = (tid + 256 < 450) ? xi2p[row0 + tid + 256] : 0.f;
    __syncthreads();

    for (int t = 0; t < 100; ++t) {
        if (tid < 450) xis2[tid] = xr1;
        if (tid + 256 < 450) xis2[tid + 256] = xr2;
        __syncthreads();
        if (tid < 225) {
            float alo = bh_lo, ahi = bh_hi;
            #pragma unroll
            for (int k = 0; k < 150; ++k) {
                float hk = hs2[k];
                alo += (float)w2[k][0] * hk;
                ahi += (float)w2[k][1] * hk;
            }
            ghs2[tid] = alo;
            ghs2[tid + 225] = ahi;
        }
        // prefetch next xi row
        int tn = (t < 99) ? t + 1 : 99;
        size_t nrow = ((size_t)b * 100 + tn) * 512;
        xr1 = xi2p[nrow + tid];
        xr2 = (tid + 256 < 450) ? xi2p[nrow + tid + 256] : 0.f;
        __syncthreads();
        if (tid < 150) {
            int i = tid;
            float r = sigmoidf_(xis2[i] + ghs2[i]);
            float z = sigmoidf_(xis2[150 + i] + ghs2[150 + i]);
            float n = tanhf(xis2[300 + i] + r * ghs2[300 + i]);
            float hnew = (1.f - z) * n + z * hs2[i];
            hs2[i] = hnew;
            decb[((size_t)b*100 + t)*160 + i] = (f16)hnew;
        }
        __syncthreads();
    }
}

// ---------------- launch ----------------
extern "C" void kernel_launch(void* const* d_in, const int* in_sizes, int n_in,
                              void* d_out, int out_size, void* d_ws, size_t ws_size,
                              hipStream_t stream) {
    const float* window = (const float*)d_in[0];
    const float* emb    = (const float*)d_in[1];
    const float* w_init = (const float*)d_in[2];
    const float* w_root = (const float*)d_in[3];
    const float* arma_b = (const float*)d_in[4];
    const float* Wi1    = (const float*)d_in[5];
    const float* Wh1    = (const float*)d_in[6];
    const float* bi1    = (const float*)d_in[7];
    const float* bh1    = (const float*)d_in[8];
    const float* Wi2    = (const float*)d_in[9];
    const float* Wh2    = (const float*)d_in[10];
    const float* bi2    = (const float*)d_in[11];
    const float* bh2    = (const float*)d_in[12];
    const float* W_fc   = (const float*)d_in[13];
    const float* b_fc   = (const float*)d_in[14];
    float* out = (float*)d_out;

    char* ws = (char*)d_ws;
    float* MT   = (float*)(ws + OFF_MT);
    int*   CNT  = (int*)  (ws + OFF_CNT);
    float* DEG  = (float*)(ws + OFF_DEG);
    float* HB0  = (float*)(ws + OFF_HB0);
    float* HB1  = (float*)(ws + OFF_HB1);
    f16*   WI2P = (f16*)  (ws + OFF_WI2P);
    f16*   WFCP = (f16*)  (ws + OFF_WFCP);
    f16*   DECB = (f16*)  (ws + OFF_DECB);
    float* WN   = (float*)(ws + OFF_WN);
    int*   EDST = (int*)  (ws + OFF_EDST);
    float* EVAL = (float*)(ws + OFF_EVAL);
    float* XF   = (float*)(ws + OFF_XF);
    float* SS   = (float*)(ws + OFF_SS);
    f16*   XT   = (f16*)  (ws + OFF_XT);
    f16*   WI1H = (f16*)  (ws + OFF_WI1H);
    float* XI1  = (float*)(ws + OFF_XI1);
    f16*   UB   = (f16*)  (ws + OFF_U);
    float* XI2P = (float*)(ws + OFF_XI2P);

    // zero the zone (MT scatter target, barrier counters, deg, h buffers, padded weights, dec)
    hipMemsetAsync(d_ws, 0, ZONE_END, stream);

    // graph build
    k_norm<<<1, 256, 0, stream>>>(emb, WN);
    k_topk<<<150, 256, 0, stream>>>(WN, EDST, EVAL, DEG);
    k_finalize<<<1, 256, 0, stream>>>(EDST, EVAL, DEG, MT);

    // weight conversions
    {
        long long n1 = (long long)1536*4800;
        k_cvt_pad<<<(unsigned)((n1 + 255)/256), 256, 0, stream>>>(Wi1, WI1H, 1536, 4800, 4800);
        long long n2 = (long long)450*512;
        k_cvt_pad<<<(unsigned)((n2 + 255)/256), 256, 0, stream>>>(Wi2, WI2P, 450, 512, 512);
        long long n3 = (long long)150*150;
        k_cvt_pad<<<(unsigned)((n3 + 255)/256), 256, 0, stream>>>(W_fc, WFCP, 150, 150, 160);
    }

    // x in row layout, scrambled aggregation, epilogue -> xt (f16)
    k_perm<<<(480000 + 255)/256, 256, 0, stream>>>(window, XF);
    k_conv<<<3200, 256, 0, stream>>>(XF, MT, SS);
    k_xt<<<3200, 256, 0, stream>>>(SS, XF, w_init, w_root, arma_b, emb, XT);

    // xi1 = xt @ Wi1^T + bi1   [3200 x 1536]
    k_gemm_f16<<<25*12, 256, 0, stream>>>(XT, WI1H, bi1, XI1, 4800, 1536, 1536, 12);

    // GRU1 scan -> h_end in HB0
    k_gru1<<<256, 256, 0, stream>>>(XI1, Wh1, bh1, HB0, HB1, CNT);

    // u (repeat_interleave quirk), f16
    k_build_u<<<(32*100*512 + 255)/256, 256, 0, stream>>>(HB0, UB);

    // xi2 = u @ Wi2^T + bi2   [3200 x 450] (padded to 512)
    k_gemm_f16<<<25*4, 256, 0, stream>>>(UB, WI2P, bi2, XI2P, 512, 512, 450, 4);

    // GRU2 scan -> dec (f16, padded K=160)
    k_gru2<<<32, 256, 0, stream>>>(XI2P, Wh2, bh2, DECB);

    // out = dec @ W_fc^T + b_fc  -> directly into d_out [3200 x 150]
    k_gemm_f16<<<25*2, 256, 0, stream>>>(DECB, WFCP, b_fc, out, 160, 150, 150, 2);

    (void)in_sizes; (void)n_in; (void)out_size; (void)ws_size;
}

// Round 3
// 2996.397 us; speedup vs baseline: 2.1344x; 2.1344x over previous
//
#include <hip/hip_runtime.h>
#include <hip/hip_fp16.h>
#include <math.h>

typedef _Float16 f16;
typedef _Float16 half8 __attribute__((ext_vector_type(8)));
typedef _Float16 half2v __attribute__((ext_vector_type(2)));
typedef float float4v __attribute__((ext_vector_type(4)));

#define AS1 __attribute__((address_space(1)))
#define AS3 __attribute__((address_space(3)))

// ---------------- workspace layout ----------------
constexpr size_t alup(size_t x){ return (x + 255) & ~(size_t)255; }
constexpr size_t OFF_MT   = 0;                                    // 150*150 fp32 (zeroed)
constexpr size_t OFF_CNT  = alup(OFF_MT + 150*150*4);             // 8 barrier counters, 256B apart (zeroed)
constexpr size_t OFF_DEG  = alup(OFF_CNT + 8*256);                // 150 fp32 (zeroed)
constexpr size_t OFF_HB0  = alup(OFF_DEG + 150*4);                // 32*512 fp32 (zeroed)
constexpr size_t OFF_HB1  = alup(OFF_HB0 + 32*512*4);             // 32*512 fp32 (zeroed)
constexpr size_t OFF_WI2P = alup(OFF_HB1 + 32*512*4);             // 512*512 f16 padded (zeroed)
constexpr size_t OFF_WFCP = alup(OFF_WI2P + (size_t)512*512*2);   // 256*160 f16 padded (zeroed)
constexpr size_t OFF_DECB = alup(OFF_WFCP + (size_t)256*160*2);   // 3200*160 f16 (zeroed)
constexpr size_t ZONE_END = alup(OFF_DECB + (size_t)3200*160*2);
constexpr size_t OFF_WN   = ZONE_END;                             // 150*32 fp32
constexpr size_t OFF_EDST = alup(OFF_WN + 4800*4);                // 1500 int
constexpr size_t OFF_EVAL = alup(OFF_EDST + 1500*4);              // 1500 fp32
constexpr size_t OFF_XF   = alup(OFF_EVAL + 1500*4);              // 480000 fp32 (x in row layout)
constexpr size_t OFF_SS   = alup(OFF_XF + (size_t)480000*4);      // 480000 fp32 (agg scalar)
constexpr size_t OFF_XT   = alup(OFF_SS + (size_t)480000*4);      // 3200*4800 f16
constexpr size_t OFF_WI1H = alup(OFF_XT + (size_t)3200*4800*2);   // 1536*4800 f16
constexpr size_t OFF_XI1  = alup(OFF_WI1H + (size_t)1536*4800*2); // 3200*1536 fp32
constexpr size_t OFF_U    = alup(OFF_XI1 + (size_t)3200*1536*4);  // 3200*512 f16
constexpr size_t OFF_XI2P = alup(OFF_U + (size_t)3200*512*2);     // 3200*512 fp32

static __device__ __forceinline__ float sigmoidf_(float x){ return 1.0f/(1.0f+expf(-x)); }

// ---------------- graph construction ----------------
__global__ void k_norm(const float* __restrict__ emb, float* __restrict__ WN) {
    int n = threadIdx.x;
    if (n < 150) {
        float s = 0.f;
        #pragma unroll
        for (int c = 0; c < 32; ++c) { float v = emb[n*32+c]; s += v*v; }
        float nrm = fmaxf(sqrtf(s), 1e-8f);
        float inv = 1.0f / nrm;
        #pragma unroll
        for (int c = 0; c < 32; ++c) WN[n*32+c] = emb[n*32+c] * inv;
    }
}

__global__ void k_topk(const float* __restrict__ WN, int* __restrict__ EDST,
                       float* __restrict__ EVAL, float* __restrict__ DEG) {
    __shared__ float WnT[32*152];
    __shared__ float As[160];
    int tid = threadIdx.x;
    int i = blockIdx.x;  // row
    for (int idx = tid; idx < 4800; idx += 256) {
        int jj = idx >> 5, c = idx & 31;
        WnT[c*152 + jj] = WN[idx];
    }
    __syncthreads();
    int j = tid;
    if (j < 150) {
        float a = 0.f;
        #pragma unroll
        for (int c = 0; c < 32; ++c) a += WnT[c*152 + i] * WnT[c*152 + j];
        a = (j == i) ? 0.f : fmaxf(a, 0.f);
        As[j] = a;
    }
    __syncthreads();
    if (j < 150) {
        float aj = As[j];
        int cnt = 0;
        for (int m = 0; m < 150; ++m) {
            float am = As[m];
            cnt += (am > aj) || (am == aj && m < j);
        }
        if (cnt < 10) {
            EDST[i*10 + cnt] = j;
            EVAL[i*10 + cnt] = aj;
            atomicAdd(&DEG[j], aj);
        }
    }
}

__global__ void k_finalize(const int* __restrict__ EDST, const float* __restrict__ EVAL,
                           const float* __restrict__ DEG, float* __restrict__ MT) {
    __shared__ float dinv[160];
    int tid = threadIdx.x;
    if (tid < 150) {
        float d = DEG[tid];
        dinv[tid] = (d > 0.f) ? rsqrtf(d) : 0.f;
    }
    __syncthreads();
    for (int e = tid; e < 1500; e += 256) {
        int src = e / 10;
        int dst = EDST[e];
        MT[src*150 + dst] = dinv[src] * EVAL[e] * dinv[dst];
    }
}

// ---------------- fp32 -> f16 (with optional row padding) ----------------
__global__ void k_cvt_pad(const float* __restrict__ src, f16* __restrict__ dst,
                          int rows, int cols, int ldd) {
    long long idx = (long long)blockIdx.x * blockDim.x + threadIdx.x;
    long long n = (long long)rows * cols;
    if (idx >= n) return;
    if (ldd == cols) {
        dst[idx] = (f16)src[idx];
    } else {
        int r = (int)(idx / cols), c = (int)(idx % cols);
        dst[(size_t)r*ldd + c] = (f16)src[idx];
    }
}

// ---------------- x row-layout permute: XF[b*15000 + n*100 + t] = window[b,t,n] ----------------
__global__ void k_perm(const float* __restrict__ window, float* __restrict__ XF) {
    int idx = blockIdx.x * blockDim.x + threadIdx.x;   // source index (b*100+t)*150+n
    if (idx >= 480000) return;
    float v = window[idx];
    int b = idx / 15000;
    int r = idx % 15000;
    int t = r / 150, n = r % 150;
    XF[b*15000 + n*100 + t] = v;
}

// ---------------- scrambled ARMA aggregation: per contiguous 150-chunk of XF ----------------
// SS[base + j] = sum_i MT[i,j] * XF[base + i],  base = chunk*150
__global__ void k_conv(const float* __restrict__ XF, const float* __restrict__ MT,
                       float* __restrict__ SS) {
    __shared__ float xs[152];
    int tid = threadIdx.x;
    int base = blockIdx.x * 150;
    if (tid < 150) xs[tid] = XF[base + tid];
    __syncthreads();
    if (tid < 150) {
        float s = 0.f;
        for (int m = 0; m < 150; ++m) s += MT[m*150 + tid] * xs[m];
        SS[base + tid] = s;
    }
}

// ---------------- epilogue: gelu(SS*wi + XF*wr + b) + emb -> xt (f16) ----------------
// xt[(b*100+t)*150 + n][c], reading SS/XF at f = b*15000 + n*100 + t
__global__ void k_xt(const float* __restrict__ SS, const float* __restrict__ XF,
                     const float* __restrict__ w_init, const float* __restrict__ w_root,
                     const float* __restrict__ arma_b, const float* __restrict__ emb,
                     f16* __restrict__ xt) {
    __shared__ float ssl[152];
    __shared__ float xfl[152];
    int tid = threadIdx.x;
    int bid = blockIdx.x;           // = b*100 + t
    int b = bid / 100, t = bid % 100;
    if (tid < 150) {
        int f = b*15000 + tid*100 + t;
        ssl[tid] = SS[f];
        xfl[tid] = XF[f];
    }
    __syncthreads();
    for (int e = tid; e < 4800; e += 256) {
        int n = e >> 5, c = e & 31;
        float pre = ssl[n]*w_init[c] + xfl[n]*w_root[c] + arma_b[c];
        float g = 0.5f * pre * (1.0f + erff(pre * 0.70710678118654752f));
        xt[(size_t)bid*4800 + e] = (f16)(g + emb[e]);
    }
}

// ---------------- f16 MFMA GEMM: C[M,N] = A[M,K] @ B[N,K]^T + bias ----------------
// M,Npad multiples of 128; K multiple of 32. Stores only cols < nvalid.
__global__ void k_gemm_f16(const f16* __restrict__ A, const f16* __restrict__ Bm,
                           const float* __restrict__ bias, float* __restrict__ C,
                           int K, int ldc, int nvalid, int ntn) {
    __shared__ f16 As[128*32];
    __shared__ f16 Bs[128*32];
    int tid = threadIdx.x;
    int lane = tid & 63, wave = tid >> 6;
    int wm = wave >> 1, wn = wave & 1;
    int tm = blockIdx.x / ntn, tn = blockIdx.x % ntn;
    int m0 = tm * 128, n0 = tn * 128;
    int lrow = lane & 15, quad = lane >> 4;

    float4v acc[4][4];
    #pragma unroll
    for (int mi = 0; mi < 4; ++mi)
        #pragma unroll
        for (int ni = 0; ni < 4; ++ni)
            acc[mi][ni] = (float4v){0.f, 0.f, 0.f, 0.f};

    for (int k0 = 0; k0 < K; k0 += 32) {
        #pragma unroll
        for (int i = 0; i < 2; ++i) {
            int chunk = i*256 + tid;
            int row = chunk >> 2, cq = chunk & 3;
            int cbase = chunk & ~63;  // wave-uniform
            const f16* ga = A + (size_t)(m0+row)*K + k0 + cq*8;
            __builtin_amdgcn_global_load_lds((const AS1 void*)ga, (AS3 void*)(As + cbase*8), 16, 0, 0);
            const f16* gb = Bm + (size_t)(n0+row)*K + k0 + cq*8;
            __builtin_amdgcn_global_load_lds((const AS1 void*)gb, (AS3 void*)(Bs + cbase*8), 16, 0, 0);
        }
        __syncthreads();
        half8 aF[4], bF[4];
        #pragma unroll
        for (int mi = 0; mi < 4; ++mi)
            aF[mi] = *(const half8*)&As[(wm*64 + mi*16 + lrow)*32 + quad*8];
        #pragma unroll
        for (int ni = 0; ni < 4; ++ni)
            bF[ni] = *(const half8*)&Bs[(wn*64 + ni*16 + lrow)*32 + quad*8];
        #pragma unroll
        for (int mi = 0; mi < 4; ++mi)
            #pragma unroll
            for (int ni = 0; ni < 4; ++ni)
                acc[mi][ni] = __builtin_amdgcn_mfma_f32_16x16x32_f16(aF[mi], bF[ni], acc[mi][ni], 0, 0, 0);
        __syncthreads();
    }

    #pragma unroll
    for (int ni = 0; ni < 4; ++ni) {
        int gcol = n0 + wn*64 + ni*16 + lrow;
        if (gcol >= nvalid) continue;
        float bv = bias[gcol];
        #pragma unroll
        for (int mi = 0; mi < 4; ++mi) {
            int growb = m0 + wm*64 + mi*16 + quad*4;
            #pragma unroll
            for (int r = 0; r < 4; ++r)
                C[(size_t)(growb + r)*ldc + gcol] = acc[mi][ni][r] + bv;
        }
    }
}

// ---------------- GRU1: 8 groups x 32 blocks; group g = blockIdx&7 (XCD-local) ----------------
// All cross-block h exchange via RELAXED agent-scope atomics (no fences: an agent
// acquire/release fence on gfx950 emits buffer_inv/buffer_wbl2 — measured 43us/step).
// __syncthreads() drains vmcnt, so stores are at the coherence point before the
// counter increment; readers use atomic loads (bypass stale L1/L2).
__global__ void k_gru1(const float* __restrict__ xi1, const float* __restrict__ Wh1,
                       const float* __restrict__ bh1, float* __restrict__ hb0,
                       float* __restrict__ hb1, int* __restrict__ cnt) {
    __shared__ __align__(16) f16 Wsh[48*520];
    __shared__ __align__(16) float hs[4*520];
    __shared__ float ghs[4*48];
    __shared__ float xis[4*48];
    int tid = threadIdx.x;
    int g = blockIdx.x & 7;        // group ~ XCD (blockIdx%8 heuristic; perf-only)
    int j = blockIdx.x >> 3;       // hidden-block 0..31 -> hidden [16j,16j+16)
    int b0 = g * 4;

    // preload weights (rows: gate*512 + 16j + i), fp16 into LDS
    for (int idx = tid; idx < 48*512; idx += 256) {
        int rr = idx >> 9, k = idx & 511;
        int gate = rr >> 4, hi = (j << 4) + (rr & 15);
        Wsh[rr*520 + k] = (f16)Wh1[(size_t)(gate*512 + hi)*512 + k];
    }

    bool act = tid < 192;
    int rr = tid >> 2, bl = tid & 3;
    int grow = (rr >> 4)*512 + (j << 4) + (rr & 15);
    float bhv = 0.f;
    size_t xibase = 0;
    float xi_reg = 0.f;
    if (act) {
        bhv = bh1[grow];
        xibase = ((size_t)(b0 + bl) * 100) * 1536 + grow;
        xi_reg = xi1[xibase];  // t=0 prefetch
    }
    __syncthreads();

    int* mycnt = cnt + g * 64;  // 256B apart

    for (int t = 0; t < 100; ++t) {
        const float* cur = (t & 1) ? hb1 : hb0;
        float* nxt = (t & 1) ? hb0 : hb1;
        // stage h (4 batches x 512) via relaxed agent atomic loads (coherent)
        #pragma unroll
        for (int ii = 0; ii < 8; ++ii) {
            int idx = ii*256 + tid;            // 0..2047
            int bl2 = idx >> 9, k = idx & 511;
            float v = __hip_atomic_load(&cur[((size_t)(b0 + bl2) << 9) + k],
                                        __ATOMIC_RELAXED, __HIP_MEMORY_SCOPE_AGENT);
            hs[bl2*520 + k] = v;
        }
        if (act) xis[bl*48 + rr] = xi_reg;
        __syncthreads();

        if (act) {
            const f16* wrow = &Wsh[rr*520];
            const float* hrow = &hs[bl*520];
            float a0 = 0.f, a1 = 0.f, a2 = 0.f, a3 = 0.f;
            #pragma unroll 8
            for (int k = 0; k < 512; k += 8) {
                half8 w = *(const half8*)&wrow[k];
                float4v h0 = *(const float4v*)&hrow[k];
                float4v h1 = *(const float4v*)&hrow[k+4];
                a0 += (float)w[0]*h0[0]; a1 += (float)w[1]*h0[1];
                a2 += (float)w[2]*h0[2]; a3 += (float)w[3]*h0[3];
                a0 += (float)w[4]*h1[0]; a1 += (float)w[5]*h1[1];
                a2 += (float)w[6]*h1[2]; a3 += (float)w[7]*h1[3];
            }
            ghs[bl*48 + rr] = (a0 + a1) + (a2 + a3) + bhv;
            // prefetch next xi (immutable data)
            int tn = (t < 99) ? t + 1 : 99;
            xi_reg = xi1[xibase + (size_t)tn * 1536];
        }
        __syncthreads();

        if (tid < 64) {
            int bl2 = tid >> 4, i = tid & 15;
            float xr = xis[bl2*48 + i],      gr = ghs[bl2*48 + i];
            float xz = xis[bl2*48 + 16 + i], gz = ghs[bl2*48 + 16 + i];
            float xn = xis[bl2*48 + 32 + i], gn = ghs[bl2*48 + 32 + i];
            float r = sigmoidf_(xr + gr);
            float z = sigmoidf_(xz + gz);
            float n = tanhf(xn + r * gn);
            int kidx = (j << 4) + i;
            float hold = hs[bl2*520 + kidx];
            float hnew = (1.f - z) * n + z * hold;
            __hip_atomic_store(&nxt[((size_t)(b0 + bl2) << 9) + kidx], hnew,
                               __ATOMIC_RELAXED, __HIP_MEMORY_SCOPE_AGENT);
        }

        if (t < 99) {
            __syncthreads();   // drains vmcnt: all h stores at coherence point
            if (tid == 0) {
                __hip_atomic_fetch_add(mycnt, 1, __ATOMIC_RELAXED, __HIP_MEMORY_SCOPE_AGENT);
                int target = 32 * (t + 1);
                while (__hip_atomic_load(mycnt, __ATOMIC_RELAXED, __HIP_MEMORY_SCOPE_AGENT) < target)
                    __builtin_amdgcn_s_sleep(1);
            }
            __syncthreads();
        }
    }
}

// ---------------- u[b,t,k] = h_end[b, (t*512+k)/100]  (repeat_interleave quirk) ----------------
__global__ void k_build_u(const float* __restrict__ hend, f16* __restrict__ u) {
    int idx = blockIdx.x * blockDim.x + threadIdx.x;
    if (idx >= 32*100*512) return;
    int b = idx / 51200;
    int r = idx % 51200;
    int t = r >> 9, k = r & 511;
    u[idx] = (f16)hend[(b << 9) + ((t*512 + k) / 100)];
}

// ---------------- GRU2: one block per batch, Wh2 register-resident ----------------
__global__ void k_gru2(const float* __restrict__ xi2p, const float* __restrict__ Wh2,
                       const float* __restrict__ bh2, f16* __restrict__ decb) {
    __shared__ float hs2[160];
    __shared__ float ghs2[456];
    __shared__ float xis2[456];
    int tid = threadIdx.x;
    int b = blockIdx.x;
    half2v w2[150];
    float bh_lo = 0.f, bh_hi = 0.f;
    if (tid < 225) {
        #pragma unroll
        for (int k = 0; k < 150; ++k) {
            half2v wv;
            wv[0] = (f16)Wh2[tid*150 + k];
            wv[1] = (f16)Wh2[(tid + 225)*150 + k];
            w2[k] = wv;
        }
        bh_lo = bh2[tid];
        bh_hi = bh2[tid + 225];
    }
    if (tid < 150) hs2[tid] = 0.f;
    size_t row0 = (size_t)b * 100 * 512;
    float xr1 = xi2p[row0 + tid];
    float xr2 = (tid + 256 < 450) ? xi2p[row0 + tid + 256] : 0.f;
    __syncthreads();

    for (int t = 0; t < 100; ++t) {
        if (tid < 450) xis2[tid] = xr1;
        if (tid + 256 < 450) xis2[tid + 256] = xr2;
        __syncthreads();
        if (tid < 225) {
            float alo = bh_lo, ahi = bh_hi;
            #pragma unroll
            for (int k = 0; k < 150; ++k) {
                float hk = hs2[k];
                alo += (float)w2[k][0] * hk;
                ahi += (float)w2[k][1] * hk;
            }
            ghs2[tid] = alo;
            ghs2[tid + 225] = ahi;
        }
        // prefetch next xi row
        int tn = (t < 99) ? t + 1 : 99;
        size_t nrow = ((size_t)b * 100 + tn) * 512;
        xr1 = xi2p[nrow + tid];
        xr2 = (tid + 256 < 450) ? xi2p[nrow + tid + 256] : 0.f;
        __syncthreads();
        if (tid < 150) {
            int i = tid;
            float r = sigmoidf_(xis2[i] + ghs2[i]);
            float z = sigmoidf_(xis2[150 + i] + ghs2[150 + i]);
            float n = tanhf(xis2[300 + i] + r * ghs2[300 + i]);
            float hnew = (1.f - z) * n + z * hs2[i];
            hs2[i] = hnew;
            decb[((size_t)b*100 + t)*160 + i] = (f16)hnew;
        }
        __syncthreads();
    }
}

// ---------------- launch ----------------
extern "C" void kernel_launch(void* const* d_in, const int* in_sizes, int n_in,
                              void* d_out, int out_size, void* d_ws, size_t ws_size,
                              hipStream_t stream) {
    const float* window = (const float*)d_in[0];
    const float* emb    = (const float*)d_in[1];
    const float* w_init = (const float*)d_in[2];
    const float* w_root = (const float*)d_in[3];
    const float* arma_b = (const float*)d_in[4];
    const float* Wi1    = (const float*)d_in[5];
    const float* Wh1    = (const float*)d_in[6];
    const float* bi1    = (const float*)d_in[7];
    const float* bh1    = (const float*)d_in[8];
    const float* Wi2    = (const float*)d_in[9];
    const float* Wh2    = (const float*)d_in[10];
    const float* bi2    = (const float*)d_in[11];
    const float* bh2    = (const float*)d_in[12];
    const float* W_fc   = (const float*)d_in[13];
    const float* b_fc   = (const float*)d_in[14];
    float* out = (float*)d_out;

    char* ws = (char*)d_ws;
    float* MT   = (float*)(ws + OFF_MT);
    int*   CNT  = (int*)  (ws + OFF_CNT);
    float* DEG  = (float*)(ws + OFF_DEG);
    float* HB0  = (float*)(ws + OFF_HB0);
    float* HB1  = (float*)(ws + OFF_HB1);
    f16*   WI2P = (f16*)  (ws + OFF_WI2P);
    f16*   WFCP = (f16*)  (ws + OFF_WFCP);
    f16*   DECB = (f16*)  (ws + OFF_DECB);
    float* WN   = (float*)(ws + OFF_WN);
    int*   EDST = (int*)  (ws + OFF_EDST);
    float* EVAL = (float*)(ws + OFF_EVAL);
    float* XF   = (float*)(ws + OFF_XF);
    float* SS   = (float*)(ws + OFF_SS);
    f16*   XT   = (f16*)  (ws + OFF_XT);
    f16*   WI1H = (f16*)  (ws + OFF_WI1H);
    float* XI1  = (float*)(ws + OFF_XI1);
    f16*   UB   = (f16*)  (ws + OFF_U);
    float* XI2P = (float*)(ws + OFF_XI2P);

    // zero the zone (MT scatter target, barrier counters, deg, h buffers, padded weights, dec)
    hipMemsetAsync(d_ws, 0, ZONE_END, stream);

    // graph build
    k_norm<<<1, 256, 0, stream>>>(emb, WN);
    k_topk<<<150, 256, 0, stream>>>(WN, EDST, EVAL, DEG);
    k_finalize<<<1, 256, 0, stream>>>(EDST, EVAL, DEG, MT);

    // weight conversions
    {
        long long n1 = (long long)1536*4800;
        k_cvt_pad<<<(unsigned)((n1 + 255)/256), 256, 0, stream>>>(Wi1, WI1H, 1536, 4800, 4800);
        long long n2 = (long long)450*512;
        k_cvt_pad<<<(unsigned)((n2 + 255)/256), 256, 0, stream>>>(Wi2, WI2P, 450, 512, 512);
        long long n3 = (long long)150*150;
        k_cvt_pad<<<(unsigned)((n3 + 255)/256), 256, 0, stream>>>(W_fc, WFCP, 150, 150, 160);
    }

    // x in row layout, scrambled aggregation, epilogue -> xt (f16)
    k_perm<<<(480000 + 255)/256, 256, 0, stream>>>(window, XF);
    k_conv<<<3200, 256, 0, stream>>>(XF, MT, SS);
    k_xt<<<3200, 256, 0, stream>>>(SS, XF, w_init, w_root, arma_b, emb, XT);

    // xi1 = xt @ Wi1^T + bi1   [3200 x 1536]
    k_gemm_f16<<<25*12, 256, 0, stream>>>(XT, WI1H, bi1, XI1, 4800, 1536, 1536, 12);

    // GRU1 scan -> h_end in HB0
    k_gru1<<<256, 256, 0, stream>>>(XI1, Wh1, bh1, HB0, HB1, CNT);

    // u (repeat_interleave quirk), f16
    k_build_u<<<(32*100*512 + 255)/256, 256, 0, stream>>>(HB0, UB);

    // xi2 = u @ Wi2^T + bi2   [3200 x 450] (padded to 512)
    k_gemm_f16<<<25*4, 256, 0, stream>>>(UB, WI2P, bi2, XI2P, 512, 512, 450, 4);

    // GRU2 scan -> dec (f16, padded K=160)
    k_gru2<<<32, 256, 0, stream>>>(XI2P, Wh2, bh2, DECB);

    // out = dec @ W_fc^T + b_fc  -> directly into d_out [3200 x 150]
    k_gemm_f16<<<25*2, 256, 0, stream>>>(DECB, WFCP, b_fc, out, 160, 150, 150, 2);

    (void)in_sizes; (void)n_in; (void)out_size; (void)ws_size;
}

// Round 4
// 1338.065 us; speedup vs baseline: 4.7796x; 2.2394x over previous
//
#include <hip/hip_runtime.h>
#include <hip/hip_fp16.h>
#include <math.h>

typedef _Float16 f16;
typedef _Float16 half8 __attribute__((ext_vector_type(8)));
typedef _Float16 half2v __attribute__((ext_vector_type(2)));
typedef float float4v __attribute__((ext_vector_type(4)));
typedef float float2v __attribute__((ext_vector_type(2)));

#define AS1 __attribute__((address_space(1)))
#define AS3 __attribute__((address_space(3)))

// ---------------- workspace layout ----------------
constexpr size_t alup(size_t x){ return (x + 255) & ~(size_t)255; }
constexpr size_t OFF_MT   = 0;                                    // 150*150 fp32 (zeroed)
constexpr size_t OFF_CNT  = alup(OFF_MT + 150*150*4);             // 8 barrier counters, 256B apart (zeroed)
constexpr size_t OFF_DEG  = alup(OFF_CNT + 8*256);                // 150 fp32 (zeroed)
constexpr size_t OFF_HB0  = alup(OFF_DEG + 150*4);                // 32*512 fp32 (zeroed)
constexpr size_t OFF_HB1  = alup(OFF_HB0 + 32*512*4);             // 32*512 fp32 (zeroed)
constexpr size_t OFF_WI2P = alup(OFF_HB1 + 32*512*4);             // 512*512 f16 padded (zeroed)
constexpr size_t OFF_WFCP = alup(OFF_WI2P + (size_t)512*512*2);   // 256*160 f16 padded (zeroed)
constexpr size_t OFF_DECB = alup(OFF_WFCP + (size_t)256*160*2);   // 3200*160 f16 (zeroed)
constexpr size_t ZONE_END = alup(OFF_DECB + (size_t)3200*160*2);
constexpr size_t OFF_WN   = ZONE_END;                             // 150*32 fp32
constexpr size_t OFF_EDST = alup(OFF_WN + 4800*4);                // 1500 int
constexpr size_t OFF_EVAL = alup(OFF_EDST + 1500*4);              // 1500 fp32
constexpr size_t OFF_XF   = alup(OFF_EVAL + 1500*4);              // 480000 fp32 (x in row layout)
constexpr size_t OFF_SS   = alup(OFF_XF + (size_t)480000*4);      // 480000 fp32 (agg scalar)
constexpr size_t OFF_XT   = alup(OFF_SS + (size_t)480000*4);      // 3200*4800 f16
constexpr size_t OFF_WI1H = alup(OFF_XT + (size_t)3200*4800*2);   // 1536*4800 f16
constexpr size_t OFF_XI1  = alup(OFF_WI1H + (size_t)1536*4800*2); // 3200*1536 fp32
constexpr size_t OFF_U    = alup(OFF_XI1 + (size_t)3200*1536*4);  // 3200*512 f16
constexpr size_t OFF_XI2P = alup(OFF_U + (size_t)3200*512*2);     // 3200*512 fp32

static __device__ __forceinline__ float sigmoidf_(float x){ return 1.0f/(1.0f+expf(-x)); }

// ---------------- graph construction ----------------
__global__ void k_norm(const float* __restrict__ emb, float* __restrict__ WN) {
    int n = threadIdx.x;
    if (n < 150) {
        float s = 0.f;
        #pragma unroll
        for (int c = 0; c < 32; ++c) { float v = emb[n*32+c]; s += v*v; }
        float nrm = fmaxf(sqrtf(s), 1e-8f);
        float inv = 1.0f / nrm;
        #pragma unroll
        for (int c = 0; c < 32; ++c) WN[n*32+c] = emb[n*32+c] * inv;
    }
}

__global__ void k_topk(const float* __restrict__ WN, int* __restrict__ EDST,
                       float* __restrict__ EVAL, float* __restrict__ DEG) {
    __shared__ float WnT[32*152];
    __shared__ float As[160];
    int tid = threadIdx.x;
    int i = blockIdx.x;  // row
    for (int idx = tid; idx < 4800; idx += 256) {
        int jj = idx >> 5, c = idx & 31;
        WnT[c*152 + jj] = WN[idx];
    }
    __syncthreads();
    int j = tid;
    if (j < 150) {
        float a = 0.f;
        #pragma unroll
        for (int c = 0; c < 32; ++c) a += WnT[c*152 + i] * WnT[c*152 + j];
        a = (j == i) ? 0.f : fmaxf(a, 0.f);
        As[j] = a;
    }
    __syncthreads();
    if (j < 150) {
        float aj = As[j];
        int cnt = 0;
        for (int m = 0; m < 150; ++m) {
            float am = As[m];
            cnt += (am > aj) || (am == aj && m < j);
        }
        if (cnt < 10) {
            EDST[i*10 + cnt] = j;
            EVAL[i*10 + cnt] = aj;
            atomicAdd(&DEG[j], aj);
        }
    }
}

__global__ void k_finalize(const int* __restrict__ EDST, const float* __restrict__ EVAL,
                           const float* __restrict__ DEG, float* __restrict__ MT) {
    __shared__ float dinv[160];
    int tid = threadIdx.x;
    if (tid < 150) {
        float d = DEG[tid];
        dinv[tid] = (d > 0.f) ? rsqrtf(d) : 0.f;
    }
    __syncthreads();
    for (int e = tid; e < 1500; e += 256) {
        int src = e / 10;
        int dst = EDST[e];
        MT[src*150 + dst] = dinv[src] * EVAL[e] * dinv[dst];
    }
}

// ---------------- fp32 -> f16 (with optional row padding) ----------------
__global__ void k_cvt_pad(const float* __restrict__ src, f16* __restrict__ dst,
                          int rows, int cols, int ldd) {
    long long idx = (long long)blockIdx.x * blockDim.x + threadIdx.x;
    long long n = (long long)rows * cols;
    if (idx >= n) return;
    if (ldd == cols) {
        dst[idx] = (f16)src[idx];
    } else {
        int r = (int)(idx / cols), c = (int)(idx % cols);
        dst[(size_t)r*ldd + c] = (f16)src[idx];
    }
}

// ---------------- x row-layout permute: XF[b*15000 + n*100 + t] = window[b,t,n] ----------------
__global__ void k_perm(const float* __restrict__ window, float* __restrict__ XF) {
    int idx = blockIdx.x * blockDim.x + threadIdx.x;   // source index (b*100+t)*150+n
    if (idx >= 480000) return;
    float v = window[idx];
    int b = idx / 15000;
    int r = idx % 15000;
    int t = r / 150, n = r % 150;
    XF[b*15000 + n*100 + t] = v;
}

// ---------------- scrambled ARMA aggregation: per contiguous 150-chunk of XF ----------------
// SS[base + j] = sum_i MT[i,j] * XF[base + i],  base = chunk*150
__global__ void k_conv(const float* __restrict__ XF, const float* __restrict__ MT,
                       float* __restrict__ SS) {
    __shared__ float xs[152];
    int tid = threadIdx.x;
    int base = blockIdx.x * 150;
    if (tid < 150) xs[tid] = XF[base + tid];
    __syncthreads();
    if (tid < 150) {
        float s = 0.f;
        for (int m = 0; m < 150; ++m) s += MT[m*150 + tid] * xs[m];
        SS[base + tid] = s;
    }
}

// ---------------- epilogue: gelu(SS*wi + XF*wr + b) + emb -> xt (f16) ----------------
// xt[(b*100+t)*150 + n][c], reading SS/XF at f = b*15000 + n*100 + t
__global__ void k_xt(const float* __restrict__ SS, const float* __restrict__ XF,
                     const float* __restrict__ w_init, const float* __restrict__ w_root,
                     const float* __restrict__ arma_b, const float* __restrict__ emb,
                     f16* __restrict__ xt) {
    __shared__ float ssl[152];
    __shared__ float xfl[152];
    int tid = threadIdx.x;
    int bid = blockIdx.x;           // = b*100 + t
    int b = bid / 100, t = bid % 100;
    if (tid < 150) {
        int f = b*15000 + tid*100 + t;
        ssl[tid] = SS[f];
        xfl[tid] = XF[f];
    }
    __syncthreads();
    for (int e = tid; e < 4800; e += 256) {
        int n = e >> 5, c = e & 31;
        float pre = ssl[n]*w_init[c] + xfl[n]*w_root[c] + arma_b[c];
        float g = 0.5f * pre * (1.0f + erff(pre * 0.70710678118654752f));
        xt[(size_t)bid*4800 + e] = (f16)(g + emb[e]);
    }
}

// ---------------- f16 MFMA GEMM: C[M,N] = A[M,K] @ B[N,K]^T + bias ----------------
// M,Npad multiples of 128; K multiple of 32. Stores only cols < nvalid.
__global__ void k_gemm_f16(const f16* __restrict__ A, const f16* __restrict__ Bm,
                           const float* __restrict__ bias, float* __restrict__ C,
                           int K, int ldc, int nvalid, int ntn) {
    __shared__ f16 As[128*32];
    __shared__ f16 Bs[128*32];
    int tid = threadIdx.x;
    int lane = tid & 63, wave = tid >> 6;
    int wm = wave >> 1, wn = wave & 1;
    int tm = blockIdx.x / ntn, tn = blockIdx.x % ntn;
    int m0 = tm * 128, n0 = tn * 128;
    int lrow = lane & 15, quad = lane >> 4;

    float4v acc[4][4];
    #pragma unroll
    for (int mi = 0; mi < 4; ++mi)
        #pragma unroll
        for (int ni = 0; ni < 4; ++ni)
            acc[mi][ni] = (float4v){0.f, 0.f, 0.f, 0.f};

    for (int k0 = 0; k0 < K; k0 += 32) {
        #pragma unroll
        for (int i = 0; i < 2; ++i) {
            int chunk = i*256 + tid;
            int row = chunk >> 2, cq = chunk & 3;
            int cbase = chunk & ~63;  // wave-uniform
            const f16* ga = A + (size_t)(m0+row)*K + k0 + cq*8;
            __builtin_amdgcn_global_load_lds((const AS1 void*)ga, (AS3 void*)(As + cbase*8), 16, 0, 0);
            const f16* gb = Bm + (size_t)(n0+row)*K + k0 + cq*8;
            __builtin_amdgcn_global_load_lds((const AS1 void*)gb, (AS3 void*)(Bs + cbase*8), 16, 0, 0);
        }
        __syncthreads();
        half8 aF[4], bF[4];
        #pragma unroll
        for (int mi = 0; mi < 4; ++mi)
            aF[mi] = *(const half8*)&As[(wm*64 + mi*16 + lrow)*32 + quad*8];
        #pragma unroll
        for (int ni = 0; ni < 4; ++ni)
            bF[ni] = *(const half8*)&Bs[(wn*64 + ni*16 + lrow)*32 + quad*8];
        #pragma unroll
        for (int mi = 0; mi < 4; ++mi)
            #pragma unroll
            for (int ni = 0; ni < 4; ++ni)
                acc[mi][ni] = __builtin_amdgcn_mfma_f32_16x16x32_f16(aF[mi], bF[ni], acc[mi][ni], 0, 0, 0);
        __syncthreads();
    }

    #pragma unroll
    for (int ni = 0; ni < 4; ++ni) {
        int gcol = n0 + wn*64 + ni*16 + lrow;
        if (gcol >= nvalid) continue;
        float bv = bias[gcol];
        #pragma unroll
        for (int mi = 0; mi < 4; ++mi) {
            int growb = m0 + wm*64 + mi*16 + quad*4;
            #pragma unroll
            for (int r = 0; r < 4; ++r)
                C[(size_t)(growb + r)*ldc + gcol] = acc[mi][ni][r] + bv;
        }
    }
}

// ---------------- GRU1: 8 groups x 32 blocks; group g = blockIdx&7 (XCD-local) ----------------
// All cross-block h exchange via RELAXED agent-scope atomics (no fences: an agent
// acquire/release fence on gfx950 emits buffer_inv/buffer_wbl2 — measured 43us/step).
__global__ void k_gru1(const float* __restrict__ xi1, const float* __restrict__ Wh1,
                       const float* __restrict__ bh1, float* __restrict__ hb0,
                       float* __restrict__ hb1, int* __restrict__ cnt) {
    __shared__ __align__(16) f16 Wsh[48*520];
    __shared__ __align__(16) float hs[4*520];
    __shared__ float ghs[4*48];
    __shared__ float xis[4*48];
    int tid = threadIdx.x;
    int g = blockIdx.x & 7;        // group ~ XCD (blockIdx%8 heuristic; perf-only)
    int j = blockIdx.x >> 3;       // hidden-block 0..31 -> hidden [16j,16j+16)
    int b0 = g * 4;

    // preload weights (rows: gate*512 + 16j + i), fp16 into LDS
    for (int idx = tid; idx < 48*512; idx += 256) {
        int rr = idx >> 9, k = idx & 511;
        int gate = rr >> 4, hi = (j << 4) + (rr & 15);
        Wsh[rr*520 + k] = (f16)Wh1[(size_t)(gate*512 + hi)*512 + k];
    }

    bool act = tid < 192;
    int rr = tid >> 2, bl = tid & 3;
    int grow = (rr >> 4)*512 + (j << 4) + (rr & 15);
    float bhv = 0.f;
    size_t xibase = 0;
    float xi_reg = 0.f;
    if (act) {
        bhv = bh1[grow];
        xibase = ((size_t)(b0 + bl) * 100) * 1536 + grow;
        xi_reg = xi1[xibase];  // t=0 prefetch
    }
    __syncthreads();

    int* mycnt = cnt + g * 64;  // 256B apart

    for (int t = 0; t < 100; ++t) {
        const float* cur = (t & 1) ? hb1 : hb0;
        float* nxt = (t & 1) ? hb0 : hb1;
        // stage h (4 batches x 512) via relaxed agent atomic loads (coherent)
        #pragma unroll
        for (int ii = 0; ii < 8; ++ii) {
            int idx = ii*256 + tid;            // 0..2047
            int bl2 = idx >> 9, k = idx & 511;
            float v = __hip_atomic_load(&cur[((size_t)(b0 + bl2) << 9) + k],
                                        __ATOMIC_RELAXED, __HIP_MEMORY_SCOPE_AGENT);
            hs[bl2*520 + k] = v;
        }
        if (act) xis[bl*48 + rr] = xi_reg;
        __syncthreads();

        if (act) {
            const f16* wrow = &Wsh[rr*520];
            const float* hrow = &hs[bl*520];
            float a0 = 0.f, a1 = 0.f, a2 = 0.f, a3 = 0.f;
            #pragma unroll 8
            for (int k = 0; k < 512; k += 8) {
                half8 w = *(const half8*)&wrow[k];
                float4v h0 = *(const float4v*)&hrow[k];
                float4v h1 = *(const float4v*)&hrow[k+4];
                a0 += (float)w[0]*h0[0]; a1 += (float)w[1]*h0[1];
                a2 += (float)w[2]*h0[2]; a3 += (float)w[3]*h0[3];
                a0 += (float)w[4]*h1[0]; a1 += (float)w[5]*h1[1];
                a2 += (float)w[6]*h1[2]; a3 += (float)w[7]*h1[3];
            }
            ghs[bl*48 + rr] = (a0 + a1) + (a2 + a3) + bhv;
            // prefetch next xi (immutable data)
            int tn = (t < 99) ? t + 1 : 99;
            xi_reg = xi1[xibase + (size_t)tn * 1536];
        }
        __syncthreads();

        if (tid < 64) {
            int bl2 = tid >> 4, i = tid & 15;
            float xr = xis[bl2*48 + i],      gr = ghs[bl2*48 + i];
            float xz = xis[bl2*48 + 16 + i], gz = ghs[bl2*48 + 16 + i];
            float xn = xis[bl2*48 + 32 + i], gn = ghs[bl2*48 + 32 + i];
            float r = sigmoidf_(xr + gr);
            float z = sigmoidf_(xz + gz);
            float n = tanhf(xn + r * gn);
            int kidx = (j << 4) + i;
            float hold = hs[bl2*520 + kidx];
            float hnew = (1.f - z) * n + z * hold;
            __hip_atomic_store(&nxt[((size_t)(b0 + bl2) << 9) + kidx], hnew,
                               __ATOMIC_RELAXED, __HIP_MEMORY_SCOPE_AGENT);
        }

        if (t < 99) {
            __syncthreads();   // drains vmcnt: all h stores at coherence point
            if (tid == 0) {
                __hip_atomic_fetch_add(mycnt, 1, __ATOMIC_RELAXED, __HIP_MEMORY_SCOPE_AGENT);
                int target = 32 * (t + 1);
                while (__hip_atomic_load(mycnt, __ATOMIC_RELAXED, __HIP_MEMORY_SCOPE_AGENT) < target)
                    __builtin_amdgcn_s_sleep(1);
            }
            __syncthreads();
        }
    }
}

// ---------------- u[b,t,k] = h_end[b, (t*512+k)/100]  (repeat_interleave quirk) ----------------
__global__ void k_build_u(const float* __restrict__ hend, f16* __restrict__ u) {
    int idx = blockIdx.x * blockDim.x + threadIdx.x;
    if (idx >= 32*100*512) return;
    int b = idx / 51200;
    int r = idx % 51200;
    int t = r >> 9, k = r & 511;
    u[idx] = (f16)hend[(b << 9) + ((t*512 + k) / 100)];
}

// ---------------- GRU2: one block per batch, 512 threads, one output row per thread ----------------
// Weights register-resident: 75 packed half2 per thread (~105 VGPR). __launch_bounds__(512,2)
// gives a 256-VGPR budget — NO spill (round-3 failure: default bounds capped VGPR at 64 and
// spilled w2[150] to scratch -> 18us/step + 32ms first-use scratch penalty).
__global__ __launch_bounds__(512, 2)
void k_gru2(const float* __restrict__ xi2p, const float* __restrict__ Wh2,
            const float* __restrict__ bh2, f16* __restrict__ decb) {
    __shared__ float hs2[152];
    __shared__ float ghs2[456];
    __shared__ float xis2[456];
    int tid = threadIdx.x;
    int b = blockIdx.x;
    bool act = tid < 450;
    half2v w[75];
    float bhv = 0.f;
    if (act) {
        const float2v* wrow = (const float2v*)&Wh2[tid*150];
        #pragma unroll
        for (int k = 0; k < 75; ++k) {
            float2v p = wrow[k];
            half2v wv; wv[0] = (f16)p[0]; wv[1] = (f16)p[1];
            w[k] = wv;
        }
        bhv = bh2[tid];
    }
    if (tid < 152) hs2[tid] = 0.f;
    size_t row0 = (size_t)b * 100 * 512;
    float xr = act ? xi2p[row0 + tid] : 0.f;
    __syncthreads();

    for (int t = 0; t < 100; ++t) {
        if (act) xis2[tid] = xr;
        __syncthreads();
        if (act) {
            float a = bhv;
            #pragma unroll
            for (int k = 0; k < 75; ++k) {
                a += (float)w[k][0] * hs2[2*k] + (float)w[k][1] * hs2[2*k+1];
            }
            ghs2[tid] = a;
        }
        // prefetch next xi row (immutable)
        int tn = (t < 99) ? t + 1 : 99;
        if (act) xr = xi2p[((size_t)b*100 + tn)*512 + tid];
        __syncthreads();
        if (tid < 150) {
            int i = tid;
            float r = sigmoidf_(xis2[i] + ghs2[i]);
            float z = sigmoidf_(xis2[150 + i] + ghs2[150 + i]);
            float n = tanhf(xis2[300 + i] + r * ghs2[300 + i]);
            float hnew = (1.f - z) * n + z * hs2[i];
            hs2[i] = hnew;
            decb[((size_t)b*100 + t)*160 + i] = (f16)hnew;
        }
        __syncthreads();
    }
}

// ---------------- launch ----------------
extern "C" void kernel_launch(void* const* d_in, const int* in_sizes, int n_in,
                              void* d_out, int out_size, void* d_ws, size_t ws_size,
                              hipStream_t stream) {
    const float* window = (const float*)d_in[0];
    const float* emb    = (const float*)d_in[1];
    const float* w_init = (const float*)d_in[2];
    const float* w_root = (const float*)d_in[3];
    const float* arma_b = (const float*)d_in[4];
    const float* Wi1    = (const float*)d_in[5];
    const float* Wh1    = (const float*)d_in[6];
    const float* bi1    = (const float*)d_in[7];
    const float* bh1    = (const float*)d_in[8];
    const float* Wi2    = (const float*)d_in[9];
    const float* Wh2    = (const float*)d_in[10];
    const float* bi2    = (const float*)d_in[11];
    const float* bh2    = (const float*)d_in[12];
    const float* W_fc   = (const float*)d_in[13];
    const float* b_fc   = (const float*)d_in[14];
    float* out = (float*)d_out;

    char* ws = (char*)d_ws;
    float* MT   = (float*)(ws + OFF_MT);
    int*   CNT  = (int*)  (ws + OFF_CNT);
    float* DEG  = (float*)(ws + OFF_DEG);
    float* HB0  = (float*)(ws + OFF_HB0);
    float* HB1  = (float*)(ws + OFF_HB1);
    f16*   WI2P = (f16*)  (ws + OFF_WI2P);
    f16*   WFCP = (f16*)  (ws + OFF_WFCP);
    f16*   DECB = (f16*)  (ws + OFF_DECB);
    float* WN   = (float*)(ws + OFF_WN);
    int*   EDST = (int*)  (ws + OFF_EDST);
    float* EVAL = (float*)(ws + OFF_EVAL);
    float* XF   = (float*)(ws + OFF_XF);
    float* SS   = (float*)(ws + OFF_SS);
    f16*   XT   = (f16*)  (ws + OFF_XT);
    f16*   WI1H = (f16*)  (ws + OFF_WI1H);
    float* XI1  = (float*)(ws + OFF_XI1);
    f16*   UB   = (f16*)  (ws + OFF_U);
    float* XI2P = (float*)(ws + OFF_XI2P);

    // zero the zone (MT scatter target, barrier counters, deg, h buffers, padded weights, dec)
    hipMemsetAsync(d_ws, 0, ZONE_END, stream);

    // graph build
    k_norm<<<1, 256, 0, stream>>>(emb, WN);
    k_topk<<<150, 256, 0, stream>>>(WN, EDST, EVAL, DEG);
    k_finalize<<<1, 256, 0, stream>>>(EDST, EVAL, DEG, MT);

    // weight conversions
    {
        long long n1 = (long long)1536*4800;
        k_cvt_pad<<<(unsigned)((n1 + 255)/256), 256, 0, stream>>>(Wi1, WI1H, 1536, 4800, 4800);
        long long n2 = (long long)450*512;
        k_cvt_pad<<<(unsigned)((n2 + 255)/256), 256, 0, stream>>>(Wi2, WI2P, 450, 512, 512);
        long long n3 = (long long)150*150;
        k_cvt_pad<<<(unsigned)((n3 + 255)/256), 256, 0, stream>>>(W_fc, WFCP, 150, 150, 160);
    }

    // x in row layout, scrambled aggregation, epilogue -> xt (f16)
    k_perm<<<(480000 + 255)/256, 256, 0, stream>>>(window, XF);
    k_conv<<<3200, 256, 0, stream>>>(XF, MT, SS);
    k_xt<<<3200, 256, 0, stream>>>(SS, XF, w_init, w_root, arma_b, emb, XT);

    // xi1 = xt @ Wi1^T + bi1   [3200 x 1536]
    k_gemm_f16<<<25*12, 256, 0, stream>>>(XT, WI1H, bi1, XI1, 4800, 1536, 1536, 12);

    // GRU1 scan -> h_end in HB0
    k_gru1<<<256, 256, 0, stream>>>(XI1, Wh1, bh1, HB0, HB1, CNT);

    // u (repeat_interleave quirk), f16
    k_build_u<<<(32*100*512 + 255)/256, 256, 0, stream>>>(HB0, UB);

    // xi2 = u @ Wi2^T + bi2   [3200 x 450] (padded to 512)
    k_gemm_f16<<<25*4, 256, 0, stream>>>(UB, WI2P, bi2, XI2P, 512, 512, 450, 4);

    // GRU2 scan -> dec (f16, padded K=160)
    k_gru2<<<32, 512, 0, stream>>>(XI2P, Wh2, bh2, DECB);

    // out = dec @ W_fc^T + b_fc  -> directly into d_out [3200 x 150]
    k_gemm_f16<<<25*2, 256, 0, stream>>>(DECB, WFCP, b_fc, out, 160, 150, 150, 2);

    (void)in_sizes; (void)n_in; (void)out_size; (void)ws_size;
}

// Round 5
// 965.063 us; speedup vs baseline: 6.6270x; 1.3865x over previous
//
#include <hip/hip_runtime.h>
#include <hip/hip_fp16.h>
#include <math.h>

typedef _Float16 f16;
typedef _Float16 half8 __attribute__((ext_vector_type(8)));
typedef _Float16 half2v __attribute__((ext_vector_type(2)));
typedef float float4v __attribute__((ext_vector_type(4)));
typedef float float2v __attribute__((ext_vector_type(2)));

#define AS1 __attribute__((address_space(1)))
#define AS3 __attribute__((address_space(3)))

// ---------------- workspace layout ----------------
constexpr size_t alup(size_t x){ return (x + 255) & ~(size_t)255; }
constexpr size_t OFF_MT   = 0;                                    // 150*150 fp32 (zeroed)
constexpr size_t OFF_CNT  = alup(OFF_MT + 150*150*4);             // 256 flags, 256B apart (zeroed)
constexpr size_t OFF_DEG  = alup(OFF_CNT + 256*256);              // 150 fp32 (zeroed)
constexpr size_t OFF_HB0  = alup(OFF_DEG + 150*4);                // 32*512 fp32 (zeroed)
constexpr size_t OFF_HB1  = alup(OFF_HB0 + 32*512*4);             // 32*512 fp32 (zeroed)
constexpr size_t OFF_WI2P = alup(OFF_HB1 + 32*512*4);             // 512*512 f16 padded (zeroed)
constexpr size_t OFF_WFCP = alup(OFF_WI2P + (size_t)512*512*2);   // 256*160 f16 padded (zeroed)
constexpr size_t OFF_DECB = alup(OFF_WFCP + (size_t)256*160*2);   // 3200*160 f16 (zeroed)
constexpr size_t ZONE_END = alup(OFF_DECB + (size_t)3200*160*2);
constexpr size_t OFF_WN   = ZONE_END;                             // 150*32 fp32
constexpr size_t OFF_EDST = alup(OFF_WN + 4800*4);                // 1500 int
constexpr size_t OFF_EVAL = alup(OFF_EDST + 1500*4);              // 1500 fp32
constexpr size_t OFF_XF   = alup(OFF_EVAL + 1500*4);              // 480000 fp32 (x in row layout)
constexpr size_t OFF_SS   = alup(OFF_XF + (size_t)480000*4);      // 480000 fp32 (agg scalar)
constexpr size_t OFF_XT   = alup(OFF_SS + (size_t)480000*4);      // 3200*4800 f16
constexpr size_t OFF_WI1H = alup(OFF_XT + (size_t)3200*4800*2);   // 1536*4800 f16
constexpr size_t OFF_XI1  = alup(OFF_WI1H + (size_t)1536*4800*2); // 3200*1536 fp32
constexpr size_t OFF_U    = alup(OFF_XI1 + (size_t)3200*1536*4);  // 3200*512 f16
constexpr size_t OFF_XI2P = alup(OFF_U + (size_t)3200*512*2);     // 3200*512 fp32

static __device__ __forceinline__ float sigmoidf_(float x){ return 1.0f/(1.0f+expf(-x)); }

// ---------------- graph construction ----------------
__global__ void k_norm(const float* __restrict__ emb, float* __restrict__ WN) {
    int n = threadIdx.x;
    if (n < 150) {
        float s = 0.f;
        #pragma unroll
        for (int c = 0; c < 32; ++c) { float v = emb[n*32+c]; s += v*v; }
        float nrm = fmaxf(sqrtf(s), 1e-8f);
        float inv = 1.0f / nrm;
        #pragma unroll
        for (int c = 0; c < 32; ++c) WN[n*32+c] = emb[n*32+c] * inv;
    }
}

__global__ void k_topk(const float* __restrict__ WN, int* __restrict__ EDST,
                       float* __restrict__ EVAL, float* __restrict__ DEG) {
    __shared__ float WnT[32*152];
    __shared__ float As[160];
    int tid = threadIdx.x;
    int i = blockIdx.x;  // row
    for (int idx = tid; idx < 4800; idx += 256) {
        int jj = idx >> 5, c = idx & 31;
        WnT[c*152 + jj] = WN[idx];
    }
    __syncthreads();
    int j = tid;
    if (j < 150) {
        float a = 0.f;
        #pragma unroll
        for (int c = 0; c < 32; ++c) a += WnT[c*152 + i] * WnT[c*152 + j];
        a = (j == i) ? 0.f : fmaxf(a, 0.f);
        As[j] = a;
    }
    __syncthreads();
    if (j < 150) {
        float aj = As[j];
        int cnt = 0;
        for (int m = 0; m < 150; ++m) {
            float am = As[m];
            cnt += (am > aj) || (am == aj && m < j);
        }
        if (cnt < 10) {
            EDST[i*10 + cnt] = j;
            EVAL[i*10 + cnt] = aj;
            atomicAdd(&DEG[j], aj);
        }
    }
}

__global__ void k_finalize(const int* __restrict__ EDST, const float* __restrict__ EVAL,
                           const float* __restrict__ DEG, float* __restrict__ MT) {
    __shared__ float dinv[160];
    int tid = threadIdx.x;
    if (tid < 150) {
        float d = DEG[tid];
        dinv[tid] = (d > 0.f) ? rsqrtf(d) : 0.f;
    }
    __syncthreads();
    for (int e = tid; e < 1500; e += 256) {
        int src = e / 10;
        int dst = EDST[e];
        MT[src*150 + dst] = dinv[src] * EVAL[e] * dinv[dst];
    }
}

// ---------------- fp32 -> f16 (with optional row padding) ----------------
__global__ void k_cvt_pad(const float* __restrict__ src, f16* __restrict__ dst,
                          int rows, int cols, int ldd) {
    long long idx = (long long)blockIdx.x * blockDim.x + threadIdx.x;
    long long n = (long long)rows * cols;
    if (idx >= n) return;
    if (ldd == cols) {
        dst[idx] = (f16)src[idx];
    } else {
        int r = (int)(idx / cols), c = (int)(idx % cols);
        dst[(size_t)r*ldd + c] = (f16)src[idx];
    }
}

// ---------------- x row-layout permute: XF[b*15000 + n*100 + t] = window[b,t,n] ----------------
__global__ void k_perm(const float* __restrict__ window, float* __restrict__ XF) {
    int idx = blockIdx.x * blockDim.x + threadIdx.x;   // source index (b*100+t)*150+n
    if (idx >= 480000) return;
    float v = window[idx];
    int b = idx / 15000;
    int r = idx % 15000;
    int t = r / 150, n = r % 150;
    XF[b*15000 + n*100 + t] = v;
}

// ---------------- scrambled ARMA aggregation: per contiguous 150-chunk of XF ----------------
// SS[base + j] = sum_i MT[i,j] * XF[base + i],  base = chunk*150
__global__ void k_conv(const float* __restrict__ XF, const float* __restrict__ MT,
                       float* __restrict__ SS) {
    __shared__ float xs[152];
    int tid = threadIdx.x;
    int base = blockIdx.x * 150;
    if (tid < 150) xs[tid] = XF[base + tid];
    __syncthreads();
    if (tid < 150) {
        float s = 0.f;
        for (int m = 0; m < 150; ++m) s += MT[m*150 + tid] * xs[m];
        SS[base + tid] = s;
    }
}

// ---------------- epilogue: gelu(SS*wi + XF*wr + b) + emb -> xt (f16) ----------------
// xt[(b*100+t)*150 + n][c], reading SS/XF at f = b*15000 + n*100 + t
__global__ void k_xt(const float* __restrict__ SS, const float* __restrict__ XF,
                     const float* __restrict__ w_init, const float* __restrict__ w_root,
                     const float* __restrict__ arma_b, const float* __restrict__ emb,
                     f16* __restrict__ xt) {
    __shared__ float ssl[152];
    __shared__ float xfl[152];
    int tid = threadIdx.x;
    int bid = blockIdx.x;           // = b*100 + t
    int b = bid / 100, t = bid % 100;
    if (tid < 150) {
        int f = b*15000 + tid*100 + t;
        ssl[tid] = SS[f];
        xfl[tid] = XF[f];
    }
    __syncthreads();
    for (int e = tid; e < 4800; e += 256) {
        int n = e >> 5, c = e & 31;
        float pre = ssl[n]*w_init[c] + xfl[n]*w_root[c] + arma_b[c];
        float g = 0.5f * pre * (1.0f + erff(pre * 0.70710678118654752f));
        xt[(size_t)bid*4800 + e] = (f16)(g + emb[e]);
    }
}

// ---------------- f16 MFMA GEMM: C[M,N] = A[M,K] @ B[N,K]^T + bias ----------------
// M,Npad multiples of 128; K multiple of 32. Stores only cols < nvalid.
__global__ void k_gemm_f16(const f16* __restrict__ A, const f16* __restrict__ Bm,
                           const float* __restrict__ bias, float* __restrict__ C,
                           int K, int ldc, int nvalid, int ntn) {
    __shared__ f16 As[128*32];
    __shared__ f16 Bs[128*32];
    int tid = threadIdx.x;
    int lane = tid & 63, wave = tid >> 6;
    int wm = wave >> 1, wn = wave & 1;
    int tm = blockIdx.x / ntn, tn = blockIdx.x % ntn;
    int m0 = tm * 128, n0 = tn * 128;
    int lrow = lane & 15, quad = lane >> 4;

    float4v acc[4][4];
    #pragma unroll
    for (int mi = 0; mi < 4; ++mi)
        #pragma unroll
        for (int ni = 0; ni < 4; ++ni)
            acc[mi][ni] = (float4v){0.f, 0.f, 0.f, 0.f};

    for (int k0 = 0; k0 < K; k0 += 32) {
        #pragma unroll
        for (int i = 0; i < 2; ++i) {
            int chunk = i*256 + tid;
            int row = chunk >> 2, cq = chunk & 3;
            int cbase = chunk & ~63;  // wave-uniform
            const f16* ga = A + (size_t)(m0+row)*K + k0 + cq*8;
            __builtin_amdgcn_global_load_lds((const AS1 void*)ga, (AS3 void*)(As + cbase*8), 16, 0, 0);
            const f16* gb = Bm + (size_t)(n0+row)*K + k0 + cq*8;
            __builtin_amdgcn_global_load_lds((const AS1 void*)gb, (AS3 void*)(Bs + cbase*8), 16, 0, 0);
        }
        __syncthreads();
        half8 aF[4], bF[4];
        #pragma unroll
        for (int mi = 0; mi < 4; ++mi)
            aF[mi] = *(const half8*)&As[(wm*64 + mi*16 + lrow)*32 + quad*8];
        #pragma unroll
        for (int ni = 0; ni < 4; ++ni)
            bF[ni] = *(const half8*)&Bs[(wn*64 + ni*16 + lrow)*32 + quad*8];
        #pragma unroll
        for (int mi = 0; mi < 4; ++mi)
            #pragma unroll
            for (int ni = 0; ni < 4; ++ni)
                acc[mi][ni] = __builtin_amdgcn_mfma_f32_16x16x32_f16(aF[mi], bF[ni], acc[mi][ni], 0, 0, 0);
        __syncthreads();
    }

    #pragma unroll
    for (int ni = 0; ni < 4; ++ni) {
        int gcol = n0 + wn*64 + ni*16 + lrow;
        if (gcol >= nvalid) continue;
        float bv = bias[gcol];
        #pragma unroll
        for (int mi = 0; mi < 4; ++mi) {
            int growb = m0 + wm*64 + mi*16 + quad*4;
            #pragma unroll
            for (int r = 0; r < 4; ++r)
                C[(size_t)(growb + r)*ldc + gcol] = acc[mi][ni][r] + bv;
        }
    }
}

// ---------------- GRU1: 16 groups x 16 blocks; group g owns batches 2g,2g+1 ----------------
// Block j of group g owns hidden [32j,32j+32) (x3 gates x2 batches = 192 dots of 512).
// Cross-block exchange: producers store h via relaxed agent atomics (LLC-direct),
// drain with __syncthreads (emits vmcnt(0) before s_barrier), then set per-block
// flag = t+1. Consumers poll ONLY their producer's flag (fine-grained dataflow),
// then stage via one coherent global_load_dwordx4 sc0 sc1 (pipelined, 1 per thread).
// NO fences anywhere (agent fence = buffer_wbl2/inv storm, measured 43us/step in R2).
// NO counter RMW (32-way same-line fetch_add serialized at LLC in R3/R4).
__global__ __launch_bounds__(256, 1)
void k_gru1(const float* __restrict__ xi1, const float* __restrict__ Wh1,
            const float* __restrict__ bh1, float* __restrict__ hb0,
            float* __restrict__ hb1, int* __restrict__ cnt) {
    __shared__ __align__(16) f16 Wsh[96*520];    // 99.8 KB
    __shared__ __align__(16) float hs[2*520];
    __shared__ float ghs[2*96];
    __shared__ float xis[2*96];
    int tid = threadIdx.x;
    int g = blockIdx.x & 15;       // group (16 blocks, same XCD mod 8)
    int j = blockIdx.x >> 4;       // hidden-block 0..15 -> hidden [32j,32j+32)
    int b0 = g * 2;

    // preload weights: rows rr = gate*32 + i -> Wh1 row gate*512 + 32j + i
    for (int idx = tid; idx < 96*512; idx += 256) {
        int rr = idx >> 9, k = idx & 511;
        int gate = rr >> 5, hi = (j << 5) + (rr & 31);
        Wsh[rr*520 + k] = (f16)Wh1[(size_t)(gate*512 + hi)*512 + k];
    }

    bool act = tid < 192;
    int rr = tid >> 1, bl = tid & 1;            // row 0..95, batch 0..1
    int grow = (rr >> 5)*512 + (j << 5) + (rr & 31);
    float bhv = 0.f;
    size_t xibase = 0;
    float xi_reg = 0.f;
    if (act) {
        bhv = bh1[grow];
        xibase = ((size_t)(b0 + bl) * 100) * 1536 + grow;
        xi_reg = xi1[xibase];  // t=0 prefetch
    }
    // staging assignment: thread -> one dwordx4 of h
    int sbl = tid >> 7;            // batch 0..1
    int sk  = (tid & 127) << 2;    // k offset 0..508
    int jp  = sk >> 5;             // producer block of this chunk
    int* myflag = cnt + (g*16 + j ) * 64;   // 256B apart
    int* pflag  = cnt + (g*16 + jp) * 64;
    __syncthreads();

    for (int t = 0; t < 100; ++t) {
        const float* cur = (t & 1) ? hb1 : hb0;
        float* nxt = (t & 1) ? hb0 : hb1;
        // wait for this thread's producer, then stage 16B coherently
        if (t > 0) {
            while (__hip_atomic_load(pflag, __ATOMIC_RELAXED, __HIP_MEMORY_SCOPE_AGENT) < t)
                __builtin_amdgcn_s_sleep(1);
        }
        {
            const float* ga = cur + (((size_t)(b0 + sbl)) << 9) + sk;
            float4v v;
            asm volatile("global_load_dwordx4 %0, %1, off sc0 sc1\n\ts_waitcnt vmcnt(0)"
                         : "=v"(v) : "v"(ga) : "memory");
            *(float4v*)&hs[sbl*520 + sk] = v;
        }
        if (act) xis[bl*96 + rr] = xi_reg;
        __syncthreads();

        if (act) {
            const f16* wrow = &Wsh[rr*520];
            const float* hrow = &hs[bl*520];
            float a0 = 0.f, a1 = 0.f, a2 = 0.f, a3 = 0.f;
            #pragma unroll 8
            for (int k = 0; k < 512; k += 8) {
                half8 w = *(const half8*)&wrow[k];
                float4v h0 = *(const float4v*)&hrow[k];
                float4v h1 = *(const float4v*)&hrow[k+4];
                a0 += (float)w[0]*h0[0]; a1 += (float)w[1]*h0[1];
                a2 += (float)w[2]*h0[2]; a3 += (float)w[3]*h0[3];
                a0 += (float)w[4]*h1[0]; a1 += (float)w[5]*h1[1];
                a2 += (float)w[6]*h1[2]; a3 += (float)w[7]*h1[3];
            }
            ghs[bl*96 + rr] = (a0 + a1) + (a2 + a3) + bhv;
            // prefetch next xi (immutable data)
            int tn = (t < 99) ? t + 1 : 99;
            xi_reg = xi1[xibase + (size_t)tn * 1536];
        }
        __syncthreads();

        if (tid < 64) {
            int bl2 = tid >> 5, i = tid & 31;
            float xr = xis[bl2*96 + i],      gr = ghs[bl2*96 + i];
            float xz = xis[bl2*96 + 32 + i], gz = ghs[bl2*96 + 32 + i];
            float xn = xis[bl2*96 + 64 + i], gn = ghs[bl2*96 + 64 + i];
            float r = sigmoidf_(xr + gr);
            float z = sigmoidf_(xz + gz);
            float n = tanhf(xn + r * gn);
            int kidx = (j << 5) + i;
            float hold = hs[bl2*520 + kidx];
            float hnew = (1.f - z) * n + z * hold;
            __hip_atomic_store(&nxt[((size_t)(b0 + bl2) << 9) + kidx], hnew,
                               __ATOMIC_RELAXED, __HIP_MEMORY_SCOPE_AGENT);
        }

        if (t < 99) {
            __syncthreads();   // drains vmcnt: h stores at LLC before flag
            if (tid == 0)
                __hip_atomic_store(myflag, t + 1, __ATOMIC_RELAXED, __HIP_MEMORY_SCOPE_AGENT);
        }
    }
}

// ---------------- u[b,t,k] = h_end[b, (t*512+k)/100]  (repeat_interleave quirk) ----------------
__global__ void k_build_u(const float* __restrict__ hend, f16* __restrict__ u) {
    int idx = blockIdx.x * blockDim.x + threadIdx.x;
    if (idx >= 32*100*512) return;
    int b = idx / 51200;
    int r = idx % 51200;
    int t = r >> 9, k = r & 511;
    u[idx] = (f16)hend[(b << 9) + ((t*512 + k) / 100)];
}

// ---------------- GRU2: one block per batch, 512 threads, one output row per thread ----------------
// Weights register-resident: 75 packed half2 per thread (~105 VGPR). __launch_bounds__(512,2)
// gives a 256-VGPR budget — NO spill (round-3 failure: default bounds capped VGPR at 64 and
// spilled w2[150] to scratch -> 18us/step + 32ms first-use scratch penalty).
__global__ __launch_bounds__(512, 2)
void k_gru2(const float* __restrict__ xi2p, const float* __restrict__ Wh2,
            const float* __restrict__ bh2, f16* __restrict__ decb) {
    __shared__ float hs2[152];
    __shared__ float ghs2[456];
    __shared__ float xis2[456];
    int tid = threadIdx.x;
    int b = blockIdx.x;
    bool act = tid < 450;
    half2v w[75];
    float bhv = 0.f;
    if (act) {
        const float2v* wrow = (const float2v*)&Wh2[tid*150];
        #pragma unroll
        for (int k = 0; k < 75; ++k) {
            float2v p = wrow[k];
            half2v wv; wv[0] = (f16)p[0]; wv[1] = (f16)p[1];
            w[k] = wv;
        }
        bhv = bh2[tid];
    }
    if (tid < 152) hs2[tid] = 0.f;
    size_t row0 = (size_t)b * 100 * 512;
    float xr = act ? xi2p[row0 + tid] : 0.f;
    __syncthreads();

    for (int t = 0; t < 100; ++t) {
        if (act) xis2[tid] = xr;
        __syncthreads();
        if (act) {
            float a = bhv;
            #pragma unroll
            for (int k = 0; k < 75; ++k) {
                a += (float)w[k][0] * hs2[2*k] + (float)w[k][1] * hs2[2*k+1];
            }
            ghs2[tid] = a;
        }
        // prefetch next xi row (immutable)
        int tn = (t < 99) ? t + 1 : 99;
        if (act) xr = xi2p[((size_t)b*100 + tn)*512 + tid];
        __syncthreads();
        if (tid < 150) {
            int i = tid;
            float r = sigmoidf_(xis2[i] + ghs2[i]);
            float z = sigmoidf_(xis2[150 + i] + ghs2[150 + i]);
            float n = tanhf(xis2[300 + i] + r * ghs2[300 + i]);
            float hnew = (1.f - z) * n + z * hs2[i];
            hs2[i] = hnew;
            decb[((size_t)b*100 + t)*160 + i] = (f16)hnew;
        }
        __syncthreads();
    }
}

// ---------------- launch ----------------
extern "C" void kernel_launch(void* const* d_in, const int* in_sizes, int n_in,
                              void* d_out, int out_size, void* d_ws, size_t ws_size,
                              hipStream_t stream) {
    const float* window = (const float*)d_in[0];
    const float* emb    = (const float*)d_in[1];
    const float* w_init = (const float*)d_in[2];
    const float* w_root = (const float*)d_in[3];
    const float* arma_b = (const float*)d_in[4];
    const float* Wi1    = (const float*)d_in[5];
    const float* Wh1    = (const float*)d_in[6];
    const float* bi1    = (const float*)d_in[7];
    const float* bh1    = (const float*)d_in[8];
    const float* Wi2    = (const float*)d_in[9];
    const float* Wh2    = (const float*)d_in[10];
    const float* bi2    = (const float*)d_in[11];
    const float* bh2    = (const float*)d_in[12];
    const float* W_fc   = (const float*)d_in[13];
    const float* b_fc   = (const float*)d_in[14];
    float* out = (float*)d_out;

    char* ws = (char*)d_ws;
    float* MT   = (float*)(ws + OFF_MT);
    int*   CNT  = (int*)  (ws + OFF_CNT);
    float* DEG  = (float*)(ws + OFF_DEG);
    float* HB0  = (float*)(ws + OFF_HB0);
    float* HB1  = (float*)(ws + OFF_HB1);
    f16*   WI2P = (f16*)  (ws + OFF_WI2P);
    f16*   WFCP = (f16*)  (ws + OFF_WFCP);
    f16*   DECB = (f16*)  (ws + OFF_DECB);
    float* WN   = (float*)(ws + OFF_WN);
    int*   EDST = (int*)  (ws + OFF_EDST);
    float* EVAL = (float*)(ws + OFF_EVAL);
    float* XF   = (float*)(ws + OFF_XF);
    float* SS   = (float*)(ws + OFF_SS);
    f16*   XT   = (f16*)  (ws + OFF_XT);
    f16*   WI1H = (f16*)  (ws + OFF_WI1H);
    float* XI1  = (float*)(ws + OFF_XI1);
    f16*   UB   = (f16*)  (ws + OFF_U);
    float* XI2P = (float*)(ws + OFF_XI2P);

    // zero the zone (MT scatter target, flags, deg, h buffers, padded weights, dec)
    hipMemsetAsync(d_ws, 0, ZONE_END, stream);

    // graph build
    k_norm<<<1, 256, 0, stream>>>(emb, WN);
    k_topk<<<150, 256, 0, stream>>>(WN, EDST, EVAL, DEG);
    k_finalize<<<1, 256, 0, stream>>>(EDST, EVAL, DEG, MT);

    // weight conversions
    {
        long long n1 = (long long)1536*4800;
        k_cvt_pad<<<(unsigned)((n1 + 255)/256), 256, 0, stream>>>(Wi1, WI1H, 1536, 4800, 4800);
        long long n2 = (long long)450*512;
        k_cvt_pad<<<(unsigned)((n2 + 255)/256), 256, 0, stream>>>(Wi2, WI2P, 450, 512, 512);
        long long n3 = (long long)150*150;
        k_cvt_pad<<<(unsigned)((n3 + 255)/256), 256, 0, stream>>>(W_fc, WFCP, 150, 150, 160);
    }

    // x in row layout, scrambled aggregation, epilogue -> xt (f16)
    k_perm<<<(480000 + 255)/256, 256, 0, stream>>>(window, XF);
    k_conv<<<3200, 256, 0, stream>>>(XF, MT, SS);
    k_xt<<<3200, 256, 0, stream>>>(SS, XF, w_init, w_root, arma_b, emb, XT);

    // xi1 = xt @ Wi1^T + bi1   [3200 x 1536]
    k_gemm_f16<<<25*12, 256, 0, stream>>>(XT, WI1H, bi1, XI1, 4800, 1536, 1536, 12);

    // GRU1 scan -> h_end in HB0
    k_gru1<<<256, 256, 0, stream>>>(XI1, Wh1, bh1, HB0, HB1, CNT);

    // u (repeat_interleave quirk), f16
    k_build_u<<<(32*100*512 + 255)/256, 256, 0, stream>>>(HB0, UB);

    // xi2 = u @ Wi2^T + bi2   [3200 x 450] (padded to 512)
    k_gemm_f16<<<25*4, 256, 0, stream>>>(UB, WI2P, bi2, XI2P, 512, 512, 450, 4);

    // GRU2 scan -> dec (f16, padded K=160)
    k_gru2<<<32, 512, 0, stream>>>(XI2P, Wh2, bh2, DECB);

    // out = dec @ W_fc^T + b_fc  -> directly into d_out [3200 x 150]
    k_gemm_f16<<<25*2, 256, 0, stream>>>(DECB, WFCP, b_fc, out, 160, 150, 150, 2);

    (void)in_sizes; (void)n_in; (void)out_size; (void)ws_size;
}

// Round 6
// 721.667 us; speedup vs baseline: 8.8620x; 1.3373x over previous
//
#include <hip/hip_runtime.h>
#include <hip/hip_fp16.h>
#include <math.h>

typedef _Float16 f16;
typedef _Float16 half8 __attribute__((ext_vector_type(8)));
typedef _Float16 half4 __attribute__((ext_vector_type(4)));
typedef _Float16 half2v __attribute__((ext_vector_type(2)));
typedef float float4v __attribute__((ext_vector_type(4)));
typedef float float2v __attribute__((ext_vector_type(2)));
typedef unsigned int uint4v __attribute__((ext_vector_type(4)));

#define AS1 __attribute__((address_space(1)))
#define AS3 __attribute__((address_space(3)))

// ---------------- workspace layout ----------------
constexpr size_t alup(size_t x){ return (x + 255) & ~(size_t)255; }
constexpr size_t OFF_MT   = 0;                                    // 150*150 fp32 (zeroed)
constexpr size_t OFF_DEG  = alup(OFF_MT + 150*150*4);             // 150 fp32 (zeroed)
constexpr size_t OFF_HT0  = alup(OFF_DEG + 150*4);                // 32*512 uint2 tagged h (zeroed)
constexpr size_t OFF_HT1  = alup(OFF_HT0 + (size_t)32*512*8);     // 32*512 uint2 (zeroed)
constexpr size_t OFF_WI2P = alup(OFF_HT1 + (size_t)32*512*8);     // 512*512 f16 padded (zeroed)
constexpr size_t OFF_WFCP = alup(OFF_WI2P + (size_t)512*512*2);   // 256*160 f16 padded (zeroed)
constexpr size_t OFF_DECB = alup(OFF_WFCP + (size_t)256*160*2);   // 3200*160 f16 (zeroed)
constexpr size_t ZONE_END = alup(OFF_DECB + (size_t)3200*160*2);
constexpr size_t OFF_WN   = ZONE_END;                             // 150*32 fp32
constexpr size_t OFF_EDST = alup(OFF_WN + 4800*4);                // 1500 int
constexpr size_t OFF_EVAL = alup(OFF_EDST + 1500*4);              // 1500 fp32
constexpr size_t OFF_XF   = alup(OFF_EVAL + 1500*4);              // 480000 fp32 (x in row layout)
constexpr size_t OFF_SS   = alup(OFF_XF + (size_t)480000*4);      // 480000 fp32 (agg scalar)
constexpr size_t OFF_XT   = alup(OFF_SS + (size_t)480000*4);      // 3200*4800 f16
constexpr size_t OFF_WI1H = alup(OFF_XT + (size_t)3200*4800*2);   // 1536*4800 f16
constexpr size_t OFF_XI1  = alup(OFF_WI1H + (size_t)1536*4800*2); // 3200*1536 fp32
constexpr size_t OFF_U    = alup(OFF_XI1 + (size_t)3200*1536*4);  // 3200*512 f16
constexpr size_t OFF_XI2P = alup(OFF_U + (size_t)3200*512*2);     // 3200*512 fp32

static __device__ __forceinline__ float sigmoidf_(float x){ return 1.0f/(1.0f+expf(-x)); }

// ---------------- graph construction ----------------
__global__ void k_norm(const float* __restrict__ emb, float* __restrict__ WN) {
    int n = threadIdx.x;
    if (n < 150) {
        float s = 0.f;
        #pragma unroll
        for (int c = 0; c < 32; ++c) { float v = emb[n*32+c]; s += v*v; }
        float nrm = fmaxf(sqrtf(s), 1e-8f);
        float inv = 1.0f / nrm;
        #pragma unroll
        for (int c = 0; c < 32; ++c) WN[n*32+c] = emb[n*32+c] * inv;
    }
}

__global__ void k_topk(const float* __restrict__ WN, int* __restrict__ EDST,
                       float* __restrict__ EVAL, float* __restrict__ DEG) {
    __shared__ float WnT[32*152];
    __shared__ float As[160];
    int tid = threadIdx.x;
    int i = blockIdx.x;  // row
    for (int idx = tid; idx < 4800; idx += 256) {
        int jj = idx >> 5, c = idx & 31;
        WnT[c*152 + jj] = WN[idx];
    }
    __syncthreads();
    int j = tid;
    if (j < 150) {
        float a = 0.f;
        #pragma unroll
        for (int c = 0; c < 32; ++c) a += WnT[c*152 + i] * WnT[c*152 + j];
        a = (j == i) ? 0.f : fmaxf(a, 0.f);
        As[j] = a;
    }
    __syncthreads();
    if (j < 150) {
        float aj = As[j];
        int cnt = 0;
        for (int m = 0; m < 150; ++m) {
            float am = As[m];
            cnt += (am > aj) || (am == aj && m < j);
        }
        if (cnt < 10) {
            EDST[i*10 + cnt] = j;
            EVAL[i*10 + cnt] = aj;
            atomicAdd(&DEG[j], aj);
        }
    }
}

__global__ void k_finalize(const int* __restrict__ EDST, const float* __restrict__ EVAL,
                           const float* __restrict__ DEG, float* __restrict__ MT) {
    __shared__ float dinv[160];
    int tid = threadIdx.x;
    if (tid < 150) {
        float d = DEG[tid];
        dinv[tid] = (d > 0.f) ? rsqrtf(d) : 0.f;
    }
    __syncthreads();
    for (int e = tid; e < 1500; e += 256) {
        int src = e / 10;
        int dst = EDST[e];
        MT[src*150 + dst] = dinv[src] * EVAL[e] * dinv[dst];
    }
}

// ---------------- fp32 -> f16 (with optional row padding) ----------------
__global__ void k_cvt_pad(const float* __restrict__ src, f16* __restrict__ dst,
                          int rows, int cols, int ldd) {
    long long idx = (long long)blockIdx.x * blockDim.x + threadIdx.x;
    long long n = (long long)rows * cols;
    if (idx >= n) return;
    if (ldd == cols) {
        dst[idx] = (f16)src[idx];
    } else {
        int r = (int)(idx / cols), c = (int)(idx % cols);
        dst[(size_t)r*ldd + c] = (f16)src[idx];
    }
}

// ---------------- x row-layout permute: XF[b*15000 + n*100 + t] = window[b,t,n] ----------------
__global__ void k_perm(const float* __restrict__ window, float* __restrict__ XF) {
    int idx = blockIdx.x * blockDim.x + threadIdx.x;   // source index (b*100+t)*150+n
    if (idx >= 480000) return;
    float v = window[idx];
    int b = idx / 15000;
    int r = idx % 15000;
    int t = r / 150, n = r % 150;
    XF[b*15000 + n*100 + t] = v;
}

// ---------------- scrambled ARMA aggregation: per contiguous 150-chunk of XF ----------------
__global__ void k_conv(const float* __restrict__ XF, const float* __restrict__ MT,
                       float* __restrict__ SS) {
    __shared__ float xs[152];
    int tid = threadIdx.x;
    int base = blockIdx.x * 150;
    if (tid < 150) xs[tid] = XF[base + tid];
    __syncthreads();
    if (tid < 150) {
        float s = 0.f;
        for (int m = 0; m < 150; ++m) s += MT[m*150 + tid] * xs[m];
        SS[base + tid] = s;
    }
}

// ---------------- epilogue: gelu(SS*wi + XF*wr + b) + emb -> xt (f16) ----------------
__global__ void k_xt(const float* __restrict__ SS, const float* __restrict__ XF,
                     const float* __restrict__ w_init, const float* __restrict__ w_root,
                     const float* __restrict__ arma_b, const float* __restrict__ emb,
                     f16* __restrict__ xt) {
    __shared__ float ssl[152];
    __shared__ float xfl[152];
    int tid = threadIdx.x;
    int bid = blockIdx.x;           // = b*100 + t
    int b = bid / 100, t = bid % 100;
    if (tid < 150) {
        int f = b*15000 + tid*100 + t;
        ssl[tid] = SS[f];
        xfl[tid] = XF[f];
    }
    __syncthreads();
    for (int e = tid; e < 4800; e += 256) {
        int n = e >> 5, c = e & 31;
        float pre = ssl[n]*w_init[c] + xfl[n]*w_root[c] + arma_b[c];
        float g = 0.5f * pre * (1.0f + erff(pre * 0.70710678118654752f));
        xt[(size_t)bid*4800 + e] = (f16)(g + emb[e]);
    }
}

// ---------------- f16 MFMA GEMM: C[M,N] = A[M,K] @ B[N,K]^T + bias ----------------
__global__ void k_gemm_f16(const f16* __restrict__ A, const f16* __restrict__ Bm,
                           const float* __restrict__ bias, float* __restrict__ C,
                           int K, int ldc, int nvalid, int ntn) {
    __shared__ f16 As[128*32];
    __shared__ f16 Bs[128*32];
    int tid = threadIdx.x;
    int lane = tid & 63, wave = tid >> 6;
    int wm = wave >> 1, wn = wave & 1;
    int tm = blockIdx.x / ntn, tn = blockIdx.x % ntn;
    int m0 = tm * 128, n0 = tn * 128;
    int lrow = lane & 15, quad = lane >> 4;

    float4v acc[4][4];
    #pragma unroll
    for (int mi = 0; mi < 4; ++mi)
        #pragma unroll
        for (int ni = 0; ni < 4; ++ni)
            acc[mi][ni] = (float4v){0.f, 0.f, 0.f, 0.f};

    for (int k0 = 0; k0 < K; k0 += 32) {
        #pragma unroll
        for (int i = 0; i < 2; ++i) {
            int chunk = i*256 + tid;
            int row = chunk >> 2, cq = chunk & 3;
            int cbase = chunk & ~63;  // wave-uniform
            const f16* ga = A + (size_t)(m0+row)*K + k0 + cq*8;
            __builtin_amdgcn_global_load_lds((const AS1 void*)ga, (AS3 void*)(As + cbase*8), 16, 0, 0);
            const f16* gb = Bm + (size_t)(n0+row)*K + k0 + cq*8;
            __builtin_amdgcn_global_load_lds((const AS1 void*)gb, (AS3 void*)(Bs + cbase*8), 16, 0, 0);
        }
        __syncthreads();
        half8 aF[4], bF[4];
        #pragma unroll
        for (int mi = 0; mi < 4; ++mi)
            aF[mi] = *(const half8*)&As[(wm*64 + mi*16 + lrow)*32 + quad*8];
        #pragma unroll
        for (int ni = 0; ni < 4; ++ni)
            bF[ni] = *(const half8*)&Bs[(wn*64 + ni*16 + lrow)*32 + quad*8];
        #pragma unroll
        for (int mi = 0; mi < 4; ++mi)
            #pragma unroll
            for (int ni = 0; ni < 4; ++ni)
                acc[mi][ni] = __builtin_amdgcn_mfma_f32_16x16x32_f16(aF[mi], bF[ni], acc[mi][ni], 0, 0, 0);
        __syncthreads();
    }

    #pragma unroll
    for (int ni = 0; ni < 4; ++ni) {
        int gcol = n0 + wn*64 + ni*16 + lrow;
        if (gcol >= nvalid) continue;
        float bv = bias[gcol];
        #pragma unroll
        for (int mi = 0; mi < 4; ++mi) {
            int growb = m0 + wm*64 + mi*16 + quad*4;
            #pragma unroll
            for (int r = 0; r < 4; ++r)
                C[(size_t)(growb + r)*ldc + gcol] = acc[mi][ni][r] + bv;
        }
    }
}

// ---------------- GRU1: 16 groups x 16 blocks; MFMA dot + tag-in-data exchange ----------------
// Block j of group g: batches {2g,2g+1}, hidden [32j,32j+32) (96 weight rows).
// Per-step GEMM [2x512]@[512x96] via mfma 16x16x32 f16 (M padded to 16; garbage rows unused).
// h exchanged as tagged 8B pairs {f32 bits, step tag} in ping-pong buffers via relaxed
// agent atomics. Consumers poll the DATA tags directly (2 coherent dwordx4 per thread)
// -> no flags, no drain barrier, 2 barriers/step. Overwrite safety: completing step t
// requires reading all tag-t slots; buf reused only at t+2. NO fences (R2: 43us/step),
// NO counter RMW (R4: serialized LLC line).
__global__ __launch_bounds__(256, 1)
void k_gru1(const float* __restrict__ xi1, const float* __restrict__ Wh1,
            const float* __restrict__ bh1, uint2* __restrict__ ht0,
            uint2* __restrict__ ht1) {
    __shared__ __align__(16) f16 Wf[16*3072];   // 96KB: [k0][rr*32+kk], rr=gate*32+i
    __shared__ __align__(16) f16 hA[16*512];    // 16KB: [k0][row*32+kk], rows 0,1 = batches
    __shared__ float xis[192];                  // [bl*96+rr]
    __shared__ float ghs[192];
    int tid = threadIdx.x;
    int g = blockIdx.x & 15;
    int j = blockIdx.x >> 4;
    int b0 = g * 2;
    int lane = tid & 63, wave = tid >> 6;
    int lrow = lane & 15, quad = lane >> 4;

    // preload weights into MFMA-B-fragment-friendly layout
    for (int idx = tid; idx < 96*512; idx += 256) {
        int rr = idx >> 9, k = idx & 511;
        int hi = (j << 5) + (rr & 31);
        Wf[(k >> 5)*3072 + rr*32 + (k & 31)] =
            (f16)Wh1[(size_t)((rr >> 5)*512 + hi)*512 + k];
    }

    // gates state (tid<64): own hidden in register, bh preloaded
    float hold = 0.f, bhr = 0.f, bhz = 0.f, bhn = 0.f;
    if (tid < 64) {
        int col = (j << 5) + (tid & 31);
        bhr = bh1[col]; bhz = bh1[512 + col]; bhn = bh1[1024 + col];
    }
    // wave 3: xi staging (3 values per thread per step)
    float xr[3]; int xvi[3]; size_t xad[3];
    if (wave == 3) {
        int idx = tid - 192;
        #pragma unroll
        for (int q = 0; q < 3; ++q) {
            int vi = idx + 64*q; xvi[q] = vi;
            int bl = vi / 96, rr = vi % 96;
            int col = (rr >> 5)*512 + (j << 5) + (rr & 31);
            xad[q] = (size_t)((b0 + bl)*100)*1536 + col;
            xr[q] = xi1[xad[q]];   // t=0
        }
    }
    // staging assignment: thread -> 4 consecutive tagged pairs (32B)
    int sbl = tid >> 7;
    int kb  = (tid & 127) << 2;
    __syncthreads();

    for (int t = 0; t < 100; ++t) {
        const uint2* cur = (t & 1) ? ht1 : ht0;
        uint2* nxt = (t & 1) ? ht0 : ht1;
        // ---- stage h: poll data tags, cvt to f16 A-fragments ----
        {
            const unsigned* p = (const unsigned*)(cur + (size_t)(b0 + sbl)*512 + kb);
            uint4v A4, B4;
            unsigned tagw = (unsigned)t;
            for (;;) {
                asm volatile("global_load_dwordx4 %0, %2, off sc0 sc1\n\t"
                             "global_load_dwordx4 %1, %3, off sc0 sc1\n\t"
                             "s_waitcnt vmcnt(0)"
                             : "=v"(A4), "=v"(B4) : "v"(p), "v"(p + 4) : "memory");
                if (A4[1] == tagw && A4[3] == tagw && B4[1] == tagw && B4[3] == tagw) break;
                __builtin_amdgcn_s_sleep(1);
            }
            union { unsigned u; float f; } c0, c1, c2, c3;
            c0.u = A4[0]; c1.u = A4[2]; c2.u = B4[0]; c3.u = B4[2];
            half4 hv; hv[0] = (f16)c0.f; hv[1] = (f16)c1.f; hv[2] = (f16)c2.f; hv[3] = (f16)c3.f;
            *(half4*)&hA[(kb >> 5)*512 + sbl*32 + (kb & 31)] = hv;
        }
        __syncthreads();   // A

        if (wave < 3) {
            // ---- MFMA: 2 N-tiles per wave, K=512 over 16 iters ----
            float4v acc0 = (float4v){0.f,0.f,0.f,0.f}, acc1 = (float4v){0.f,0.f,0.f,0.f};
            int n0 = wave*2, n1 = wave*2 + 1;
            const f16* aB  = &hA[lrow*32 + quad*8];
            const f16* b0p = &Wf[(n0*16 + lrow)*32 + quad*8];
            const f16* b1p = &Wf[(n1*16 + lrow)*32 + quad*8];
            #pragma unroll
            for (int k0 = 0; k0 < 16; ++k0) {
                half8 a   = *(const half8*)(aB  + k0*512);
                half8 bb0 = *(const half8*)(b0p + k0*3072);
                half8 bb1 = *(const half8*)(b1p + k0*3072);
                acc0 = __builtin_amdgcn_mfma_f32_16x16x32_f16(a, bb0, acc0, 0, 0, 0);
                acc1 = __builtin_amdgcn_mfma_f32_16x16x32_f16(a, bb1, acc1, 0, 0, 0);
            }
            if (lane < 16) {   // C rows 0,1 = batches; col = tile*16 + lane
                ghs[n0*16 + lane]      = acc0[0];
                ghs[96 + n0*16 + lane] = acc0[1];
                ghs[n1*16 + lane]      = acc1[0];
                ghs[96 + n1*16 + lane] = acc1[1];
            }
        } else {
            // wave 3: publish xi[t], prefetch xi[t+1]
            #pragma unroll
            for (int q = 0; q < 3; ++q) xis[xvi[q]] = xr[q];
            int tn = (t < 99) ? t + 1 : 99;
            #pragma unroll
            for (int q = 0; q < 3; ++q) xr[q] = xi1[xad[q] + (size_t)tn*1536];
        }
        __syncthreads();   // B

        if (tid < 64) {
            int bl = tid >> 5, i = tid & 31;
            float gr = ghs[bl*96 + i]      + bhr;
            float gz = ghs[bl*96 + 32 + i] + bhz;
            float gn = ghs[bl*96 + 64 + i] + bhn;
            float r = sigmoidf_(xis[bl*96 + i] + gr);
            float z = sigmoidf_(xis[bl*96 + 32 + i] + gz);
            float n = tanhf(xis[bl*96 + 64 + i] + r*gn);
            float hnew = (1.f - z)*n + z*hold;
            hold = hnew;
            union { float f; unsigned u; } hb; hb.f = hnew;
            unsigned long long pk = ((unsigned long long)(unsigned)(t + 1) << 32) | (unsigned long long)hb.u;
            __hip_atomic_store((unsigned long long*)(nxt + (size_t)(b0 + bl)*512 + (j << 5) + i),
                               pk, __ATOMIC_RELAXED, __HIP_MEMORY_SCOPE_AGENT);
        }
    }
}

// ---------------- u[b,t,k] = h_end[b, (t*512+k)/100]  (repeat_interleave quirk) ----------------
// h_end lives in HT0 as tagged pairs (t=99 stores to buffer (99+1)&1 = 0)
__global__ void k_build_u(const uint2* __restrict__ ht0, f16* __restrict__ u) {
    int idx = blockIdx.x * blockDim.x + threadIdx.x;
    if (idx >= 32*100*512) return;
    int b = idx / 51200;
    int r = idx % 51200;
    int t = r >> 9, k = r & 511;
    union { unsigned u32; float f; } v;
    v.u32 = ht0[(b << 9) + ((t*512 + k) / 100)].x;
    u[idx] = (f16)v.f;
}

// ---------------- GRU2: one block per batch, 512 threads, one output row per thread ----------------
__global__ __launch_bounds__(512, 2)
void k_gru2(const float* __restrict__ xi2p, const float* __restrict__ Wh2,
            const float* __restrict__ bh2, f16* __restrict__ decb) {
    __shared__ float hs2[152];
    __shared__ float ghs2[456];
    __shared__ float xis2[456];
    int tid = threadIdx.x;
    int b = blockIdx.x;
    bool act = tid < 450;
    half2v w[75];
    float bhv = 0.f;
    if (act) {
        const float2v* wrow = (const float2v*)&Wh2[tid*150];
        #pragma unroll
        for (int k = 0; k < 75; ++k) {
            float2v p = wrow[k];
            half2v wv; wv[0] = (f16)p[0]; wv[1] = (f16)p[1];
            w[k] = wv;
        }
        bhv = bh2[tid];
    }
    if (tid < 152) hs2[tid] = 0.f;
    size_t row0 = (size_t)b * 100 * 512;
    float xr = act ? xi2p[row0 + tid] : 0.f;
    __syncthreads();

    for (int t = 0; t < 100; ++t) {
        if (act) xis2[tid] = xr;
        __syncthreads();
        if (act) {
            float a = bhv;
            #pragma unroll
            for (int k = 0; k < 75; ++k) {
                a += (float)w[k][0] * hs2[2*k] + (float)w[k][1] * hs2[2*k+1];
            }
            ghs2[tid] = a;
        }
        int tn = (t < 99) ? t + 1 : 99;
        if (act) xr = xi2p[((size_t)b*100 + tn)*512 + tid];
        __syncthreads();
        if (tid < 150) {
            int i = tid;
            float r = sigmoidf_(xis2[i] + ghs2[i]);
            float z = sigmoidf_(xis2[150 + i] + ghs2[150 + i]);
            float n = tanhf(xis2[300 + i] + r * ghs2[300 + i]);
            float hnew = (1.f - z) * n + z * hs2[i];
            hs2[i] = hnew;
            decb[((size_t)b*100 + t)*160 + i] = (f16)hnew;
        }
        __syncthreads();
    }
}

// ---------------- launch ----------------
extern "C" void kernel_launch(void* const* d_in, const int* in_sizes, int n_in,
                              void* d_out, int out_size, void* d_ws, size_t ws_size,
                              hipStream_t stream) {
    const float* window = (const float*)d_in[0];
    const float* emb    = (const float*)d_in[1];
    const float* w_init = (const float*)d_in[2];
    const float* w_root = (const float*)d_in[3];
    const float* arma_b = (const float*)d_in[4];
    const float* Wi1    = (const float*)d_in[5];
    const float* Wh1    = (const float*)d_in[6];
    const float* bi1    = (const float*)d_in[7];
    const float* bh1    = (const float*)d_in[8];
    const float* Wi2    = (const float*)d_in[9];
    const float* Wh2    = (const float*)d_in[10];
    const float* bi2    = (const float*)d_in[11];
    const float* bh2    = (const float*)d_in[12];
    const float* W_fc   = (const float*)d_in[13];
    const float* b_fc   = (const float*)d_in[14];
    float* out = (float*)d_out;

    char* ws = (char*)d_ws;
    float* MT   = (float*)(ws + OFF_MT);
    float* DEG  = (float*)(ws + OFF_DEG);
    uint2* HT0  = (uint2*)(ws + OFF_HT0);
    uint2* HT1  = (uint2*)(ws + OFF_HT1);
    f16*   WI2P = (f16*)  (ws + OFF_WI2P);
    f16*   WFCP = (f16*)  (ws + OFF_WFCP);
    f16*   DECB = (f16*)  (ws + OFF_DECB);
    float* WN   = (float*)(ws + OFF_WN);
    int*   EDST = (int*)  (ws + OFF_EDST);
    float* EVAL = (float*)(ws + OFF_EVAL);
    float* XF   = (float*)(ws + OFF_XF);
    float* SS   = (float*)(ws + OFF_SS);
    f16*   XT   = (f16*)  (ws + OFF_XT);
    f16*   WI1H = (f16*)  (ws + OFF_WI1H);
    float* XI1  = (float*)(ws + OFF_XI1);
    f16*   UB   = (f16*)  (ws + OFF_U);
    float* XI2P = (float*)(ws + OFF_XI2P);

    // zero the zone (MT scatter target, deg, tagged h buffers, padded weights, dec)
    hipMemsetAsync(d_ws, 0, ZONE_END, stream);

    // graph build
    k_norm<<<1, 256, 0, stream>>>(emb, WN);
    k_topk<<<150, 256, 0, stream>>>(WN, EDST, EVAL, DEG);
    k_finalize<<<1, 256, 0, stream>>>(EDST, EVAL, DEG, MT);

    // weight conversions
    {
        long long n1 = (long long)1536*4800;
        k_cvt_pad<<<(unsigned)((n1 + 255)/256), 256, 0, stream>>>(Wi1, WI1H, 1536, 4800, 4800);
        long long n2 = (long long)450*512;
        k_cvt_pad<<<(unsigned)((n2 + 255)/256), 256, 0, stream>>>(Wi2, WI2P, 450, 512, 512);
        long long n3 = (long long)150*150;
        k_cvt_pad<<<(unsigned)((n3 + 255)/256), 256, 0, stream>>>(W_fc, WFCP, 150, 150, 160);
    }

    // x in row layout, scrambled aggregation, epilogue -> xt (f16)
    k_perm<<<(480000 + 255)/256, 256, 0, stream>>>(window, XF);
    k_conv<<<3200, 256, 0, stream>>>(XF, MT, SS);
    k_xt<<<3200, 256, 0, stream>>>(SS, XF, w_init, w_root, arma_b, emb, XT);

    // xi1 = xt @ Wi1^T + bi1   [3200 x 1536]
    k_gemm_f16<<<25*12, 256, 0, stream>>>(XT, WI1H, bi1, XI1, 4800, 1536, 1536, 12);

    // GRU1 scan -> h_end (tagged) in HT0
    k_gru1<<<256, 256, 0, stream>>>(XI1, Wh1, bh1, HT0, HT1);

    // u (repeat_interleave quirk), f16
    k_build_u<<<(32*100*512 + 255)/256, 256, 0, stream>>>(HT0, UB);

    // xi2 = u @ Wi2^T + bi2   [3200 x 450] (padded to 512)
    k_gemm_f16<<<25*4, 256, 0, stream>>>(UB, WI2P, bi2, XI2P, 512, 512, 450, 4);

    // GRU2 scan -> dec (f16, padded K=160)
    k_gru2<<<32, 512, 0, stream>>>(XI2P, Wh2, bh2, DECB);

    // out = dec @ W_fc^T + b_fc  -> directly into d_out [3200 x 150]
    k_gemm_f16<<<25*2, 256, 0, stream>>>(DECB, WFCP, b_fc, out, 160, 150, 150, 2);

    (void)in_sizes; (void)n_in; (void)out_size; (void)ws_size;
}

// Round 7
// 625.109 us; speedup vs baseline: 10.2309x; 1.1545x over previous
//
#include <hip/hip_runtime.h>
#include <hip/hip_fp16.h>
#include <math.h>

typedef _Float16 f16;
typedef _Float16 half8 __attribute__((ext_vector_type(8)));
typedef _Float16 half4 __attribute__((ext_vector_type(4)));
typedef float float4v __attribute__((ext_vector_type(4)));
typedef float float2v __attribute__((ext_vector_type(2)));
typedef unsigned int uint4v __attribute__((ext_vector_type(4)));

#define AS1 __attribute__((address_space(1)))
#define AS3 __attribute__((address_space(3)))

// ---------------- workspace layout ----------------
constexpr size_t alup(size_t x){ return (x + 255) & ~(size_t)255; }
constexpr size_t OFF_MT   = 0;                                    // 150*150 fp32 (zeroed)
constexpr size_t OFF_DEG  = alup(OFF_MT + 150*150*4);             // 150 fp32 (zeroed)
constexpr size_t OFF_HT0  = alup(OFF_DEG + 150*4);                // 32*512 u32 {tag|f16} (zeroed)
constexpr size_t OFF_HT1  = alup(OFF_HT0 + (size_t)32*512*4);     // 32*512 u32 (zeroed)
constexpr size_t OFF_WI2P = alup(OFF_HT1 + (size_t)32*512*4);     // 512*512 f16 padded (zeroed)
constexpr size_t OFF_WFCP = alup(OFF_WI2P + (size_t)512*512*2);   // 256*160 f16 padded (zeroed)
constexpr size_t OFF_DECB = alup(OFF_WFCP + (size_t)256*160*2);   // 3200*160 f16 (zeroed)
constexpr size_t ZONE_END = alup(OFF_DECB + (size_t)3200*160*2);
constexpr size_t OFF_WN   = ZONE_END;                             // 150*32 fp32
constexpr size_t OFF_EDST = alup(OFF_WN + 4800*4);                // 1500 int
constexpr size_t OFF_EVAL = alup(OFF_EDST + 1500*4);              // 1500 fp32
constexpr size_t OFF_XF   = alup(OFF_EVAL + 1500*4);              // 480000 fp32 (x in row layout)
constexpr size_t OFF_SS   = alup(OFF_XF + (size_t)480000*4);      // 480000 fp32 (agg scalar)
constexpr size_t OFF_XT   = alup(OFF_SS + (size_t)480000*4);      // 3200*4800 f16
constexpr size_t OFF_WI1H = alup(OFF_XT + (size_t)3200*4800*2);   // 1536*4800 f16
constexpr size_t OFF_XI1  = alup(OFF_WI1H + (size_t)1536*4800*2); // 3200*1536 fp32
constexpr size_t OFF_U    = alup(OFF_XI1 + (size_t)3200*1536*4);  // 3200*512 f16
constexpr size_t OFF_XI2P = alup(OFF_U + (size_t)3200*512*2);     // 3200*512 fp32

// fast gates: __expf lowers to v_exp_f32-based fast path (~2ulp; absmax slack is 5.6x)
static __device__ __forceinline__ float fsig(float x){ return 1.0f/(1.0f + __expf(-x)); }
static __device__ __forceinline__ float ftanh(float x){
    x = fminf(fmaxf(x, -15.f), 15.f);
    float e = __expf(2.0f*x);
    return (e - 1.0f)/(e + 1.0f);
}
static __device__ __forceinline__ float sigmoidf_(float x){ return 1.0f/(1.0f+expf(-x)); }

// ---------------- graph construction ----------------
__global__ void k_norm(const float* __restrict__ emb, float* __restrict__ WN) {
    int n = threadIdx.x;
    if (n < 150) {
        float s = 0.f;
        #pragma unroll
        for (int c = 0; c < 32; ++c) { float v = emb[n*32+c]; s += v*v; }
        float nrm = fmaxf(sqrtf(s), 1e-8f);
        float inv = 1.0f / nrm;
        #pragma unroll
        for (int c = 0; c < 32; ++c) WN[n*32+c] = emb[n*32+c] * inv;
    }
}

__global__ void k_topk(const float* __restrict__ WN, int* __restrict__ EDST,
                       float* __restrict__ EVAL, float* __restrict__ DEG) {
    __shared__ float WnT[32*152];
    __shared__ float As[160];
    int tid = threadIdx.x;
    int i = blockIdx.x;  // row
    for (int idx = tid; idx < 4800; idx += 256) {
        int jj = idx >> 5, c = idx & 31;
        WnT[c*152 + jj] = WN[idx];
    }
    __syncthreads();
    int j = tid;
    if (j < 150) {
        float a = 0.f;
        #pragma unroll
        for (int c = 0; c < 32; ++c) a += WnT[c*152 + i] * WnT[c*152 + j];
        a = (j == i) ? 0.f : fmaxf(a, 0.f);
        As[j] = a;
    }
    __syncthreads();
    if (j < 150) {
        float aj = As[j];
        int cnt = 0;
        for (int m = 0; m < 150; ++m) {
            float am = As[m];
            cnt += (am > aj) || (am == aj && m < j);
        }
        if (cnt < 10) {
            EDST[i*10 + cnt] = j;
            EVAL[i*10 + cnt] = aj;
            atomicAdd(&DEG[j], aj);
        }
    }
}

__global__ void k_finalize(const int* __restrict__ EDST, const float* __restrict__ EVAL,
                           const float* __restrict__ DEG, float* __restrict__ MT) {
    __shared__ float dinv[160];
    int tid = threadIdx.x;
    if (tid < 150) {
        float d = DEG[tid];
        dinv[tid] = (d > 0.f) ? rsqrtf(d) : 0.f;
    }
    __syncthreads();
    for (int e = tid; e < 1500; e += 256) {
        int src = e / 10;
        int dst = EDST[e];
        MT[src*150 + dst] = dinv[src] * EVAL[e] * dinv[dst];
    }
}

// ---------------- fp32 -> f16 (with optional row padding) ----------------
__global__ void k_cvt_pad(const float* __restrict__ src, f16* __restrict__ dst,
                          int rows, int cols, int ldd) {
    long long idx = (long long)blockIdx.x * blockDim.x + threadIdx.x;
    long long n = (long long)rows * cols;
    if (idx >= n) return;
    if (ldd == cols) {
        dst[idx] = (f16)src[idx];
    } else {
        int r = (int)(idx / cols), c = (int)(idx % cols);
        dst[(size_t)r*ldd + c] = (f16)src[idx];
    }
}

// ---------------- x row-layout permute: XF[b*15000 + n*100 + t] = window[b,t,n] ----------------
__global__ void k_perm(const float* __restrict__ window, float* __restrict__ XF) {
    int idx = blockIdx.x * blockDim.x + threadIdx.x;   // source index (b*100+t)*150+n
    if (idx >= 480000) return;
    float v = window[idx];
    int b = idx / 15000;
    int r = idx % 15000;
    int t = r / 150, n = r % 150;
    XF[b*15000 + n*100 + t] = v;
}

// ---------------- scrambled ARMA aggregation: per contiguous 150-chunk of XF ----------------
__global__ void k_conv(const float* __restrict__ XF, const float* __restrict__ MT,
                       float* __restrict__ SS) {
    __shared__ float xs[152];
    int tid = threadIdx.x;
    int base = blockIdx.x * 150;
    if (tid < 150) xs[tid] = XF[base + tid];
    __syncthreads();
    if (tid < 150) {
        float s = 0.f;
        for (int m = 0; m < 150; ++m) s += MT[m*150 + tid] * xs[m];
        SS[base + tid] = s;
    }
}

// ---------------- epilogue: gelu(SS*wi + XF*wr + b) + emb -> xt (f16) ----------------
__global__ void k_xt(const float* __restrict__ SS, const float* __restrict__ XF,
                     const float* __restrict__ w_init, const float* __restrict__ w_root,
                     const float* __restrict__ arma_b, const float* __restrict__ emb,
                     f16* __restrict__ xt) {
    __shared__ float ssl[152];
    __shared__ float xfl[152];
    int tid = threadIdx.x;
    int bid = blockIdx.x;           // = b*100 + t
    int b = bid / 100, t = bid % 100;
    if (tid < 150) {
        int f = b*15000 + tid*100 + t;
        ssl[tid] = SS[f];
        xfl[tid] = XF[f];
    }
    __syncthreads();
    for (int e = tid; e < 4800; e += 256) {
        int n = e >> 5, c = e & 31;
        float pre = ssl[n]*w_init[c] + xfl[n]*w_root[c] + arma_b[c];
        float g = 0.5f * pre * (1.0f + erff(pre * 0.70710678118654752f));
        xt[(size_t)bid*4800 + e] = (f16)(g + emb[e]);
    }
}

// ---------------- f16 MFMA GEMM: C[M,N] = A[M,K] @ B[N,K]^T + bias ----------------
__global__ void k_gemm_f16(const f16* __restrict__ A, const f16* __restrict__ Bm,
                           const float* __restrict__ bias, float* __restrict__ C,
                           int K, int ldc, int nvalid, int ntn) {
    __shared__ f16 As[128*32];
    __shared__ f16 Bs[128*32];
    int tid = threadIdx.x;
    int lane = tid & 63, wave = tid >> 6;
    int wm = wave >> 1, wn = wave & 1;
    int tm = blockIdx.x / ntn, tn = blockIdx.x % ntn;
    int m0 = tm * 128, n0 = tn * 128;
    int lrow = lane & 15, quad = lane >> 4;

    float4v acc[4][4];
    #pragma unroll
    for (int mi = 0; mi < 4; ++mi)
        #pragma unroll
        for (int ni = 0; ni < 4; ++ni)
            acc[mi][ni] = (float4v){0.f, 0.f, 0.f, 0.f};

    for (int k0 = 0; k0 < K; k0 += 32) {
        #pragma unroll
        for (int i = 0; i < 2; ++i) {
            int chunk = i*256 + tid;
            int row = chunk >> 2, cq = chunk & 3;
            int cbase = chunk & ~63;  // wave-uniform
            const f16* ga = A + (size_t)(m0+row)*K + k0 + cq*8;
            __builtin_amdgcn_global_load_lds((const AS1 void*)ga, (AS3 void*)(As + cbase*8), 16, 0, 0);
            const f16* gb = Bm + (size_t)(n0+row)*K + k0 + cq*8;
            __builtin_amdgcn_global_load_lds((const AS1 void*)gb, (AS3 void*)(Bs + cbase*8), 16, 0, 0);
        }
        __syncthreads();
        half8 aF[4], bF[4];
        #pragma unroll
        for (int mi = 0; mi < 4; ++mi)
            aF[mi] = *(const half8*)&As[(wm*64 + mi*16 + lrow)*32 + quad*8];
        #pragma unroll
        for (int ni = 0; ni < 4; ++ni)
            bF[ni] = *(const half8*)&Bs[(wn*64 + ni*16 + lrow)*32 + quad*8];
        #pragma unroll
        for (int mi = 0; mi < 4; ++mi)
            #pragma unroll
            for (int ni = 0; ni < 4; ++ni)
                acc[mi][ni] = __builtin_amdgcn_mfma_f32_16x16x32_f16(aF[mi], bF[ni], acc[mi][ni], 0, 0, 0);
        __syncthreads();
    }

    #pragma unroll
    for (int ni = 0; ni < 4; ++ni) {
        int gcol = n0 + wn*64 + ni*16 + lrow;
        if (gcol >= nvalid) continue;
        float bv = bias[gcol];
        #pragma unroll
        for (int mi = 0; mi < 4; ++mi) {
            int growb = m0 + wm*64 + mi*16 + quad*4;
            #pragma unroll
            for (int r = 0; r < 4; ++r)
                C[(size_t)(growb + r)*ldc + gcol] = acc[mi][ni][r] + bv;
        }
    }
}

// ---------------- GRU1: 16 groups x 16 blocks; reg-resident B-frags + u32 tag|f16 exchange ----
// Block j of group g: batches {2g,2g+1}, hidden [32j,32j+32).
// Per-step GEMM [2x512]@[512x96] via mfma 16x16x32 f16; B-fragments (Wh rows) live in
// 128 VGPRs per thread (waves 0-2) -> zero weight-LDS traffic in the loop (R6: 8-way
// bank conflicts on Wf reads, 1.5e7 conflict cycles). h exchanged as ONE u32 per value
// {u16 tag | f16 bits} via relaxed agent atomics: tag+payload in one atomic word, no
// fences (R2), no counter RMW (R4), poll = 1 dwordx4/thread. hA rows padded to 40
// halves (80B: 16B-aligned b128, <=2-way bank alias = free).
__global__ __launch_bounds__(256, 1)
void k_gru1(const float* __restrict__ xi1, const float* __restrict__ Wh1,
            const float* __restrict__ bh1, unsigned* __restrict__ ht0,
            unsigned* __restrict__ ht1) {
    __shared__ __align__(16) f16 hA[16*640];    // 20KB: [k0][row*40+kk], rows 0,1 real
    __shared__ float xis[192];                  // [bl*96+rr]
    __shared__ float ghs[192];
    int tid = threadIdx.x;
    int g = blockIdx.x & 15;
    int j = blockIdx.x >> 4;
    int b0 = g * 2;
    int lane = tid & 63, wave = tid >> 6;
    int lrow = lane & 15, quad = lane >> 4;

    // B-fragments in registers (waves 0..2): tiles 2w, 2w+1; B[n][k]: n=lrow, k=k0*32+quad*8+i
    half8 Bf0[16], Bf1[16];
    if (wave < 3) {
        #pragma unroll
        for (int tile = 0; tile < 2; ++tile) {
            int rr = (wave*2 + tile)*16 + lrow;
            int grow = (rr >> 5)*512 + (j << 5) + (rr & 31);
            const float* wp = Wh1 + (size_t)grow*512 + quad*8;
            #pragma unroll
            for (int k0 = 0; k0 < 16; ++k0) {
                float4v w0 = *(const float4v*)(wp + k0*32);
                float4v w1 = *(const float4v*)(wp + k0*32 + 4);
                half8 hb;
                hb[0]=(f16)w0[0]; hb[1]=(f16)w0[1]; hb[2]=(f16)w0[2]; hb[3]=(f16)w0[3];
                hb[4]=(f16)w1[0]; hb[5]=(f16)w1[1]; hb[6]=(f16)w1[2]; hb[7]=(f16)w1[3];
                if (tile == 0) Bf0[k0] = hb; else Bf1[k0] = hb;
            }
        }
    }

    // gates state (tid<64): own hidden in register, bh preloaded
    float hold = 0.f, bhr = 0.f, bhz = 0.f, bhn = 0.f;
    if (tid < 64) {
        int col = (j << 5) + (tid & 31);
        bhr = bh1[col]; bhz = bh1[512 + col]; bhn = bh1[1024 + col];
    }
    // wave 3: xi staging (3 values per thread per step)
    float xr[3]; int xvi[3]; size_t xad[3];
    if (wave == 3) {
        int idx = tid - 192;
        #pragma unroll
        for (int q = 0; q < 3; ++q) {
            int vi = idx + 64*q; xvi[q] = vi;
            int bl = vi / 96, rr = vi % 96;
            int col = (rr >> 5)*512 + (j << 5) + (rr & 31);
            xad[q] = (size_t)((b0 + bl)*100)*1536 + col;
            xr[q] = xi1[xad[q]];   // t=0
        }
    }
    // staging: thread -> 4 consecutive u32 h-slots (16B)
    int sbl = tid >> 7;
    int kb  = (tid & 127) << 2;

    for (int t = 0; t < 100; ++t) {
        const unsigned* cur = (t & 1) ? ht1 : ht0;
        unsigned* nxt = (t & 1) ? ht0 : ht1;
        // ---- stage h: poll tag-in-data, place f16 A-fragment ----
        {
            const unsigned* p = cur + (size_t)(b0 + sbl)*512 + kb;
            uint4v A4;
            unsigned tagw = (unsigned)t << 16;
            for (;;) {
                asm volatile("global_load_dwordx4 %0, %1, off sc0 sc1\n\ts_waitcnt vmcnt(0)"
                             : "=v"(A4) : "v"(p) : "memory");
                if ((A4[0] & 0xffff0000u) == tagw && (A4[1] & 0xffff0000u) == tagw &&
                    (A4[2] & 0xffff0000u) == tagw && (A4[3] & 0xffff0000u) == tagw) break;
                __builtin_amdgcn_s_sleep(1);
            }
            union { unsigned short s[4]; half4 h; } cv;
            cv.s[0] = (unsigned short)A4[0]; cv.s[1] = (unsigned short)A4[1];
            cv.s[2] = (unsigned short)A4[2]; cv.s[3] = (unsigned short)A4[3];
            *(half4*)&hA[(kb >> 5)*640 + sbl*40 + (kb & 31)] = cv.h;
        }
        __syncthreads();   // A

        if (wave < 3) {
            float4v acc0 = (float4v){0.f,0.f,0.f,0.f}, acc1 = (float4v){0.f,0.f,0.f,0.f};
            const f16* aB = &hA[lrow*40 + quad*8];
            #pragma unroll
            for (int k0 = 0; k0 < 16; ++k0) {
                half8 a = *(const half8*)(aB + k0*640);
                acc0 = __builtin_amdgcn_mfma_f32_16x16x32_f16(a, Bf0[k0], acc0, 0, 0, 0);
                acc1 = __builtin_amdgcn_mfma_f32_16x16x32_f16(a, Bf1[k0], acc1, 0, 0, 0);
            }
            if (lane < 16) {   // C: col=lane&15, row=quad*4+reg; rows 0,1 = batches
                int n0 = wave*2, n1 = n0 + 1;
                ghs[n0*16 + lane]      = acc0[0];
                ghs[96 + n0*16 + lane] = acc0[1];
                ghs[n1*16 + lane]      = acc1[0];
                ghs[96 + n1*16 + lane] = acc1[1];
            }
        } else {
            // wave 3: publish xi[t], prefetch xi[t+1]
            #pragma unroll
            for (int q = 0; q < 3; ++q) xis[xvi[q]] = xr[q];
            int tn = (t < 99) ? t + 1 : 99;
            #pragma unroll
            for (int q = 0; q < 3; ++q) xr[q] = xi1[xad[q] + (size_t)tn*1536];
        }
        __syncthreads();   // B

        if (tid < 64) {
            int bl = tid >> 5, i = tid & 31;
            float gr = ghs[bl*96 + i]      + bhr;
            float gz = ghs[bl*96 + 32 + i] + bhz;
            float gn = ghs[bl*96 + 64 + i] + bhn;
            float r = fsig(xis[bl*96 + i] + gr);
            float z = fsig(xis[bl*96 + 32 + i] + gz);
            float n = ftanh(xis[bl*96 + 64 + i] + r*gn);
            float hnew = (1.f - z)*n + z*hold;
            hold = hnew;
            union { f16 h; unsigned short s; } hb; hb.h = (f16)hnew;
            unsigned pk = ((unsigned)(t + 1) << 16) | (unsigned)hb.s;
            __hip_atomic_store(nxt + (size_t)(b0 + bl)*512 + (j << 5) + i, pk,
                               __ATOMIC_RELAXED, __HIP_MEMORY_SCOPE_AGENT);
        }
    }
}

// ---------------- u[b,t,k] = h_end[b, (t*512+k)/100]  (repeat_interleave quirk) ----------------
// h_end lives in HT0 as {tag|f16}; payload low 16 bits IS the f16 value of u
__global__ void k_build_u(const unsigned* __restrict__ ht0, f16* __restrict__ u) {
    int idx = blockIdx.x * blockDim.x + threadIdx.x;
    if (idx >= 32*100*512) return;
    int b = idx / 51200;
    int r = idx % 51200;
    int t = r >> 9, k = r & 511;
    union { unsigned short s; f16 h; } cv;
    cv.s = (unsigned short)ht0[(b << 9) + ((t*512 + k) / 100)];
    u[idx] = cv.h;
}

// ---------------- GRU2: one block per batch, 512 threads, one output row per thread ----------------
// fp32 register weights (150 VGPR; (512,2) -> 256 budget, no spill, no per-iter cvt)
__global__ __launch_bounds__(512, 2)
void k_gru2(const float* __restrict__ xi2p, const float* __restrict__ Wh2,
            const float* __restrict__ bh2, f16* __restrict__ decb) {
    __shared__ float hs2[152];
    __shared__ float ghs2[456];
    __shared__ float xis2[456];
    int tid = threadIdx.x;
    int b = blockIdx.x;
    bool act = tid < 450;
    float2v w[75];
    float bhv = 0.f;
    if (act) {
        const float2v* wrow = (const float2v*)&Wh2[tid*150];
        #pragma unroll
        for (int k = 0; k < 75; ++k) w[k] = wrow[k];
        bhv = bh2[tid];
    }
    if (tid < 152) hs2[tid] = 0.f;
    size_t row0 = (size_t)b * 100 * 512;
    float xr = act ? xi2p[row0 + tid] : 0.f;
    __syncthreads();

    for (int t = 0; t < 100; ++t) {
        if (act) xis2[tid] = xr;
        __syncthreads();
        if (act) {
            float a = bhv;
            #pragma unroll
            for (int k = 0; k < 75; ++k)
                a += w[k][0] * hs2[2*k] + w[k][1] * hs2[2*k+1];
            ghs2[tid] = a;
        }
        int tn = (t < 99) ? t + 1 : 99;
        if (act) xr = xi2p[((size_t)b*100 + tn)*512 + tid];
        __syncthreads();
        if (tid < 150) {
            int i = tid;
            float r = fsig(xis2[i] + ghs2[i]);
            float z = fsig(xis2[150 + i] + ghs2[150 + i]);
            float n = ftanh(xis2[300 + i] + r * ghs2[300 + i]);
            float hnew = (1.f - z) * n + z * hs2[i];
            hs2[i] = hnew;
            decb[((size_t)b*100 + t)*160 + i] = (f16)hnew;
        }
        __syncthreads();
    }
}

// ---------------- launch ----------------
extern "C" void kernel_launch(void* const* d_in, const int* in_sizes, int n_in,
                              void* d_out, int out_size, void* d_ws, size_t ws_size,
                              hipStream_t stream) {
    const float* window = (const float*)d_in[0];
    const float* emb    = (const float*)d_in[1];
    const float* w_init = (const float*)d_in[2];
    const float* w_root = (const float*)d_in[3];
    const float* arma_b = (const float*)d_in[4];
    const float* Wi1    = (const float*)d_in[5];
    const float* Wh1    = (const float*)d_in[6];
    const float* bi1    = (const float*)d_in[7];
    const float* bh1    = (const float*)d_in[8];
    const float* Wi2    = (const float*)d_in[9];
    const float* Wh2    = (const float*)d_in[10];
    const float* bi2    = (const float*)d_in[11];
    const float* bh2    = (const float*)d_in[12];
    const float* W_fc   = (const float*)d_in[13];
    const float* b_fc   = (const float*)d_in[14];
    float* out = (float*)d_out;

    char* ws = (char*)d_ws;
    float*    MT   = (float*)(ws + OFF_MT);
    float*    DEG  = (float*)(ws + OFF_DEG);
    unsigned* HT0  = (unsigned*)(ws + OFF_HT0);
    unsigned* HT1  = (unsigned*)(ws + OFF_HT1);
    f16*      WI2P = (f16*)  (ws + OFF_WI2P);
    f16*      WFCP = (f16*)  (ws + OFF_WFCP);
    f16*      DECB = (f16*)  (ws + OFF_DECB);
    float*    WN   = (float*)(ws + OFF_WN);
    int*      EDST = (int*)  (ws + OFF_EDST);
    float*    EVAL = (float*)(ws + OFF_EVAL);
    float*    XF   = (float*)(ws + OFF_XF);
    float*    SS   = (float*)(ws + OFF_SS);
    f16*      XT   = (f16*)  (ws + OFF_XT);
    f16*      WI1H = (f16*)  (ws + OFF_WI1H);
    float*    XI1  = (float*)(ws + OFF_XI1);
    f16*      UB   = (f16*)  (ws + OFF_U);
    float*    XI2P = (float*)(ws + OFF_XI2P);

    // zero the zone (MT scatter target, deg, tagged h buffers, padded weights, dec)
    hipMemsetAsync(d_ws, 0, ZONE_END, stream);

    // graph build
    k_norm<<<1, 256, 0, stream>>>(emb, WN);
    k_topk<<<150, 256, 0, stream>>>(WN, EDST, EVAL, DEG);
    k_finalize<<<1, 256, 0, stream>>>(EDST, EVAL, DEG, MT);

    // weight conversions
    {
        long long n1 = (long long)1536*4800;
        k_cvt_pad<<<(unsigned)((n1 + 255)/256), 256, 0, stream>>>(Wi1, WI1H, 1536, 4800, 4800);
        long long n2 = (long long)450*512;
        k_cvt_pad<<<(unsigned)((n2 + 255)/256), 256, 0, stream>>>(Wi2, WI2P, 450, 512, 512);
        long long n3 = (long long)150*150;
        k_cvt_pad<<<(unsigned)((n3 + 255)/256), 256, 0, stream>>>(W_fc, WFCP, 150, 150, 160);
    }

    // x in row layout, scrambled aggregation, epilogue -> xt (f16)
    k_perm<<<(480000 + 255)/256, 256, 0, stream>>>(window, XF);
    k_conv<<<3200, 256, 0, stream>>>(XF, MT, SS);
    k_xt<<<3200, 256, 0, stream>>>(SS, XF, w_init, w_root, arma_b, emb, XT);

    // xi1 = xt @ Wi1^T + bi1   [3200 x 1536]
    k_gemm_f16<<<25*12, 256, 0, stream>>>(XT, WI1H, bi1, XI1, 4800, 1536, 1536, 12);

    // GRU1 scan -> h_end (tagged f16) in HT0
    k_gru1<<<256, 256, 0, stream>>>(XI1, Wh1, bh1, HT0, HT1);

    // u (repeat_interleave quirk), f16
    k_build_u<<<(32*100*512 + 255)/256, 256, 0, stream>>>(HT0, UB);

    // xi2 = u @ Wi2^T + bi2   [3200 x 450] (padded to 512)
    k_gemm_f16<<<25*4, 256, 0, stream>>>(UB, WI2P, bi2, XI2P, 512, 512, 450, 4);

    // GRU2 scan -> dec (f16, padded K=160)
    k_gru2<<<32, 512, 0, stream>>>(XI2P, Wh2, bh2, DECB);

    // out = dec @ W_fc^T + b_fc  -> directly into d_out [3200 x 150]
    k_gemm_f16<<<25*2, 256, 0, stream>>>(DECB, WFCP, b_fc, out, 160, 150, 150, 2);

    (void)in_sizes; (void)n_in; (void)out_size; (void)ws_size;
}

// Round 8
// 615.046 us; speedup vs baseline: 10.3983x; 1.0164x over previous
//
#include <hip/hip_runtime.h>
#include <hip/hip_fp16.h>
#include <math.h>

typedef _Float16 f16;
typedef _Float16 half8 __attribute__((ext_vector_type(8)));
typedef _Float16 half4 __attribute__((ext_vector_type(4)));
typedef float float4v __attribute__((ext_vector_type(4)));
typedef float float2v __attribute__((ext_vector_type(2)));
typedef unsigned int uint4v __attribute__((ext_vector_type(4)));

#define AS1 __attribute__((address_space(1)))
#define AS3 __attribute__((address_space(3)))

// ---------------- workspace layout ----------------
constexpr size_t alup(size_t x){ return (x + 255) & ~(size_t)255; }
constexpr size_t OFF_MT   = 0;                                    // 150*150 fp32 (zeroed)
constexpr size_t OFF_DEG  = alup(OFF_MT + 150*150*4);             // 150 fp32 (zeroed)
constexpr size_t OFF_HT0  = alup(OFF_DEG + 150*4);                // 32*512 u32 {tag|f16} (zeroed)
constexpr size_t OFF_HT1  = alup(OFF_HT0 + (size_t)32*512*4);     // 32*512 u32 (zeroed)
constexpr size_t OFF_WI2P = alup(OFF_HT1 + (size_t)32*512*4);     // 512*512 f16 padded (zeroed)
constexpr size_t OFF_WFCP = alup(OFF_WI2P + (size_t)512*512*2);   // 256*192 f16 padded (zeroed)
constexpr size_t OFF_DECB = alup(OFF_WFCP + (size_t)256*192*2);   // 3200*192 f16 (zeroed)
constexpr size_t ZONE_END = alup(OFF_DECB + (size_t)3200*192*2);
constexpr size_t OFF_EDST = ZONE_END;                             // 1500 int
constexpr size_t OFF_EVAL = alup(OFF_EDST + 1500*4);              // 1500 fp32
constexpr size_t OFF_XF   = alup(OFF_EVAL + 1500*4);              // 480000 fp32 (x in row layout)
constexpr size_t OFF_SS   = alup(OFF_XF + (size_t)480000*4);      // 480000 fp32 (agg scalar)
constexpr size_t OFF_XT   = alup(OFF_SS + (size_t)480000*4);      // 3200*4800 f16
constexpr size_t OFF_WI1H = alup(OFF_XT + (size_t)3200*4800*2);   // 1536*4800 f16
constexpr size_t OFF_XI1  = alup(OFF_WI1H + (size_t)1536*4800*2); // 3200*1536 f16
constexpr size_t OFF_U    = alup(OFF_XI1 + (size_t)3200*1536*2);  // 3200*512 f16
constexpr size_t OFF_XI2  = alup(OFF_U + (size_t)3200*512*2);     // 3200*512 f16

// fast gates: __expf lowers to v_exp_f32 fast path (~2ulp; absmax slack ~5x)
static __device__ __forceinline__ float fsig(float x){ return 1.0f/(1.0f + __expf(-x)); }
static __device__ __forceinline__ float ftanh(float x){
    x = fminf(fmaxf(x, -15.f), 15.f);
    float e = __expf(2.0f*x);
    return (e - 1.0f)/(e + 1.0f);
}

// ---------------- topk with inline normalize (drops k_norm launch) ----------------
__global__ void k_topk(const float* __restrict__ emb, int* __restrict__ EDST,
                       float* __restrict__ EVAL, float* __restrict__ DEG) {
    __shared__ float WnT[32*152];
    __shared__ float invn[160];
    __shared__ float As[160];
    int tid = threadIdx.x;
    int i = blockIdx.x;  // row
    for (int idx = tid; idx < 4800; idx += 256) {
        int jj = idx >> 5, c = idx & 31;
        WnT[c*152 + jj] = emb[idx];
    }
    __syncthreads();
    if (tid < 150) {
        float s = 0.f;
        #pragma unroll
        for (int c = 0; c < 32; ++c) { float v = WnT[c*152 + tid]; s += v*v; }
        invn[tid] = 1.0f / fmaxf(sqrtf(s), 1e-8f);
    }
    __syncthreads();
    for (int idx = tid; idx < 4800; idx += 256) {
        int jj = idx >> 5, c = idx & 31;
        WnT[c*152 + jj] *= invn[jj];
    }
    __syncthreads();
    int j = tid;
    if (j < 150) {
        float a = 0.f;
        #pragma unroll
        for (int c = 0; c < 32; ++c) a += WnT[c*152 + i] * WnT[c*152 + j];
        a = (j == i) ? 0.f : fmaxf(a, 0.f);
        As[j] = a;
    }
    __syncthreads();
    if (j < 150) {
        float aj = As[j];
        int cnt = 0;
        for (int m = 0; m < 150; ++m) {
            float am = As[m];
            cnt += (am > aj) || (am == aj && m < j);
        }
        if (cnt < 10) {
            EDST[i*10 + cnt] = j;
            EVAL[i*10 + cnt] = aj;
            atomicAdd(&DEG[j], aj);
        }
    }
}

// ---------------- merged prep: finalize + 3x weight cvt + perm (one launch) ----------------
// block 0: MT finalize | [1,28801): Wi1 cvt | [28801,29701): Wi2 cvt |
// [29701,29789): W_fc cvt (pad ld 192) | [29789,31664): window permute
__global__ void k_prep(const int* __restrict__ EDST, const float* __restrict__ EVAL,
                       const float* __restrict__ DEG, float* __restrict__ MT,
                       const float* __restrict__ Wi1, f16* __restrict__ WI1H,
                       const float* __restrict__ Wi2, f16* __restrict__ WI2P,
                       const float* __restrict__ W_fc, f16* __restrict__ WFCP,
                       const float* __restrict__ window, float* __restrict__ XF) {
    int b = blockIdx.x, tid = threadIdx.x;
    if (b == 0) {
        __shared__ float dinv[160];
        if (tid < 150) {
            float d = DEG[tid];
            dinv[tid] = (d > 0.f) ? rsqrtf(d) : 0.f;
        }
        __syncthreads();
        for (int e = tid; e < 1500; e += 256) {
            int src = e / 10;
            int dst = EDST[e];
            MT[src*150 + dst] = dinv[src] * EVAL[e] * dinv[dst];
        }
    } else if (b < 28801) {
        int idx = (b - 1)*256 + tid;              // 1536*4800 = 7372800, exact
        WI1H[idx] = (f16)Wi1[idx];
    } else if (b < 29701) {
        int idx = (b - 28801)*256 + tid;          // 450*512 = 230400, exact
        WI2P[idx] = (f16)Wi2[idx];
    } else if (b < 29789) {
        int idx = (b - 29701)*256 + tid;          // 150*150 = 22500
        if (idx < 22500) {
            int r = idx / 150, c = idx % 150;
            WFCP[r*192 + c] = (f16)W_fc[idx];
        }
    } else {
        int idx = (b - 29789)*256 + tid;          // 480000, exact
        float v = window[idx];
        int bb = idx / 15000;
        int r = idx % 15000;
        int t = r / 150, n = r % 150;
        XF[bb*15000 + n*100 + t] = v;
    }
}

// ---------------- scrambled ARMA aggregation: per contiguous 150-chunk of XF ----------------
__global__ void k_conv(const float* __restrict__ XF, const float* __restrict__ MT,
                       float* __restrict__ SS) {
    __shared__ float xs[152];
    int tid = threadIdx.x;
    int base = blockIdx.x * 150;
    if (tid < 150) xs[tid] = XF[base + tid];
    __syncthreads();
    if (tid < 150) {
        float s = 0.f;
        for (int m = 0; m < 150; ++m) s += MT[m*150 + tid] * xs[m];
        SS[base + tid] = s;
    }
}

// ---------------- epilogue: gelu(SS*wi + XF*wr + b) + emb -> xt (f16) ----------------
__global__ void k_xt(const float* __restrict__ SS, const float* __restrict__ XF,
                     const float* __restrict__ w_init, const float* __restrict__ w_root,
                     const float* __restrict__ arma_b, const float* __restrict__ emb,
                     f16* __restrict__ xt) {
    __shared__ float ssl[152];
    __shared__ float xfl[152];
    int tid = threadIdx.x;
    int bid = blockIdx.x;           // = b*100 + t
    int b = bid / 100, t = bid % 100;
    if (tid < 150) {
        int f = b*15000 + tid*100 + t;
        ssl[tid] = SS[f];
        xfl[tid] = XF[f];
    }
    __syncthreads();
    for (int e = tid; e < 4800; e += 256) {
        int n = e >> 5, c = e & 31;
        float pre = ssl[n]*w_init[c] + xfl[n]*w_root[c] + arma_b[c];
        float g = 0.5f * pre * (1.0f + erff(pre * 0.70710678118654752f));
        xt[(size_t)bid*4800 + e] = (f16)(g + emb[e]);
    }
}

// ---------------- f16 MFMA GEMM, BK=64, N-major block order ----------------
// C[M,N] = A[M,K] @ B[N,K]^T + bias. M,Npad mult of 128; K mult of 64.
// N-major (tn = blockIdx/ntm): consecutive blocks share the B-tile -> L2-resident,
// A streamed once. BK=64 halves barrier pairs (occupancy is 1 block/CU at these
// grid sizes, so bigger BK has no occupancy cost). TC = f16 or float output.
template <typename TC>
__global__ void k_gemm(const f16* __restrict__ A, const f16* __restrict__ Bm,
                       const float* __restrict__ bias, TC* __restrict__ C,
                       int K, int ldc, int nvalid, int ntm) {
    __shared__ f16 As[128*64];
    __shared__ f16 Bs[128*64];
    int tid = threadIdx.x;
    int lane = tid & 63, wave = tid >> 6;
    int wm = wave >> 1, wn = wave & 1;
    int tm = blockIdx.x % ntm, tn = blockIdx.x / ntm;
    int m0 = tm * 128, n0 = tn * 128;
    int lrow = lane & 15, quad = lane >> 4;

    float4v acc[4][4];
    #pragma unroll
    for (int mi = 0; mi < 4; ++mi)
        #pragma unroll
        for (int ni = 0; ni < 4; ++ni)
            acc[mi][ni] = (float4v){0.f, 0.f, 0.f, 0.f};

    for (int k0 = 0; k0 < K; k0 += 64) {
        #pragma unroll
        for (int i = 0; i < 4; ++i) {
            int cid = i*256 + tid;          // 1024 chunks of 8 halves
            int row = cid >> 3, cq = cid & 7;
            int cbase = cid & ~63;          // wave-uniform
            const f16* ga = A + (size_t)(m0+row)*K + k0 + cq*8;
            __builtin_amdgcn_global_load_lds((const AS1 void*)ga, (AS3 void*)(As + cbase*8), 16, 0, 0);
            const f16* gb = Bm + (size_t)(n0+row)*K + k0 + cq*8;
            __builtin_amdgcn_global_load_lds((const AS1 void*)gb, (AS3 void*)(Bs + cbase*8), 16, 0, 0);
        }
        __syncthreads();
        #pragma unroll
        for (int kk = 0; kk < 2; ++kk) {
            half8 aF[4], bF[4];
            #pragma unroll
            for (int mi = 0; mi < 4; ++mi)
                aF[mi] = *(const half8*)&As[(wm*64 + mi*16 + lrow)*64 + kk*32 + quad*8];
            #pragma unroll
            for (int ni = 0; ni < 4; ++ni)
                bF[ni] = *(const half8*)&Bs[(wn*64 + ni*16 + lrow)*64 + kk*32 + quad*8];
            #pragma unroll
            for (int mi = 0; mi < 4; ++mi)
                #pragma unroll
                for (int ni = 0; ni < 4; ++ni)
                    acc[mi][ni] = __builtin_amdgcn_mfma_f32_16x16x32_f16(aF[mi], bF[ni], acc[mi][ni], 0, 0, 0);
        }
        __syncthreads();
    }

    #pragma unroll
    for (int ni = 0; ni < 4; ++ni) {
        int gcol = n0 + wn*64 + ni*16 + lrow;
        if (gcol >= nvalid) continue;
        float bv = bias[gcol];
        #pragma unroll
        for (int mi = 0; mi < 4; ++mi) {
            int growb = m0 + wm*64 + mi*16 + quad*4;
            #pragma unroll
            for (int r = 0; r < 4; ++r)
                C[(size_t)(growb + r)*ldc + gcol] = (TC)(acc[mi][ni][r] + bv);
        }
    }
}

// ---------------- GRU1: 16 groups x 16 blocks; AGPR B-frags + u32 tag|f16 exchange ----
// Block j of group g: batches {2g,2g+1}, hidden [32j,32j+32).
// Per-step GEMM [2x512]@[512x96] via mfma 16x16x32 f16; B-frags live in AGPRs (128,
// unified file). h exchanged as u32 {u16 tag | f16} via relaxed agent atomics — no
// fences (R2: 43us/step), no counter RMW (R4). Gates hold xi in registers (3 f16
// loads/thread, prefetched 1 step ahead) — wave-3 xi staging removed (R7).
__global__ __launch_bounds__(256, 1)
void k_gru1(const f16* __restrict__ xi1, const float* __restrict__ Wh1,
            const float* __restrict__ bh1, unsigned* __restrict__ ht0,
            unsigned* __restrict__ ht1) {
    __shared__ __align__(16) f16 hA[16*640];    // 20KB: [k0][row*40+kk], rows 0,1 real
    __shared__ float ghs[192];
    int tid = threadIdx.x;
    int g = blockIdx.x & 15;
    int j = blockIdx.x >> 4;
    int b0 = g * 2;
    int lane = tid & 63, wave = tid >> 6;
    int lrow = lane & 15, quad = lane >> 4;

    // B-fragments (waves 0..2): tiles 2w, 2w+1; B[n][k]: n=lrow, k=k0*32+quad*8+i
    half8 Bf0[16], Bf1[16];
    if (wave < 3) {
        #pragma unroll
        for (int tile = 0; tile < 2; ++tile) {
            int rr = (wave*2 + tile)*16 + lrow;
            int grow = (rr >> 5)*512 + (j << 5) + (rr & 31);
            const float* wp = Wh1 + (size_t)grow*512 + quad*8;
            #pragma unroll
            for (int k0 = 0; k0 < 16; ++k0) {
                float4v w0 = *(const float4v*)(wp + k0*32);
                float4v w1 = *(const float4v*)(wp + k0*32 + 4);
                half8 hb;
                hb[0]=(f16)w0[0]; hb[1]=(f16)w0[1]; hb[2]=(f16)w0[2]; hb[3]=(f16)w0[3];
                hb[4]=(f16)w1[0]; hb[5]=(f16)w1[1]; hb[6]=(f16)w1[2]; hb[7]=(f16)w1[3];
                if (tile == 0) Bf0[k0] = hb; else Bf1[k0] = hb;
            }
        }
    }

    // gates state (tid<64): own hidden + biases + xi in registers
    float hold = 0.f, bhr = 0.f, bhz = 0.f, bhn = 0.f;
    f16 xir = (f16)0.f, xiz = (f16)0.f, xin = (f16)0.f;
    size_t xb = 0;
    if (tid < 64) {
        int bl = tid >> 5, i = tid & 31;
        int col = (j << 5) + i;
        bhr = bh1[col]; bhz = bh1[512 + col]; bhn = bh1[1024 + col];
        xb = (size_t)((b0 + bl)*100)*1536 + col;
        xir = xi1[xb]; xiz = xi1[xb + 512]; xin = xi1[xb + 1024];   // t=0
    }
    // staging: thread -> 4 consecutive u32 h-slots (16B)
    int sbl = tid >> 7;
    int kb  = (tid & 127) << 2;

    for (int t = 0; t < 100; ++t) {
        const unsigned* cur = (t & 1) ? ht1 : ht0;
        unsigned* nxt = (t & 1) ? ht0 : ht1;
        // ---- stage h: poll tag-in-data, place f16 A-fragment ----
        {
            const unsigned* p = cur + (size_t)(b0 + sbl)*512 + kb;
            uint4v A4;
            unsigned tagw = (unsigned)t << 16;
            for (;;) {
                asm volatile("global_load_dwordx4 %0, %1, off sc0 sc1\n\ts_waitcnt vmcnt(0)"
                             : "=v"(A4) : "v"(p) : "memory");
                if ((A4[0] & 0xffff0000u) == tagw && (A4[1] & 0xffff0000u) == tagw &&
                    (A4[2] & 0xffff0000u) == tagw && (A4[3] & 0xffff0000u) == tagw) break;
                __builtin_amdgcn_s_sleep(1);
            }
            union { unsigned short s[4]; half4 h; } cv;
            cv.s[0] = (unsigned short)A4[0]; cv.s[1] = (unsigned short)A4[1];
            cv.s[2] = (unsigned short)A4[2]; cv.s[3] = (unsigned short)A4[3];
            *(half4*)&hA[(kb >> 5)*640 + sbl*40 + (kb & 31)] = cv.h;
        }
        __syncthreads();   // A

        if (wave < 3) {
            // split accumulator chains (2x8 deps instead of 1x16)
            float4v a0a = (float4v){0.f,0.f,0.f,0.f}, a0b = a0a, a1a = a0a, a1b = a0a;
            const f16* aB = &hA[lrow*40 + quad*8];
            #pragma unroll
            for (int k0 = 0; k0 < 16; k0 += 2) {
                half8 a0 = *(const half8*)(aB + k0*640);
                half8 a1 = *(const half8*)(aB + (k0+1)*640);
                a0a = __builtin_amdgcn_mfma_f32_16x16x32_f16(a0, Bf0[k0], a0a, 0, 0, 0);
                a1a = __builtin_amdgcn_mfma_f32_16x16x32_f16(a0, Bf1[k0], a1a, 0, 0, 0);
                a0b = __builtin_amdgcn_mfma_f32_16x16x32_f16(a1, Bf0[k0+1], a0b, 0, 0, 0);
                a1b = __builtin_amdgcn_mfma_f32_16x16x32_f16(a1, Bf1[k0+1], a1b, 0, 0, 0);
            }
            if (lane < 16) {   // C: col=lane, row=reg; rows 0,1 = batches
                int n0 = wave*2, n1 = n0 + 1;
                ghs[n0*16 + lane]      = a0a[0] + a0b[0];
                ghs[96 + n0*16 + lane] = a0a[1] + a0b[1];
                ghs[n1*16 + lane]      = a1a[0] + a1b[0];
                ghs[96 + n1*16 + lane] = a1a[1] + a1b[1];
            }
        }
        __syncthreads();   // B

        if (tid < 64) {
            int bl = tid >> 5, i = tid & 31;
            float xr_ = (float)xir, xz_ = (float)xiz, xn_ = (float)xin;
            // prefetch xi for t+1 (immutable; lands during next step's exchange)
            int tn = (t < 99) ? t + 1 : 99;
            size_t xo = xb + (size_t)tn*1536;
            xir = xi1[xo]; xiz = xi1[xo + 512]; xin = xi1[xo + 1024];
            float gr = ghs[bl*96 + i]      + bhr;
            float gz = ghs[bl*96 + 32 + i] + bhz;
            float gn = ghs[bl*96 + 64 + i] + bhn;
            float r = fsig(xr_ + gr);
            float z = fsig(xz_ + gz);
            float n = ftanh(xn_ + r*gn);
            float hnew = (1.f - z)*n + z*hold;
            hold = hnew;
            union { f16 h; unsigned short s; } hb; hb.h = (f16)hnew;
            unsigned pk = ((unsigned)(t + 1) << 16) | (unsigned)hb.s;
            __hip_atomic_store(nxt + (size_t)(b0 + bl)*512 + (j << 5) + i, pk,
                               __ATOMIC_RELAXED, __HIP_MEMORY_SCOPE_AGENT);
        }
    }
}

// ---------------- u[b,t,k] = h_end[b, (t*512+k)/100]  (repeat_interleave quirk) ----------------
__global__ void k_build_u(const unsigned* __restrict__ ht0, f16* __restrict__ u) {
    int idx = blockIdx.x * blockDim.x + threadIdx.x;
    if (idx >= 32*100*512) return;
    int b = idx / 51200;
    int r = idx % 51200;
    int t = r >> 9, k = r & 511;
    union { unsigned short s; f16 h; } cv;
    cv.s = (unsigned short)ht0[(b << 9) + ((t*512 + k) / 100)];
    u[idx] = cv.h;
}

// ---------------- GRU2: one block per batch, 512 threads, one output row per thread ----------------
// fp32 register weights (150 VGPR; (512,2) -> 256 budget, no spill — R3 lesson)
__global__ __launch_bounds__(512, 2)
void k_gru2(const f16* __restrict__ xi2, const float* __restrict__ Wh2,
            const float* __restrict__ bh2, f16* __restrict__ decb) {
    __shared__ float hs2[152];
    __shared__ float ghs2[456];
    __shared__ float xis2[456];
    int tid = threadIdx.x;
    int b = blockIdx.x;
    bool act = tid < 450;
    float2v w[75];
    float bhv = 0.f;
    if (act) {
        const float2v* wrow = (const float2v*)&Wh2[tid*150];
        #pragma unroll
        for (int k = 0; k < 75; ++k) w[k] = wrow[k];
        bhv = bh2[tid];
    }
    if (tid < 152) hs2[tid] = 0.f;
    size_t row0 = (size_t)b * 100 * 512;
    float xr = act ? (float)xi2[row0 + tid] : 0.f;
    __syncthreads();

    for (int t = 0; t < 100; ++t) {
        if (act) xis2[tid] = xr;
        __syncthreads();
        if (act) {
            float a = bhv;
            #pragma unroll
            for (int k = 0; k < 75; ++k)
                a += w[k][0] * hs2[2*k] + w[k][1] * hs2[2*k+1];
            ghs2[tid] = a;
        }
        int tn = (t < 99) ? t + 1 : 99;
        if (act) xr = (float)xi2[((size_t)b*100 + tn)*512 + tid];
        __syncthreads();
        if (tid < 150) {
            int i = tid;
            float r = fsig(xis2[i] + ghs2[i]);
            float z = fsig(xis2[150 + i] + ghs2[150 + i]);
            float n = ftanh(xis2[300 + i] + r * ghs2[300 + i]);
            float hnew = (1.f - z) * n + z * hs2[i];
            hs2[i] = hnew;
            decb[((size_t)b*100 + t)*192 + i] = (f16)hnew;
        }
        __syncthreads();
    }
}

// ---------------- launch ----------------
extern "C" void kernel_launch(void* const* d_in, const int* in_sizes, int n_in,
                              void* d_out, int out_size, void* d_ws, size_t ws_size,
                              hipStream_t stream) {
    const float* window = (const float*)d_in[0];
    const float* emb    = (const float*)d_in[1];
    const float* w_init = (const float*)d_in[2];
    const float* w_root = (const float*)d_in[3];
    const float* arma_b = (const float*)d_in[4];
    const float* Wi1    = (const float*)d_in[5];
    const float* Wh1    = (const float*)d_in[6];
    const float* bi1    = (const float*)d_in[7];
    const float* bh1    = (const float*)d_in[8];
    const float* Wi2    = (const float*)d_in[9];
    const float* Wh2    = (const float*)d_in[10];
    const float* bi2    = (const float*)d_in[11];
    const float* bh2    = (const float*)d_in[12];
    const float* W_fc   = (const float*)d_in[13];
    const float* b_fc   = (const float*)d_in[14];
    float* out = (float*)d_out;

    char* ws = (char*)d_ws;
    float*    MT   = (float*)(ws + OFF_MT);
    float*    DEG  = (float*)(ws + OFF_DEG);
    unsigned* HT0  = (unsigned*)(ws + OFF_HT0);
    unsigned* HT1  = (unsigned*)(ws + OFF_HT1);
    f16*      WI2P = (f16*)  (ws + OFF_WI2P);
    f16*      WFCP = (f16*)  (ws + OFF_WFCP);
    f16*      DECB = (f16*)  (ws + OFF_DECB);
    int*      EDST = (int*)  (ws + OFF_EDST);
    float*    EVAL = (float*)(ws + OFF_EVAL);
    float*    XF   = (float*)(ws + OFF_XF);
    float*    SS   = (float*)(ws + OFF_SS);
    f16*      XT   = (f16*)  (ws + OFF_XT);
    f16*      WI1H = (f16*)  (ws + OFF_WI1H);
    f16*      XI1H = (f16*)  (ws + OFF_XI1);
    f16*      UB   = (f16*)  (ws + OFF_U);
    f16*      XI2H = (f16*)  (ws + OFF_XI2);

    // zero the zone (MT scatter target, deg, tagged h buffers, padded weights, dec)
    hipMemsetAsync(d_ws, 0, ZONE_END, stream);

    // graph build (norm inlined in topk)
    k_topk<<<150, 256, 0, stream>>>(emb, EDST, EVAL, DEG);

    // merged prep: finalize + weight cvts + window permute
    k_prep<<<31664, 256, 0, stream>>>(EDST, EVAL, DEG, MT,
                                      Wi1, WI1H, Wi2, WI2P, W_fc, WFCP, window, XF);

    // scrambled aggregation, epilogue -> xt (f16)
    k_conv<<<3200, 256, 0, stream>>>(XF, MT, SS);
    k_xt<<<3200, 256, 0, stream>>>(SS, XF, w_init, w_root, arma_b, emb, XT);

    // xi1 = xt @ Wi1^T + bi1   [3200 x 1536] f16 out, N-major, ntm=25
    k_gemm<f16><<<25*12, 256, 0, stream>>>(XT, WI1H, bi1, XI1H, 4800, 1536, 1536, 25);

    // GRU1 scan -> h_end (tagged f16) in HT0
    k_gru1<<<256, 256, 0, stream>>>(XI1H, Wh1, bh1, HT0, HT1);

    // u (repeat_interleave quirk), f16
    k_build_u<<<(32*100*512 + 255)/256, 256, 0, stream>>>(HT0, UB);

    // xi2 = u @ Wi2^T + bi2   [3200 x 450] (padded to 512), f16 out
    k_gemm<f16><<<25*4, 256, 0, stream>>>(UB, WI2P, bi2, XI2H, 512, 512, 450, 25);

    // GRU2 scan -> dec (f16, padded K=192)
    k_gru2<<<32, 512, 0, stream>>>(XI2H, Wh2, bh2, DECB);

    // out = dec @ W_fc^T + b_fc  -> directly into d_out [3200 x 150] (fp32)
    k_gemm<float><<<25*2, 256, 0, stream>>>(DECB, WFCP, b_fc, out, 192, 150, 150, 25);

    (void)in_sizes; (void)n_in; (void)out_size; (void)ws_size;
}

// Round 9
// 544.058 us; speedup vs baseline: 11.7551x; 1.1305x over previous
//
#include <hip/hip_runtime.h>
#include <hip/hip_fp16.h>
#include <math.h>

typedef _Float16 f16;
typedef _Float16 half8 __attribute__((ext_vector_type(8)));
typedef _Float16 half4 __attribute__((ext_vector_type(4)));
typedef float float4v __attribute__((ext_vector_type(4)));
typedef float float2v __attribute__((ext_vector_type(2)));
typedef unsigned int uint4v __attribute__((ext_vector_type(4)));

#define AS1 __attribute__((address_space(1)))
#define AS3 __attribute__((address_space(3)))

// ---------------- workspace layout ----------------
constexpr size_t alup(size_t x){ return (x + 255) & ~(size_t)255; }
constexpr size_t OFF_MT   = 0;                                    // 150*150 fp32 (zeroed)
constexpr size_t OFF_DEG  = alup(OFF_MT + 150*150*4);             // 150 fp32 (zeroed)
constexpr size_t OFF_HT0  = alup(OFF_DEG + 150*4);                // 32*512 u32 {tag|f16} (zeroed)
constexpr size_t OFF_HT1  = alup(OFF_HT0 + (size_t)32*512*4);     // 32*512 u32 (zeroed)
constexpr size_t OFF_WI2P = alup(OFF_HT1 + (size_t)32*512*4);     // 512*512 f16 padded (zeroed)
constexpr size_t OFF_WFCP = alup(OFF_WI2P + (size_t)512*512*2);   // 256*192 f16 padded (zeroed)
constexpr size_t OFF_WH2P = alup(OFF_WFCP + (size_t)256*192*2);   // 512*160 f16 padded (zeroed)
constexpr size_t OFF_DECB = alup(OFF_WH2P + (size_t)512*160*2);   // 3200*192 f16 (zeroed)
constexpr size_t ZONE_END = alup(OFF_DECB + (size_t)3200*192*2);
constexpr size_t OFF_EDST = ZONE_END;                             // 1500 int
constexpr size_t OFF_EVAL = alup(OFF_EDST + 1500*4);              // 1500 fp32
constexpr size_t OFF_XF   = alup(OFF_EVAL + 1500*4);              // 480000 fp32 (x in row layout)
constexpr size_t OFF_SS   = alup(OFF_XF + (size_t)480000*4);      // 480000 fp32 (agg scalar)
constexpr size_t OFF_XT   = alup(OFF_SS + (size_t)480000*4);      // 3200*4800 f16
constexpr size_t OFF_WI1H = alup(OFF_XT + (size_t)3200*4800*2);   // 1536*4800 f16
constexpr size_t OFF_XI1  = alup(OFF_WI1H + (size_t)1536*4800*2); // 3200*1536 f16
constexpr size_t OFF_U    = alup(OFF_XI1 + (size_t)3200*1536*2);  // 3200*512 f16
constexpr size_t OFF_XI2  = alup(OFF_U + (size_t)3200*512*2);     // 3200*512 f16

// fast gates: __expf lowers to v_exp_f32 fast path (~2ulp; absmax slack ~5x)
static __device__ __forceinline__ float fsig(float x){ return 1.0f/(1.0f + __expf(-x)); }
static __device__ __forceinline__ float ftanh(float x){
    x = fminf(fmaxf(x, -15.f), 15.f);
    float e = __expf(2.0f*x);
    return (e - 1.0f)/(e + 1.0f);
}

// ---------------- topk with inline normalize ----------------
__global__ void k_topk(const float* __restrict__ emb, int* __restrict__ EDST,
                       float* __restrict__ EVAL, float* __restrict__ DEG) {
    __shared__ float WnT[32*152];
    __shared__ float invn[160];
    __shared__ float As[160];
    int tid = threadIdx.x;
    int i = blockIdx.x;  // row
    for (int idx = tid; idx < 4800; idx += 256) {
        int jj = idx >> 5, c = idx & 31;
        WnT[c*152 + jj] = emb[idx];
    }
    __syncthreads();
    if (tid < 150) {
        float s = 0.f;
        #pragma unroll
        for (int c = 0; c < 32; ++c) { float v = WnT[c*152 + tid]; s += v*v; }
        invn[tid] = 1.0f / fmaxf(sqrtf(s), 1e-8f);
    }
    __syncthreads();
    for (int idx = tid; idx < 4800; idx += 256) {
        int jj = idx >> 5, c = idx & 31;
        WnT[c*152 + jj] *= invn[jj];
    }
    __syncthreads();
    int j = tid;
    if (j < 150) {
        float a = 0.f;
        #pragma unroll
        for (int c = 0; c < 32; ++c) a += WnT[c*152 + i] * WnT[c*152 + j];
        a = (j == i) ? 0.f : fmaxf(a, 0.f);
        As[j] = a;
    }
    __syncthreads();
    if (j < 150) {
        float aj = As[j];
        int cnt = 0;
        for (int m = 0; m < 150; ++m) {
            float am = As[m];
            cnt += (am > aj) || (am == aj && m < j);
        }
        if (cnt < 10) {
            EDST[i*10 + cnt] = j;
            EVAL[i*10 + cnt] = aj;
            atomicAdd(&DEG[j], aj);
        }
    }
}

// ---------------- merged prep: finalize + 4x weight cvt + perm (one launch) ----------------
// 0: MT finalize | [1,28801): Wi1 | [28801,29701): Wi2 | [29701,29789): W_fc (ld 192)
// [29789,30053): Wh2 (ld 160) | [30053,31928): window permute
__global__ void k_prep(const int* __restrict__ EDST, const float* __restrict__ EVAL,
                       const float* __restrict__ DEG, float* __restrict__ MT,
                       const float* __restrict__ Wi1, f16* __restrict__ WI1H,
                       const float* __restrict__ Wi2, f16* __restrict__ WI2P,
                       const float* __restrict__ W_fc, f16* __restrict__ WFCP,
                       const float* __restrict__ Wh2, f16* __restrict__ WH2P,
                       const float* __restrict__ window, float* __restrict__ XF) {
    int b = blockIdx.x, tid = threadIdx.x;
    if (b == 0) {
        __shared__ float dinv[160];
        if (tid < 150) {
            float d = DEG[tid];
            dinv[tid] = (d > 0.f) ? rsqrtf(d) : 0.f;
        }
        __syncthreads();
        for (int e = tid; e < 1500; e += 256) {
            int src = e / 10;
            int dst = EDST[e];
            MT[src*150 + dst] = dinv[src] * EVAL[e] * dinv[dst];
        }
    } else if (b < 28801) {
        int idx = (b - 1)*256 + tid;              // 1536*4800 = 7372800, exact
        WI1H[idx] = (f16)Wi1[idx];
    } else if (b < 29701) {
        int idx = (b - 28801)*256 + tid;          // 450*512 = 230400, exact
        WI2P[idx] = (f16)Wi2[idx];
    } else if (b < 29789) {
        int idx = (b - 29701)*256 + tid;          // 150*150 = 22500
        if (idx < 22500) {
            int r = idx / 150, c = idx % 150;
            WFCP[r*192 + c] = (f16)W_fc[idx];
        }
    } else if (b < 30053) {
        int idx = (b - 29789)*256 + tid;          // 450*150 = 67500
        if (idx < 67500) {
            int r = idx / 150, c = idx % 150;
            WH2P[r*160 + c] = (f16)Wh2[idx];
        }
    } else {
        int idx = (b - 30053)*256 + tid;          // 480000, exact
        float v = window[idx];
        int bb = idx / 15000;
        int r = idx % 15000;
        int t = r / 150, n = r % 150;
        XF[bb*15000 + n*100 + t] = v;
    }
}

// ---------------- scrambled ARMA aggregation: per contiguous 150-chunk of XF ----------------
__global__ void k_conv(const float* __restrict__ XF, const float* __restrict__ MT,
                       float* __restrict__ SS) {
    __shared__ float xs[152];
    int tid = threadIdx.x;
    int base = blockIdx.x * 150;
    if (tid < 150) xs[tid] = XF[base + tid];
    __syncthreads();
    if (tid < 150) {
        float s = 0.f;
        for (int m = 0; m < 150; ++m) s += MT[m*150 + tid] * xs[m];
        SS[base + tid] = s;
    }
}

// ---------------- epilogue: gelu(SS*wi + XF*wr + b) + emb -> xt (f16) ----------------
__global__ void k_xt(const float* __restrict__ SS, const float* __restrict__ XF,
                     const float* __restrict__ w_init, const float* __restrict__ w_root,
                     const float* __restrict__ arma_b, const float* __restrict__ emb,
                     f16* __restrict__ xt) {
    __shared__ float ssl[152];
    __shared__ float xfl[152];
    int tid = threadIdx.x;
    int bid = blockIdx.x;           // = b*100 + t
    int b = bid / 100, t = bid % 100;
    if (tid < 150) {
        int f = b*15000 + tid*100 + t;
        ssl[tid] = SS[f];
        xfl[tid] = XF[f];
    }
    __syncthreads();
    for (int e = tid; e < 4800; e += 256) {
        int n = e >> 5, c = e & 31;
        float pre = ssl[n]*w_init[c] + xfl[n]*w_root[c] + arma_b[c];
        float g = 0.5f * pre * (1.0f + erff(pre * 0.70710678118654752f));
        xt[(size_t)bid*4800 + e] = (f16)(g + emb[e]);
    }
}

// ---------------- f16 MFMA GEMM, BK=64, N-major block order ----------------
template <typename TC>
__global__ void k_gemm(const f16* __restrict__ A, const f16* __restrict__ Bm,
                       const float* __restrict__ bias, TC* __restrict__ C,
                       int K, int ldc, int nvalid, int ntm) {
    __shared__ f16 As[128*64];
    __shared__ f16 Bs[128*64];
    int tid = threadIdx.x;
    int lane = tid & 63, wave = tid >> 6;
    int wm = wave >> 1, wn = wave & 1;
    int tm = blockIdx.x % ntm, tn = blockIdx.x / ntm;
    int m0 = tm * 128, n0 = tn * 128;
    int lrow = lane & 15, quad = lane >> 4;

    float4v acc[4][4];
    #pragma unroll
    for (int mi = 0; mi < 4; ++mi)
        #pragma unroll
        for (int ni = 0; ni < 4; ++ni)
            acc[mi][ni] = (float4v){0.f, 0.f, 0.f, 0.f};

    for (int k0 = 0; k0 < K; k0 += 64) {
        #pragma unroll
        for (int i = 0; i < 4; ++i) {
            int cid = i*256 + tid;          // 1024 chunks of 8 halves
            int row = cid >> 3, cq = cid & 7;
            int cbase = cid & ~63;          // wave-uniform
            const f16* ga = A + (size_t)(m0+row)*K + k0 + cq*8;
            __builtin_amdgcn_global_load_lds((const AS1 void*)ga, (AS3 void*)(As + cbase*8), 16, 0, 0);
            const f16* gb = Bm + (size_t)(n0+row)*K + k0 + cq*8;
            __builtin_amdgcn_global_load_lds((const AS1 void*)gb, (AS3 void*)(Bs + cbase*8), 16, 0, 0);
        }
        __syncthreads();
        #pragma unroll
        for (int kk = 0; kk < 2; ++kk) {
            half8 aF[4], bF[4];
            #pragma unroll
            for (int mi = 0; mi < 4; ++mi)
                aF[mi] = *(const half8*)&As[(wm*64 + mi*16 + lrow)*64 + kk*32 + quad*8];
            #pragma unroll
            for (int ni = 0; ni < 4; ++ni)
                bF[ni] = *(const half8*)&Bs[(wn*64 + ni*16 + lrow)*64 + kk*32 + quad*8];
            #pragma unroll
            for (int mi = 0; mi < 4; ++mi)
                #pragma unroll
                for (int ni = 0; ni < 4; ++ni)
                    acc[mi][ni] = __builtin_amdgcn_mfma_f32_16x16x32_f16(aF[mi], bF[ni], acc[mi][ni], 0, 0, 0);
        }
        __syncthreads();
    }

    #pragma unroll
    for (int ni = 0; ni < 4; ++ni) {
        int gcol = n0 + wn*64 + ni*16 + lrow;
        if (gcol >= nvalid) continue;
        float bv = bias[gcol];
        #pragma unroll
        for (int mi = 0; mi < 4; ++mi) {
            int growb = m0 + wm*64 + mi*16 + quad*4;
            #pragma unroll
            for (int r = 0; r < 4; ++r)
                C[(size_t)(growb + r)*ldc + gcol] = (TC)(acc[mi][ni][r] + bv);
        }
    }
}

// ---------------- GRU1: 16 groups x 16 blocks; AGPR B-frags + u32 tag|f16 exchange ----
__global__ __launch_bounds__(256, 1)
void k_gru1(const f16* __restrict__ xi1, const float* __restrict__ Wh1,
            const float* __restrict__ bh1, unsigned* __restrict__ ht0,
            unsigned* __restrict__ ht1) {
    __shared__ __align__(16) f16 hA[16*640];    // 20KB: [k0][row*40+kk], rows 0,1 real
    __shared__ float ghs[192];
    int tid = threadIdx.x;
    int g = blockIdx.x & 15;
    int j = blockIdx.x >> 4;
    int b0 = g * 2;
    int lane = tid & 63, wave = tid >> 6;
    int lrow = lane & 15, quad = lane >> 4;

    // B-fragments (waves 0..2): tiles 2w, 2w+1; B[n][k]: n=lrow, k=k0*32+quad*8+i
    half8 Bf0[16], Bf1[16];
    if (wave < 3) {
        #pragma unroll
        for (int tile = 0; tile < 2; ++tile) {
            int rr = (wave*2 + tile)*16 + lrow;
            int grow = (rr >> 5)*512 + (j << 5) + (rr & 31);
            const float* wp = Wh1 + (size_t)grow*512 + quad*8;
            #pragma unroll
            for (int k0 = 0; k0 < 16; ++k0) {
                float4v w0 = *(const float4v*)(wp + k0*32);
                float4v w1 = *(const float4v*)(wp + k0*32 + 4);
                half8 hb;
                hb[0]=(f16)w0[0]; hb[1]=(f16)w0[1]; hb[2]=(f16)w0[2]; hb[3]=(f16)w0[3];
                hb[4]=(f16)w1[0]; hb[5]=(f16)w1[1]; hb[6]=(f16)w1[2]; hb[7]=(f16)w1[3];
                if (tile == 0) Bf0[k0] = hb; else Bf1[k0] = hb;
            }
        }
    }

    // gates state (tid<64): own hidden + biases + xi in registers
    float hold = 0.f, bhr = 0.f, bhz = 0.f, bhn = 0.f;
    f16 xir = (f16)0.f, xiz = (f16)0.f, xin = (f16)0.f;
    size_t xb = 0;
    if (tid < 64) {
        int bl = tid >> 5, i = tid & 31;
        int col = (j << 5) + i;
        bhr = bh1[col]; bhz = bh1[512 + col]; bhn = bh1[1024 + col];
        xb = (size_t)((b0 + bl)*100)*1536 + col;
        xir = xi1[xb]; xiz = xi1[xb + 512]; xin = xi1[xb + 1024];   // t=0
    }
    // staging: thread -> 4 consecutive u32 h-slots (16B)
    int sbl = tid >> 7;
    int kb  = (tid & 127) << 2;

    for (int t = 0; t < 100; ++t) {
        const unsigned* cur = (t & 1) ? ht1 : ht0;
        unsigned* nxt = (t & 1) ? ht0 : ht1;
        // ---- stage h: poll tag-in-data, place f16 A-fragment ----
        {
            const unsigned* p = cur + (size_t)(b0 + sbl)*512 + kb;
            uint4v A4;
            unsigned tagw = (unsigned)t << 16;
            for (;;) {
                asm volatile("global_load_dwordx4 %0, %1, off sc0 sc1\n\ts_waitcnt vmcnt(0)"
                             : "=v"(A4) : "v"(p) : "memory");
                if ((A4[0] & 0xffff0000u) == tagw && (A4[1] & 0xffff0000u) == tagw &&
                    (A4[2] & 0xffff0000u) == tagw && (A4[3] & 0xffff0000u) == tagw) break;
                __builtin_amdgcn_s_sleep(1);
            }
            union { unsigned short s[4]; half4 h; } cv;
            cv.s[0] = (unsigned short)A4[0]; cv.s[1] = (unsigned short)A4[1];
            cv.s[2] = (unsigned short)A4[2]; cv.s[3] = (unsigned short)A4[3];
            *(half4*)&hA[(kb >> 5)*640 + sbl*40 + (kb & 31)] = cv.h;
        }
        __syncthreads();   // A

        if (wave < 3) {
            // split accumulator chains (2x8 deps instead of 1x16)
            float4v a0a = (float4v){0.f,0.f,0.f,0.f}, a0b = a0a, a1a = a0a, a1b = a0a;
            const f16* aB = &hA[lrow*40 + quad*8];
            #pragma unroll
            for (int k0 = 0; k0 < 16; k0 += 2) {
                half8 a0 = *(const half8*)(aB + k0*640);
                half8 a1 = *(const half8*)(aB + (k0+1)*640);
                a0a = __builtin_amdgcn_mfma_f32_16x16x32_f16(a0, Bf0[k0], a0a, 0, 0, 0);
                a1a = __builtin_amdgcn_mfma_f32_16x16x32_f16(a0, Bf1[k0], a1a, 0, 0, 0);
                a0b = __builtin_amdgcn_mfma_f32_16x16x32_f16(a1, Bf0[k0+1], a0b, 0, 0, 0);
                a1b = __builtin_amdgcn_mfma_f32_16x16x32_f16(a1, Bf1[k0+1], a1b, 0, 0, 0);
            }
            if (lane < 16) {   // C: col=lane, row=reg; rows 0,1 = batches
                int n0 = wave*2, n1 = n0 + 1;
                ghs[n0*16 + lane]      = a0a[0] + a0b[0];
                ghs[96 + n0*16 + lane] = a0a[1] + a0b[1];
                ghs[n1*16 + lane]      = a1a[0] + a1b[0];
                ghs[96 + n1*16 + lane] = a1a[1] + a1b[1];
            }
        }
        __syncthreads();   // B

        if (tid < 64) {
            int bl = tid >> 5, i = tid & 31;
            float xr_ = (float)xir, xz_ = (float)xiz, xn_ = (float)xin;
            // prefetch xi for t+1 (immutable; lands during next step's exchange)
            int tn = (t < 99) ? t + 1 : 99;
            size_t xo = xb + (size_t)tn*1536;
            xir = xi1[xo]; xiz = xi1[xo + 512]; xin = xi1[xo + 1024];
            float gr = ghs[bl*96 + i]      + bhr;
            float gz = ghs[bl*96 + 32 + i] + bhz;
            float gn = ghs[bl*96 + 64 + i] + bhn;
            float r = fsig(xr_ + gr);
            float z = fsig(xz_ + gz);
            float n = ftanh(xn_ + r*gn);
            float hnew = (1.f - z)*n + z*hold;
            hold = hnew;
            union { f16 h; unsigned short s; } hb; hb.h = (f16)hnew;
            unsigned pk = ((unsigned)(t + 1) << 16) | (unsigned)hb.s;
            __hip_atomic_store(nxt + (size_t)(b0 + bl)*512 + (j << 5) + i, pk,
                               __ATOMIC_RELAXED, __HIP_MEMORY_SCOPE_AGENT);
        }
    }
}

// ---------------- u[b,t,k] = h_end[b, (t*512+k)/100]  (repeat_interleave quirk) ----------------
__global__ void k_build_u(const unsigned* __restrict__ ht0, f16* __restrict__ u) {
    int idx = blockIdx.x * blockDim.x + threadIdx.x;
    if (idx >= 32*100*512) return;
    int b = idx / 51200;
    int r = idx % 51200;
    int t = r >> 9, k = r & 511;
    union { unsigned short s; f16 h; } cv;
    cv.s = (unsigned short)ht0[(b << 9) + ((t*512 + k) / 100)];
    u[idx] = cv.h;
}

// ---------------- GRU2: MFMA rewrite — one block per batch, 256 threads, NO LDS broadcasts ----
// R8 tail analysis: old gru2 issued 150 scalar ds_read_b32 broadcasts/thread/step (~1.4us/step,
// ~140us total — the stable "445us tail" culprit). Now: per-step GEMM [1x160]@[160x512(padded)]
// via mfma 16x16x32 f16. B-frags (Wh2 padded [512x160] f16) register-resident: 8 tiles x 5
// k-chunks per wave = 160 VGPRs. Gate threads write h directly into the A-frag LDS layout
// (row 0; rows 1-15 + k 150-159 zeroed once -> no NaN). 5 ds_read_b128 + 40 MFMA per wave
// per step, 2 barriers.
__global__ __launch_bounds__(256, 1)
void k_gru2(const f16* __restrict__ xi2, const f16* __restrict__ wh2p,
            const float* __restrict__ bh2, f16* __restrict__ decb) {
    __shared__ __align__(16) f16 hA[5*640];     // [k0][row*40+kk], row 0 real
    __shared__ float ghs[512];
    int tid = threadIdx.x;
    int b = blockIdx.x;
    int lane = tid & 63, wave = tid >> 6;
    int lrow = lane & 15, quad = lane >> 4;

    // zero hA once: h(0)=0 and no NaN garbage anywhere
    for (int i = tid; i < 5*640; i += 256) hA[i] = (f16)0.f;

    // B-fragments: 8 tiles x 5 k-chunks per wave (tiles cover N=512 padded rows of Wh2P)
    half8 Bf[8][5];
    #pragma unroll
    for (int tt = 0; tt < 8; ++tt) {
        int rn = (wave*8 + tt)*16 + lrow;
        const f16* wp = wh2p + (size_t)rn*160 + quad*8;
        #pragma unroll
        for (int k0 = 0; k0 < 5; ++k0)
            Bf[tt][k0] = *(const half8*)(wp + k0*32);
    }

    // gate state (tid<150)
    float hold = 0.f, bhr = 0.f, bhz = 0.f, bhn = 0.f;
    f16 xr = (f16)0.f, xz = (f16)0.f, xn = (f16)0.f;
    size_t xbase = (size_t)b * 100 * 512;
    if (tid < 150) {
        bhr = bh2[tid]; bhz = bh2[150 + tid]; bhn = bh2[300 + tid];
        xr = xi2[xbase + tid]; xz = xi2[xbase + 150 + tid]; xn = xi2[xbase + 300 + tid];
    }
    __syncthreads();

    for (int t = 0; t < 100; ++t) {
        // MFMA: gh = Wh2 @ h  (A row 0 = h)
        float4v acc[8];
        #pragma unroll
        for (int tt = 0; tt < 8; ++tt) acc[tt] = (float4v){0.f,0.f,0.f,0.f};
        #pragma unroll
        for (int k0 = 0; k0 < 5; ++k0) {
            half8 a = *(const half8*)&hA[k0*640 + lrow*40 + quad*8];
            #pragma unroll
            for (int tt = 0; tt < 8; ++tt)
                acc[tt] = __builtin_amdgcn_mfma_f32_16x16x32_f16(a, Bf[tt][k0], acc[tt], 0, 0, 0);
        }
        if (lane < 16) {       // C row 0 = lanes 0-15, reg 0
            #pragma unroll
            for (int tt = 0; tt < 8; ++tt)
                ghs[(wave*8 + tt)*16 + lane] = acc[tt][0];
        }
        __syncthreads();       // ghs ready; hA reads done

        if (tid < 150) {
            float r = fsig((float)xr + ghs[tid] + bhr);
            float z = fsig((float)xz + ghs[150 + tid] + bhz);
            float n = ftanh((float)xn + r*(ghs[300 + tid] + bhn));
            float hnew = (1.f - z)*n + z*hold;
            hold = hnew;
            f16 hh = (f16)hnew;
            hA[(tid >> 5)*640 + (tid & 31)] = hh;    // A row 0, k = tid
            decb[((size_t)b*100 + t)*192 + tid] = hh;
            int tn = (t < 99) ? t + 1 : 99;
            size_t xo = xbase + (size_t)tn*512;
            xr = xi2[xo + tid]; xz = xi2[xo + 150 + tid]; xn = xi2[xo + 300 + tid];
        }
        __syncthreads();       // hA(t+1) ready
    }
}

// ---------------- launch ----------------
extern "C" void kernel_launch(void* const* d_in, const int* in_sizes, int n_in,
                              void* d_out, int out_size, void* d_ws, size_t ws_size,
                              hipStream_t stream) {
    const float* window = (const float*)d_in[0];
    const float* emb    = (const float*)d_in[1];
    const float* w_init = (const float*)d_in[2];
    const float* w_root = (const float*)d_in[3];
    const float* arma_b = (const float*)d_in[4];
    const float* Wi1    = (const float*)d_in[5];
    const float* Wh1    = (const float*)d_in[6];
    const float* bi1    = (const float*)d_in[7];
    const float* bh1    = (const float*)d_in[8];
    const float* Wi2    = (const float*)d_in[9];
    const float* Wh2    = (const float*)d_in[10];
    const float* bi2    = (const float*)d_in[11];
    const float* bh2    = (const float*)d_in[12];
    const float* W_fc   = (const float*)d_in[13];
    const float* b_fc   = (const float*)d_in[14];
    float* out = (float*)d_out;

    char* ws = (char*)d_ws;
    float*    MT   = (float*)(ws + OFF_MT);
    float*    DEG  = (float*)(ws + OFF_DEG);
    unsigned* HT0  = (unsigned*)(ws + OFF_HT0);
    unsigned* HT1  = (unsigned*)(ws + OFF_HT1);
    f16*      WI2P = (f16*)  (ws + OFF_WI2P);
    f16*      WFCP = (f16*)  (ws + OFF_WFCP);
    f16*      WH2P = (f16*)  (ws + OFF_WH2P);
    f16*      DECB = (f16*)  (ws + OFF_DECB);
    int*      EDST = (int*)  (ws + OFF_EDST);
    float*    EVAL = (float*)(ws + OFF_EVAL);
    float*    XF   = (float*)(ws + OFF_XF);
    float*    SS   = (float*)(ws + OFF_SS);
    f16*      XT   = (f16*)  (ws + OFF_XT);
    f16*      WI1H = (f16*)  (ws + OFF_WI1H);
    f16*      XI1H = (f16*)  (ws + OFF_XI1);
    f16*      UB   = (f16*)  (ws + OFF_U);
    f16*      XI2H = (f16*)  (ws + OFF_XI2);

    // zero the zone (MT scatter target, deg, tagged h buffers, padded weights, dec)
    hipMemsetAsync(d_ws, 0, ZONE_END, stream);

    // graph build (norm inlined in topk)
    k_topk<<<150, 256, 0, stream>>>(emb, EDST, EVAL, DEG);

    // merged prep: finalize + weight cvts + window permute
    k_prep<<<31928, 256, 0, stream>>>(EDST, EVAL, DEG, MT,
                                      Wi1, WI1H, Wi2, WI2P, W_fc, WFCP,
                                      Wh2, WH2P, window, XF);

    // scrambled aggregation, epilogue -> xt (f16)
    k_conv<<<3200, 256, 0, stream>>>(XF, MT, SS);
    k_xt<<<3200, 256, 0, stream>>>(SS, XF, w_init, w_root, arma_b, emb, XT);

    // xi1 = xt @ Wi1^T + bi1   [3200 x 1536] f16 out, N-major, ntm=25
    k_gemm<f16><<<25*12, 256, 0, stream>>>(XT, WI1H, bi1, XI1H, 4800, 1536, 1536, 25);

    // GRU1 scan -> h_end (tagged f16) in HT0
    k_gru1<<<256, 256, 0, stream>>>(XI1H, Wh1, bh1, HT0, HT1);

    // u (repeat_interleave quirk), f16
    k_build_u<<<(32*100*512 + 255)/256, 256, 0, stream>>>(HT0, UB);

    // xi2 = u @ Wi2^T + bi2   [3200 x 450] (padded to 512), f16 out
    k_gemm<f16><<<25*4, 256, 0, stream>>>(UB, WI2P, bi2, XI2H, 512, 512, 450, 25);

    // GRU2 scan -> dec (f16, padded K=192), MFMA version
    k_gru2<<<32, 256, 0, stream>>>(XI2H, WH2P, bh2, DECB);

    // out = dec @ W_fc^T + b_fc  -> directly into d_out [3200 x 150] (fp32)
    k_gemm<float><<<25*2, 256, 0, stream>>>(DECB, WFCP, b_fc, out, 192, 150, 150, 25);

    (void)in_sizes; (void)n_in; (void)out_size; (void)ws_size;
}

// Round 10
// 541.036 us; speedup vs baseline: 11.8207x; 1.0056x over previous
//
#include <hip/hip_runtime.h>
#include <hip/hip_fp16.h>
#include <math.h>

typedef _Float16 f16;
typedef _Float16 half8 __attribute__((ext_vector_type(8)));
typedef _Float16 half4 __attribute__((ext_vector_type(4)));
typedef float float4v __attribute__((ext_vector_type(4)));
typedef float float2v __attribute__((ext_vector_type(2)));
typedef unsigned int uint4v __attribute__((ext_vector_type(4)));

#define AS1 __attribute__((address_space(1)))
#define AS3 __attribute__((address_space(3)))

// ---------------- workspace layout ----------------
constexpr size_t alup(size_t x){ return (x + 255) & ~(size_t)255; }
constexpr size_t OFF_MT   = 0;                                    // 150*150 fp32 (zeroed)
constexpr size_t OFF_DEG  = alup(OFF_MT + 150*150*4);             // 150 fp32 (zeroed)
constexpr size_t OFF_HT0  = alup(OFF_DEG + 150*4);                // 32*512 u32 {tag|f16} (zeroed)
constexpr size_t OFF_HT1  = alup(OFF_HT0 + (size_t)32*512*4);     // 32*512 u32 (zeroed)
constexpr size_t OFF_WFCP = alup(OFF_HT1 + (size_t)32*512*4);     // 256*192 f16 padded (zeroed)
constexpr size_t OFF_WH2P = alup(OFF_WFCP + (size_t)256*192*2);   // 512*160 f16 padded (zeroed)
constexpr size_t OFF_DECB = alup(OFF_WH2P + (size_t)512*160*2);   // 3200*192 f16 (zeroed)
constexpr size_t ZONE_END = alup(OFF_DECB + (size_t)3200*192*2);
constexpr size_t OFF_EDST = ZONE_END;                             // 1500 int
constexpr size_t OFF_EVAL = alup(OFF_EDST + 1500*4);              // 1500 fp32
constexpr size_t OFF_PT   = alup(OFF_EVAL + 1500*4);              // 513*452 fp32 Wi2 prefix (cols o)
constexpr size_t OFF_XF   = alup(OFF_PT + (size_t)513*452*4);     // 480000 fp32 (x in row layout)
constexpr size_t OFF_SS   = alup(OFF_XF + (size_t)480000*4);      // 480000 fp32 (agg scalar)
constexpr size_t OFF_XT   = alup(OFF_SS + (size_t)480000*4);      // 3200*4800 f16
constexpr size_t OFF_WI1H = alup(OFF_XT + (size_t)3200*4800*2);   // 1536*4800 f16
constexpr size_t OFF_XI1  = alup(OFF_WI1H + (size_t)1536*4800*2); // 3200*1536 f16
constexpr size_t OFF_XI2  = alup(OFF_XI1 + (size_t)3200*1536*2);  // 3200*512 f16

// fast gates: __expf lowers to v_exp_f32 fast path (~2ulp; absmax slack ~3x)
static __device__ __forceinline__ float fsig(float x){ return 1.0f/(1.0f + __expf(-x)); }
static __device__ __forceinline__ float ftanh(float x){
    x = fminf(fmaxf(x, -15.f), 15.f);
    float e = __expf(2.0f*x);
    return (e - 1.0f)/(e + 1.0f);
}

// ---------------- topk with inline normalize ----------------
__global__ void k_topk(const float* __restrict__ emb, int* __restrict__ EDST,
                       float* __restrict__ EVAL, float* __restrict__ DEG) {
    __shared__ float WnT[32*152];
    __shared__ float invn[160];
    __shared__ float As[160];
    int tid = threadIdx.x;
    int i = blockIdx.x;  // row
    for (int idx = tid; idx < 4800; idx += 256) {
        int jj = idx >> 5, c = idx & 31;
        WnT[c*152 + jj] = emb[idx];
    }
    __syncthreads();
    if (tid < 150) {
        float s = 0.f;
        #pragma unroll
        for (int c = 0; c < 32; ++c) { float v = WnT[c*152 + tid]; s += v*v; }
        invn[tid] = 1.0f / fmaxf(sqrtf(s), 1e-8f);
    }
    __syncthreads();
    for (int idx = tid; idx < 4800; idx += 256) {
        int jj = idx >> 5, c = idx & 31;
        WnT[c*152 + jj] *= invn[jj];
    }
    __syncthreads();
    int j = tid;
    if (j < 150) {
        float a = 0.f;
        #pragma unroll
        for (int c = 0; c < 32; ++c) a += WnT[c*152 + i] * WnT[c*152 + j];
        a = (j == i) ? 0.f : fmaxf(a, 0.f);
        As[j] = a;
    }
    __syncthreads();
    if (j < 150) {
        float aj = As[j];
        int cnt = 0;
        for (int m = 0; m < 150; ++m) {
            float am = As[m];
            cnt += (am > aj) || (am == aj && m < j);
        }
        if (cnt < 10) {
            EDST[i*10 + cnt] = j;
            EVAL[i*10 + cnt] = aj;
            atomicAdd(&DEG[j], aj);
        }
    }
}

// ---------------- merged prep: finalize + weight cvts + perm + Wi2 prefix (one launch) ----
// 0: MT | [1,28801): Wi1 | [28801,28889): W_fc (ld 192) | [28889,29153): Wh2 (ld 160)
// [29153,31028): window permute | [31028,31030): Wi2 prefix-sum -> PT[k][o]
__global__ void k_prep(const int* __restrict__ EDST, const float* __restrict__ EVAL,
                       const float* __restrict__ DEG, float* __restrict__ MT,
                       const float* __restrict__ Wi1, f16* __restrict__ WI1H,
                       const float* __restrict__ W_fc, f16* __restrict__ WFCP,
                       const float* __restrict__ Wh2, f16* __restrict__ WH2P,
                       const float* __restrict__ window, float* __restrict__ XF,
                       const float* __restrict__ Wi2, float* __restrict__ PT) {
    int b = blockIdx.x, tid = threadIdx.x;
    if (b == 0) {
        __shared__ float dinv[160];
        if (tid < 150) {
            float d = DEG[tid];
            dinv[tid] = (d > 0.f) ? rsqrtf(d) : 0.f;
        }
        __syncthreads();
        for (int e = tid; e < 1500; e += 256) {
            int src = e / 10;
            int dst = EDST[e];
            MT[src*150 + dst] = dinv[src] * EVAL[e] * dinv[dst];
        }
    } else if (b < 28801) {
        int idx = (b - 1)*256 + tid;              // 1536*4800 = 7372800, exact
        WI1H[idx] = (f16)Wi1[idx];
    } else if (b < 28889) {
        int idx = (b - 28801)*256 + tid;          // 150*150 = 22500
        if (idx < 22500) {
            int r = idx / 150, c = idx % 150;
            WFCP[r*192 + c] = (f16)W_fc[idx];
        }
    } else if (b < 29153) {
        int idx = (b - 28889)*256 + tid;          // 450*150 = 67500
        if (idx < 67500) {
            int r = idx / 150, c = idx % 150;
            WH2P[r*160 + c] = (f16)Wh2[idx];
        }
    } else if (b < 31028) {
        int idx = (b - 29153)*256 + tid;          // 480000, exact
        float v = window[idx];
        int bb = idx / 15000;
        int r = idx % 15000;
        int t = r / 150, n = r % 150;
        XF[bb*15000 + n*100 + t] = v;
    } else {
        int o = (b - 31028)*256 + tid;            // 450 rows: prefix-scan Wi2 along k
        if (o < 450) {
            float run = 0.f;
            PT[o] = 0.f;
            for (int k = 0; k < 512; ++k) {
                run += Wi2[o*512 + k];
                PT[(size_t)(k+1)*452 + o] = run;
            }
        }
    }
}

// ---------------- scrambled ARMA aggregation: per contiguous 150-chunk of XF ----------------
__global__ void k_conv(const float* __restrict__ XF, const float* __restrict__ MT,
                       float* __restrict__ SS) {
    __shared__ float xs[152];
    int tid = threadIdx.x;
    int base = blockIdx.x * 150;
    if (tid < 150) xs[tid] = XF[base + tid];
    __syncthreads();
    if (tid < 150) {
        float s = 0.f;
        for (int m = 0; m < 150; ++m) s += MT[m*150 + tid] * xs[m];
        SS[base + tid] = s;
    }
}

// ---------------- epilogue: gelu(SS*wi + XF*wr + b) + emb -> xt (f16) ----------------
__global__ void k_xt(const float* __restrict__ SS, const float* __restrict__ XF,
                     const float* __restrict__ w_init, const float* __restrict__ w_root,
                     const float* __restrict__ arma_b, const float* __restrict__ emb,
                     f16* __restrict__ xt) {
    __shared__ float ssl[152];
    __shared__ float xfl[152];
    int tid = threadIdx.x;
    int bid = blockIdx.x;           // = b*100 + t
    int b = bid / 100, t = bid % 100;
    if (tid < 150) {
        int f = b*15000 + tid*100 + t;
        ssl[tid] = SS[f];
        xfl[tid] = XF[f];
    }
    __syncthreads();
    for (int e = tid; e < 4800; e += 256) {
        int n = e >> 5, c = e & 31;
        float pre = ssl[n]*w_init[c] + xfl[n]*w_root[c] + arma_b[c];
        float g = 0.5f * pre * (1.0f + erff(pre * 0.70710678118654752f));
        xt[(size_t)bid*4800 + e] = (f16)(g + emb[e]);
    }
}

// ---------------- f16 MFMA GEMM, 64x128 tile, BK=64, N-major block order ----------------
// R9: 128x128 tile gave only 300 blocks for gemm1 (1.17/CU — no co-resident overlap of
// barrier drains, bad tail quantization). 64x128 -> 600 blocks, 24KB LDS, acc 32 VGPR:
// 4+ blocks/CU co-resident, drains overlap across blocks (m114 wave-overlap).
template <typename TC>
__global__ void k_gemm(const f16* __restrict__ A, const f16* __restrict__ Bm,
                       const float* __restrict__ bias, TC* __restrict__ C,
                       int K, int ldc, int nvalid, int ntm) {
    __shared__ f16 As[64*64];
    __shared__ f16 Bs[128*64];
    int tid = threadIdx.x;
    int lane = tid & 63, wave = tid >> 6;
    int wm = wave >> 1, wn = wave & 1;           // wave tile 32 x 64
    int tm = blockIdx.x % ntm, tn = blockIdx.x / ntm;
    int m0 = tm * 64, n0 = tn * 128;
    int lrow = lane & 15, quad = lane >> 4;

    float4v acc[2][4];
    #pragma unroll
    for (int mi = 0; mi < 2; ++mi)
        #pragma unroll
        for (int ni = 0; ni < 4; ++ni)
            acc[mi][ni] = (float4v){0.f, 0.f, 0.f, 0.f};

    for (int k0 = 0; k0 < K; k0 += 64) {
        #pragma unroll
        for (int i = 0; i < 2; ++i) {            // A: 512 chunks of 8 halves
            int cid = i*256 + tid;
            int row = cid >> 3, cq = cid & 7;
            int cbase = cid & ~63;               // wave-uniform
            const f16* ga = A + (size_t)(m0+row)*K + k0 + cq*8;
            __builtin_amdgcn_global_load_lds((const AS1 void*)ga, (AS3 void*)(As + cbase*8), 16, 0, 0);
        }
        #pragma unroll
        for (int i = 0; i < 4; ++i) {            // B: 1024 chunks
            int cid = i*256 + tid;
            int row = cid >> 3, cq = cid & 7;
            int cbase = cid & ~63;
            const f16* gb = Bm + (size_t)(n0+row)*K + k0 + cq*8;
            __builtin_amdgcn_global_load_lds((const AS1 void*)gb, (AS3 void*)(Bs + cbase*8), 16, 0, 0);
        }
        __syncthreads();
        #pragma unroll
        for (int kk = 0; kk < 2; ++kk) {
            half8 aF[2], bF[4];
            #pragma unroll
            for (int mi = 0; mi < 2; ++mi)
                aF[mi] = *(const half8*)&As[(wm*32 + mi*16 + lrow)*64 + kk*32 + quad*8];
            #pragma unroll
            for (int ni = 0; ni < 4; ++ni)
                bF[ni] = *(const half8*)&Bs[(wn*64 + ni*16 + lrow)*64 + kk*32 + quad*8];
            #pragma unroll
            for (int mi = 0; mi < 2; ++mi)
                #pragma unroll
                for (int ni = 0; ni < 4; ++ni)
                    acc[mi][ni] = __builtin_amdgcn_mfma_f32_16x16x32_f16(aF[mi], bF[ni], acc[mi][ni], 0, 0, 0);
        }
        __syncthreads();
    }

    #pragma unroll
    for (int ni = 0; ni < 4; ++ni) {
        int gcol = n0 + wn*64 + ni*16 + lrow;
        if (gcol >= nvalid) continue;
        float bv = bias[gcol];
        #pragma unroll
        for (int mi = 0; mi < 2; ++mi) {
            int growb = m0 + wm*32 + mi*16 + quad*4;
            #pragma unroll
            for (int r = 0; r < 4; ++r)
                C[(size_t)(growb + r)*ldc + gcol] = (TC)(acc[mi][ni][r] + bv);
        }
    }
}

// ---------------- GRU1: 16 groups x 16 blocks; AGPR B-frags + u32 tag|f16 exchange ----
__global__ __launch_bounds__(256, 1)
void k_gru1(const f16* __restrict__ xi1, const float* __restrict__ Wh1,
            const float* __restrict__ bh1, unsigned* __restrict__ ht0,
            unsigned* __restrict__ ht1) {
    __shared__ __align__(16) f16 hA[16*640];    // 20KB: [k0][row*40+kk], rows 0,1 real
    __shared__ float ghs[192];
    int tid = threadIdx.x;
    int g = blockIdx.x & 15;
    int j = blockIdx.x >> 4;
    int b0 = g * 2;
    int lane = tid & 63, wave = tid >> 6;
    int lrow = lane & 15, quad = lane >> 4;

    // B-fragments (waves 0..2): tiles 2w, 2w+1; B[n][k]: n=lrow, k=k0*32+quad*8+i
    half8 Bf0[16], Bf1[16];
    if (wave < 3) {
        #pragma unroll
        for (int tile = 0; tile < 2; ++tile) {
            int rr = (wave*2 + tile)*16 + lrow;
            int grow = (rr >> 5)*512 + (j << 5) + (rr & 31);
            const float* wp = Wh1 + (size_t)grow*512 + quad*8;
            #pragma unroll
            for (int k0 = 0; k0 < 16; ++k0) {
                float4v w0 = *(const float4v*)(wp + k0*32);
                float4v w1 = *(const float4v*)(wp + k0*32 + 4);
                half8 hb;
                hb[0]=(f16)w0[0]; hb[1]=(f16)w0[1]; hb[2]=(f16)w0[2]; hb[3]=(f16)w0[3];
                hb[4]=(f16)w1[0]; hb[5]=(f16)w1[1]; hb[6]=(f16)w1[2]; hb[7]=(f16)w1[3];
                if (tile == 0) Bf0[k0] = hb; else Bf1[k0] = hb;
            }
        }
    }

    // gates state (tid<64): own hidden + biases + xi in registers
    float hold = 0.f, bhr = 0.f, bhz = 0.f, bhn = 0.f;
    f16 xir = (f16)0.f, xiz = (f16)0.f, xin = (f16)0.f;
    size_t xb = 0;
    if (tid < 64) {
        int bl = tid >> 5, i = tid & 31;
        int col = (j << 5) + i;
        bhr = bh1[col]; bhz = bh1[512 + col]; bhn = bh1[1024 + col];
        xb = (size_t)((b0 + bl)*100)*1536 + col;
        xir = xi1[xb]; xiz = xi1[xb + 512]; xin = xi1[xb + 1024];   // t=0
    }
    // staging: thread -> 4 consecutive u32 h-slots (16B)
    int sbl = tid >> 7;
    int kb  = (tid & 127) << 2;

    for (int t = 0; t < 100; ++t) {
        const unsigned* cur = (t & 1) ? ht1 : ht0;
        unsigned* nxt = (t & 1) ? ht0 : ht1;
        // ---- stage h: poll tag-in-data, place f16 A-fragment ----
        {
            const unsigned* p = cur + (size_t)(b0 + sbl)*512 + kb;
            uint4v A4;
            unsigned tagw = (unsigned)t << 16;
            for (;;) {
                asm volatile("global_load_dwordx4 %0, %1, off sc0 sc1\n\ts_waitcnt vmcnt(0)"
                             : "=v"(A4) : "v"(p) : "memory");
                if ((A4[0] & 0xffff0000u) == tagw && (A4[1] & 0xffff0000u) == tagw &&
                    (A4[2] & 0xffff0000u) == tagw && (A4[3] & 0xffff0000u) == tagw) break;
                __builtin_amdgcn_s_sleep(1);
            }
            union { unsigned short s[4]; half4 h; } cv;
            cv.s[0] = (unsigned short)A4[0]; cv.s[1] = (unsigned short)A4[1];
            cv.s[2] = (unsigned short)A4[2]; cv.s[3] = (unsigned short)A4[3];
            *(half4*)&hA[(kb >> 5)*640 + sbl*40 + (kb & 31)] = cv.h;
        }
        __syncthreads();   // A

        if (wave < 3) {
            // split accumulator chains (2x8 deps instead of 1x16)
            float4v a0a = (float4v){0.f,0.f,0.f,0.f}, a0b = a0a, a1a = a0a, a1b = a0a;
            const f16* aB = &hA[lrow*40 + quad*8];
            #pragma unroll
            for (int k0 = 0; k0 < 16; k0 += 2) {
                half8 a0 = *(const half8*)(aB + k0*640);
                half8 a1 = *(const half8*)(aB + (k0+1)*640);
                a0a = __builtin_amdgcn_mfma_f32_16x16x32_f16(a0, Bf0[k0], a0a, 0, 0, 0);
                a1a = __builtin_amdgcn_mfma_f32_16x16x32_f16(a0, Bf1[k0], a1a, 0, 0, 0);
                a0b = __builtin_amdgcn_mfma_f32_16x16x32_f16(a1, Bf0[k0+1], a0b, 0, 0, 0);
                a1b = __builtin_amdgcn_mfma_f32_16x16x32_f16(a1, Bf1[k0+1], a1b, 0, 0, 0);
            }
            if (lane < 16) {   // C: col=lane, row=reg; rows 0,1 = batches
                int n0 = wave*2, n1 = n0 + 1;
                ghs[n0*16 + lane]      = a0a[0] + a0b[0];
                ghs[96 + n0*16 + lane] = a0a[1] + a0b[1];
                ghs[n1*16 + lane]      = a1a[0] + a1b[0];
                ghs[96 + n1*16 + lane] = a1a[1] + a1b[1];
            }
        }
        __syncthreads();   // B

        if (tid < 64) {
            int bl = tid >> 5, i = tid & 31;
            float xr_ = (float)xir, xz_ = (float)xiz, xn_ = (float)xin;
            // prefetch xi for t+1 (immutable; lands during next step's exchange)
            int tn = (t < 99) ? t + 1 : 99;
            size_t xo = xb + (size_t)tn*1536;
            xir = xi1[xo]; xiz = xi1[xo + 512]; xin = xi1[xo + 1024];
            float gr = ghs[bl*96 + i]      + bhr;
            float gz = ghs[bl*96 + 32 + i] + bhz;
            float gn = ghs[bl*96 + 64 + i] + bhn;
            float r = fsig(xr_ + gr);
            float z = fsig(xz_ + gz);
            float n = ftanh(xn_ + r*gn);
            float hnew = (1.f - z)*n + z*hold;
            hold = hnew;
            union { f16 h; unsigned short s; } hb; hb.h = (f16)hnew;
            unsigned pk = ((unsigned)(t + 1) << 16) | (unsigned)hb.s;
            __hip_atomic_store(nxt + (size_t)(b0 + bl)*512 + (j << 5) + i, pk,
                               __ATOMIC_RELAXED, __HIP_MEMORY_SCOPE_AGENT);
        }
    }
}

// ---------------- xi2 via repeat-interleave structure: u rows are piecewise-constant ----
// xi2[(b,t),o] = bi2[o] + sum_s h[b,m0+s] * (PT[khi_s,o] - PT[klo_s,o])  (<=7 segments)
// Replaces k_build_u + gemm2 (1.47 GF -> 17 MF, fp32-exact). One block per (b,t).
__global__ void k_xi2(const unsigned* __restrict__ ht0, const float* __restrict__ PT,
                      const float* __restrict__ bi2, f16* __restrict__ xi2) {
    __shared__ float hs[512];
    int tid = threadIdx.x;
    int bid = blockIdx.x;          // b*100 + t
    int b = bid / 100, t = bid % 100;
    {
        union { unsigned short s; f16 h; } c1, c2;
        c1.s = (unsigned short)ht0[(b << 9) + tid];
        c2.s = (unsigned short)ht0[(b << 9) + tid + 256];
        hs[tid] = (float)c1.h;
        hs[tid + 256] = (float)c2.h;
    }
    __syncthreads();
    int base = t * 512;
    int m0 = base / 100;
    #pragma unroll
    for (int q = 0; q < 2; ++q) {
        int o = tid + q*256;
        if (o < 450) {
            float acc = bi2[o];
            #pragma unroll
            for (int s = 0; s < 7; ++s) {
                int klo = (m0 + s)*100 - base;     klo = klo < 0 ? 0 : klo;
                int khi = (m0 + s + 1)*100 - base; khi = khi > 512 ? 512 : khi;
                if (klo < khi) {
                    float seg = PT[(size_t)khi*452 + o] - PT[(size_t)klo*452 + o];
                    acc += hs[m0 + s] * seg;
                }
            }
            xi2[(size_t)bid*512 + o] = (f16)acc;
        }
    }
}

// ---------------- GRU2: MFMA, one block per batch, B-frags register-resident ----------------
__global__ __launch_bounds__(256, 1)
void k_gru2(const f16* __restrict__ xi2, const f16* __restrict__ wh2p,
            const float* __restrict__ bh2, f16* __restrict__ decb) {
    __shared__ __align__(16) f16 hA[5*640];     // [k0][row*40+kk], row 0 real
    __shared__ float ghs[512];
    int tid = threadIdx.x;
    int b = blockIdx.x;
    int lane = tid & 63, wave = tid >> 6;
    int lrow = lane & 15, quad = lane >> 4;

    for (int i = tid; i < 5*640; i += 256) hA[i] = (f16)0.f;

    half8 Bf[8][5];
    #pragma unroll
    for (int tt = 0; tt < 8; ++tt) {
        int rn = (wave*8 + tt)*16 + lrow;
        const f16* wp = wh2p + (size_t)rn*160 + quad*8;
        #pragma unroll
        for (int k0 = 0; k0 < 5; ++k0)
            Bf[tt][k0] = *(const half8*)(wp + k0*32);
    }

    float hold = 0.f, bhr = 0.f, bhz = 0.f, bhn = 0.f;
    f16 xr = (f16)0.f, xz = (f16)0.f, xn = (f16)0.f;
    size_t xbase = (size_t)b * 100 * 512;
    if (tid < 150) {
        bhr = bh2[tid]; bhz = bh2[150 + tid]; bhn = bh2[300 + tid];
        xr = xi2[xbase + tid]; xz = xi2[xbase + 150 + tid]; xn = xi2[xbase + 300 + tid];
    }
    __syncthreads();

    for (int t = 0; t < 100; ++t) {
        float4v acc[8];
        #pragma unroll
        for (int tt = 0; tt < 8; ++tt) acc[tt] = (float4v){0.f,0.f,0.f,0.f};
        #pragma unroll
        for (int k0 = 0; k0 < 5; ++k0) {
            half8 a = *(const half8*)&hA[k0*640 + lrow*40 + quad*8];
            #pragma unroll
            for (int tt = 0; tt < 8; ++tt)
                acc[tt] = __builtin_amdgcn_mfma_f32_16x16x32_f16(a, Bf[tt][k0], acc[tt], 0, 0, 0);
        }
        if (lane < 16) {
            #pragma unroll
            for (int tt = 0; tt < 8; ++tt)
                ghs[(wave*8 + tt)*16 + lane] = acc[tt][0];
        }
        __syncthreads();

        if (tid < 150) {
            float r = fsig((float)xr + ghs[tid] + bhr);
            float z = fsig((float)xz + ghs[150 + tid] + bhz);
            float n = ftanh((float)xn + r*(ghs[300 + tid] + bhn));
            float hnew = (1.f - z)*n + z*hold;
            hold = hnew;
            f16 hh = (f16)hnew;
            hA[(tid >> 5)*640 + (tid & 31)] = hh;
            decb[((size_t)b*100 + t)*192 + tid] = hh;
            int tn = (t < 99) ? t + 1 : 99;
            size_t xo = xbase + (size_t)tn*512;
            xr = xi2[xo + tid]; xz = xi2[xo + 150 + tid]; xn = xi2[xo + 300 + tid];
        }
        __syncthreads();
    }
}

// ---------------- launch ----------------
extern "C" void kernel_launch(void* const* d_in, const int* in_sizes, int n_in,
                              void* d_out, int out_size, void* d_ws, size_t ws_size,
                              hipStream_t stream) {
    const float* window = (const float*)d_in[0];
    const float* emb    = (const float*)d_in[1];
    const float* w_init = (const float*)d_in[2];
    const float* w_root = (const float*)d_in[3];
    const float* arma_b = (const float*)d_in[4];
    const float* Wi1    = (const float*)d_in[5];
    const float* Wh1    = (const float*)d_in[6];
    const float* bi1    = (const float*)d_in[7];
    const float* bh1    = (const float*)d_in[8];
    const float* Wi2    = (const float*)d_in[9];
    const float* Wh2    = (const float*)d_in[10];
    const float* bi2    = (const float*)d_in[11];
    const float* bh2    = (const float*)d_in[12];
    const float* W_fc   = (const float*)d_in[13];
    const float* b_fc   = (const float*)d_in[14];
    float* out = (float*)d_out;

    char* ws = (char*)d_ws;
    float*    MT   = (float*)(ws + OFF_MT);
    float*    DEG  = (float*)(ws + OFF_DEG);
    unsigned* HT0  = (unsigned*)(ws + OFF_HT0);
    unsigned* HT1  = (unsigned*)(ws + OFF_HT1);
    f16*      WFCP = (f16*)  (ws + OFF_WFCP);
    f16*      WH2P = (f16*)  (ws + OFF_WH2P);
    f16*      DECB = (f16*)  (ws + OFF_DECB);
    int*      EDST = (int*)  (ws + OFF_EDST);
    float*    EVAL = (float*)(ws + OFF_EVAL);
    float*    PT   = (float*)(ws + OFF_PT);
    float*    XF   = (float*)(ws + OFF_XF);
    float*    SS   = (float*)(ws + OFF_SS);
    f16*      XT   = (f16*)  (ws + OFF_XT);
    f16*      WI1H = (f16*)  (ws + OFF_WI1H);
    f16*      XI1H = (f16*)  (ws + OFF_XI1);
    f16*      XI2H = (f16*)  (ws + OFF_XI2);

    // zero the zone (MT scatter target, deg, tagged h buffers, padded weights, dec)
    hipMemsetAsync(d_ws, 0, ZONE_END, stream);

    // graph build (norm inlined in topk)
    k_topk<<<150, 256, 0, stream>>>(emb, EDST, EVAL, DEG);

    // merged prep: finalize + weight cvts + window permute + Wi2 prefix
    k_prep<<<31030, 256, 0, stream>>>(EDST, EVAL, DEG, MT,
                                      Wi1, WI1H, W_fc, WFCP, Wh2, WH2P,
                                      window, XF, Wi2, PT);

    // scrambled aggregation, epilogue -> xt (f16)
    k_conv<<<3200, 256, 0, stream>>>(XF, MT, SS);
    k_xt<<<3200, 256, 0, stream>>>(SS, XF, w_init, w_root, arma_b, emb, XT);

    // xi1 = xt @ Wi1^T + bi1   [3200 x 1536] f16 out, 64x128 tiles, N-major, ntm=50
    k_gemm<f16><<<50*12, 256, 0, stream>>>(XT, WI1H, bi1, XI1H, 4800, 1536, 1536, 50);

    // GRU1 scan -> h_end (tagged f16) in HT0
    k_gru1<<<256, 256, 0, stream>>>(XI1H, Wh1, bh1, HT0, HT1);

    // xi2 via repeat-interleave prefix trick (replaces build_u + gemm2)
    k_xi2<<<3200, 256, 0, stream>>>(HT0, PT, bi2, XI2H);

    // GRU2 scan -> dec (f16, padded K=192), MFMA version
    k_gru2<<<32, 256, 0, stream>>>(XI2H, WH2P, bh2, DECB);

    // out = dec @ W_fc^T + b_fc  -> directly into d_out [3200 x 150] (fp32)
    k_gemm<float><<<50*2, 256, 0, stream>>>(DECB, WFCP, b_fc, out, 192, 150, 150, 50);

    (void)in_sizes; (void)n_in; (void)out_size; (void)ws_size;
}